// Round 10
// baseline (1328.979 us; speedup 1.0000x reference)
//
#include <hip/hip_runtime.h>

// GraphTransformerModel: 2-layer graph attention network.
// CSR build -> bf16 MFMA GEMMs (mgemm6: NO LDS, direct global->VGPR fragments,
// zero barriers) -> attn0 -> gres0+LN -> 4x {qkv1 GEMM -> attn1} -> gres1.
// q/k/v live in fused [N][384] bf16 buffers; all accumulation f32.
// Peak workspace ~186 MB.

typedef unsigned short u16;
typedef __attribute__((ext_vector_type(8))) unsigned short ushort8;
typedef __attribute__((ext_vector_type(8))) short short8v;   // 8 bf16 (4 VGPRs)
typedef __attribute__((ext_vector_type(4))) float f32x4;

__device__ __forceinline__ float bf2f(unsigned short u) {
    return __uint_as_float(((unsigned)u) << 16);
}
__device__ __forceinline__ unsigned short f2bf(float f) {
    unsigned u = __float_as_uint(f);
    unsigned r = 0x7fffu + ((u >> 16) & 1u);   // round-to-nearest-even
    return (unsigned short)((u + r) >> 16);
}

// ---------------- fused weight prep: all transposed bf16 weights in one kernel ----------------
// arena (u16): [0)=inWt[128][256]  [32768)=qkv0t[384][128]  [81920)=r0t[128][128]
//              [98304)=qkv1t[4][384][128]  [294912)=r1t[64][128]  total 303104
__global__ void prep_k(const float* __restrict__ inW,
                       const float* __restrict__ q0W, const float* __restrict__ k0W,
                       const float* __restrict__ v0W, const float* __restrict__ r0W,
                       const float* __restrict__ q1W, const float* __restrict__ k1W,
                       const float* __restrict__ v1W, const float* __restrict__ r1W,
                       u16* __restrict__ arena) {
    int i = blockIdx.x * 256 + threadIdx.x;
    if (i >= 303104) return;
    float val;
    if (i < 32768) {                       // inWt[n][k] = inW[k][n], K=256, N=128
        int n = i >> 8, k = i & 255;
        val = inW[k * 128 + n];
    } else if (i < 81920) {                // qkv0t
        int j = i - 32768;
        int r = j >> 7, kk = j & 127;
        int sec = r >> 7, c = r & 127;
        const float* s = (sec == 0) ? q0W : (sec == 1) ? k0W : v0W;
        val = s[kk * 128 + c];
    } else if (i < 98304) {                // r0t
        int j = i - 81920;
        int r = j >> 7, kk = j & 127;
        val = r0W[kk * 128 + r];
    } else if (i < 294912) {               // qkv1t[p][384][128]
        int j = i - 98304;
        int row = j >> 7, kk = j & 127;
        int p = row / 384, rr = row - p * 384;
        int sec = rr >> 7, c = p * 128 + (rr & 127);
        const float* s = (sec == 0) ? q1W : (sec == 1) ? k1W : v1W;
        val = s[kk * 512 + c];
    } else {                               // r1t[64][128]
        int j = i - 294912;
        int n = j >> 7, kk = j & 127;
        val = r1W[kk * 64 + n];
    }
    arena[i] = f2bf(val);
}

// fused biases: qkv0b[384] then qkv1b[4*384]
__global__ void bias_k(const float* __restrict__ q0b, const float* __restrict__ k0b,
                       const float* __restrict__ v0b,
                       const float* __restrict__ q1b, const float* __restrict__ k1b,
                       const float* __restrict__ v1b, float* __restrict__ out) {
    int i = blockIdx.x * 256 + threadIdx.x;
    if (i >= 1920) return;
    if (i < 384) {
        int sec = i >> 7, c = i & 127;
        out[i] = (sec == 0) ? q0b[c] : (sec == 1) ? k0b[c] : v0b[c];
    } else {
        int j = i - 384;
        int p = j / 384, rr = j - p * 384;
        int sec = rr >> 7, c = p * 128 + (rr & 127);
        out[i] = (sec == 0) ? q1b[c] : (sec == 1) ? k1b[c] : v1b[c];
    }
}

// ---------------- MFMA GEMM v6: NO LDS, direct global->VGPR fragments ----------------
// C[M, NT*128] = A[M,K] @ Bt[NT*128, K]^T + bias. One block = 128 rows x full N.
// 256 thr = 4 waves (2x2 of 64x64). Each A/B byte is consumed by exactly one
// lane, so registers replace LDS: zero barriers, pure streaming.
// AF32: A is f32, converted in-register with f2bf (bit-identical to cvt_k path).
template <bool OUTBF16, int K, int NT, bool AF32>
__global__ __launch_bounds__(256) void mgemm6(const void* __restrict__ Av,
                                              const u16* __restrict__ Bt,
                                              const float* __restrict__ bias,
                                              void* __restrict__ C,
                                              int M, int Nvalid, int ldc) {
    const int bm = blockIdx.x * 128;
    const int t = threadIdx.x, lane = t & 63, wid = t >> 6;
    const int wm = (wid >> 1) * 64, wn = (wid & 1) * 64;
    const int fl = lane & 15, fh = lane >> 4;
    constexpr int KB = K / 128;            // 1 or 2
    // A row indices (clamped; epilogue guards)
    int ra[4];
#pragma unroll
    for (int mi = 0; mi < 4; ++mi) {
        ra[mi] = bm + wm + mi * 16 + fl;
        if (ra[mi] >= M) ra[mi] = 0;
    }
    // For K=128 the A fragments are loaded once and reused across all NT col-tiles.
    short8v afh[4][4];
    if (KB == 1) {
#pragma unroll
        for (int mi = 0; mi < 4; ++mi) {
            const u16* ap = (const u16*)Av + (size_t)ra[mi] * K + fh * 8;
#pragma unroll
            for (int ks = 0; ks < 4; ++ks)
                afh[mi][ks] = *(const short8v*)(ap + ks * 32);
        }
    }
#pragma unroll
    for (int nit = 0; nit < NT; ++nit) {
        f32x4 acc[4][4] = {};
#pragma unroll
        for (int kb = 0; kb < KB; ++kb) {
            short8v af[4][4];
            if (KB == 1) {
#pragma unroll
                for (int mi = 0; mi < 4; ++mi)
#pragma unroll
                    for (int ks = 0; ks < 4; ++ks) af[mi][ks] = afh[mi][ks];
            } else if (AF32) {
#pragma unroll
                for (int mi = 0; mi < 4; ++mi) {
                    const float* ap = (const float*)Av + (size_t)ra[mi] * K + kb * 128 + fh * 8;
#pragma unroll
                    for (int ks = 0; ks < 4; ++ks) {
                        float4 a = *(const float4*)(ap + ks * 32);
                        float4 b = *(const float4*)(ap + ks * 32 + 4);
                        ushort8 u = {f2bf(a.x), f2bf(a.y), f2bf(a.z), f2bf(a.w),
                                     f2bf(b.x), f2bf(b.y), f2bf(b.z), f2bf(b.w)};
                        af[mi][ks] = (short8v)u;
                    }
                }
            } else {
#pragma unroll
                for (int mi = 0; mi < 4; ++mi) {
                    const u16* ap = (const u16*)Av + (size_t)ra[mi] * K + kb * 128 + fh * 8;
#pragma unroll
                    for (int ks = 0; ks < 4; ++ks)
                        af[mi][ks] = *(const short8v*)(ap + ks * 32);
                }
            }
#pragma unroll
            for (int ks = 0; ks < 4; ++ks) {
                short8v bfr[4];
#pragma unroll
                for (int ni = 0; ni < 4; ++ni) {
                    int rb = nit * 128 + wn + ni * 16 + fl;
                    if (rb >= Nvalid) rb = 0;
                    bfr[ni] = *(const short8v*)(Bt + (size_t)rb * K + kb * 128 +
                                                ks * 32 + fh * 8);
                }
#pragma unroll
                for (int mi = 0; mi < 4; ++mi)
#pragma unroll
                    for (int ni = 0; ni < 4; ++ni)
                        acc[mi][ni] = __builtin_amdgcn_mfma_f32_16x16x32_bf16(
                            af[mi][ks], bfr[ni], acc[mi][ni], 0, 0, 0);
            }
        }
        // epilogue: C/D frag layout col=lane&15, row=(lane>>4)*4+j
#pragma unroll
        for (int ni = 0; ni < 4; ++ni) {
            int ccol = nit * 128 + wn + ni * 16 + fl;
            if (ccol >= Nvalid) continue;
            float bs = bias[ccol];
#pragma unroll
            for (int mi = 0; mi < 4; ++mi) {
#pragma unroll
                for (int j = 0; j < 4; ++j) {
                    int crow = bm + wm + mi * 16 + fh * 4 + j;
                    if (crow >= M) continue;
                    float val = acc[mi][ni][j] + bs;
                    if (OUTBF16) ((u16*)C)[(size_t)crow * ldc + ccol] = f2bf(val);
                    else         ((float*)C)[(size_t)crow * ldc + ccol] = val;
                }
            }
        }
    }
}

// ---------------- CSR build ----------------
__global__ void zero2_k(int* __restrict__ a, int* __restrict__ b, int n) {
    int i = blockIdx.x * 256 + threadIdx.x;
    if (i < n) { a[i] = 0; b[i] = 0; }
}

__global__ void hist_k(const int* __restrict__ dst, int* __restrict__ cnt, int E) {
    int i = blockIdx.x * 256 + threadIdx.x;
    if (i < E) atomicAdd(&cnt[dst[i]], 1);
}

__global__ void blocksum_k(const int* __restrict__ cnt, int* __restrict__ bsum, int n) {
    __shared__ int sd[256];
    int i = blockIdx.x * 256 + threadIdx.x;
    sd[threadIdx.x] = (i < n) ? cnt[i] : 0;
    __syncthreads();
    for (int off = 128; off > 0; off >>= 1) {
        if (threadIdx.x < off) sd[threadIdx.x] += sd[threadIdx.x + off];
        __syncthreads();
    }
    if (threadIdx.x == 0) bsum[blockIdx.x] = sd[0];
}

__global__ void scanb_k(int* bsum, int nb) {
    __shared__ int tmp[512];
    int t = threadIdx.x;
    tmp[t] = (t < nb) ? bsum[t] : 0;
    __syncthreads();
    for (int off = 1; off < 512; off <<= 1) {
        int v = (t >= off) ? tmp[t - off] : 0;
        __syncthreads();
        tmp[t] += v;
        __syncthreads();
    }
    if (t < nb) bsum[t] = (t ? tmp[t - 1] : 0);
}

__global__ void scanc_k(const int* __restrict__ cnt, const int* __restrict__ bsum,
                        int* __restrict__ row_off, int n, int E) {
    __shared__ int tmp[256];
    int b = blockIdx.x, t = threadIdx.x;
    int i = b * 256 + t;
    int own = (i < n) ? cnt[i] : 0;
    tmp[t] = own;
    __syncthreads();
    for (int off = 1; off < 256; off <<= 1) {
        int v = (t >= off) ? tmp[t - off] : 0;
        __syncthreads();
        tmp[t] += v;
        __syncthreads();
    }
    if (i < n) row_off[i] = bsum[b] + tmp[t] - own;
    if (b == 0 && t == 0) row_off[n] = E;
}

__global__ void scatter_k(const int* __restrict__ src, const int* __restrict__ dst,
                          const int* __restrict__ row_off, int* __restrict__ cur,
                          int* __restrict__ csr_src, int E) {
    int i = blockIdx.x * 256 + threadIdx.x;
    if (i < E) {
        int d = dst[i];
        int pos = row_off[d] + atomicAdd(&cur[d], 1);
        csr_src[pos] = src[i];
    }
}

// ---------------- attention layer 0: 8 heads x d=16, F=128, concat ----------------
// q/k/v at row stride 384 (fused buffer). lane l: feats 2l,2l+1; 8-lane reduce. Unroll 4.
__global__ __launch_bounds__(256) void attn0_k(const u16* __restrict__ q, const u16* __restrict__ k,
                                               const u16* __restrict__ v,
                                               const int* __restrict__ row_off,
                                               const int* __restrict__ csr,
                                               float* __restrict__ out, int n) {
    int w = (blockIdx.x * 256 + threadIdx.x) >> 6;
    int lane = threadIdx.x & 63;
    if (w >= n) return;
    int beg = row_off[w], end = row_off[w + 1];
    unsigned kv = *(const unsigned*)(k + (size_t)w * 384 + 2 * lane);
    float k0f = bf2f((u16)kv) * 0.25f, k1f = bf2f((u16)(kv >> 16)) * 0.25f;  // fold 1/sqrt(16)
    float den = 0.f, num0 = 0.f, num1 = 0.f;
    int e = beg;
    for (; e + 4 <= end; e += 4) {
        int s0 = csr[e], s1 = csr[e + 1], s2 = csr[e + 2], s3 = csr[e + 3];
        unsigned qa = *(const unsigned*)(q + (size_t)s0 * 384 + 2 * lane);
        unsigned qb = *(const unsigned*)(q + (size_t)s1 * 384 + 2 * lane);
        unsigned qc = *(const unsigned*)(q + (size_t)s2 * 384 + 2 * lane);
        unsigned qd = *(const unsigned*)(q + (size_t)s3 * 384 + 2 * lane);
        unsigned va = *(const unsigned*)(v + (size_t)s0 * 384 + 2 * lane);
        unsigned vb = *(const unsigned*)(v + (size_t)s1 * 384 + 2 * lane);
        unsigned vc = *(const unsigned*)(v + (size_t)s2 * 384 + 2 * lane);
        unsigned vd = *(const unsigned*)(v + (size_t)s3 * 384 + 2 * lane);
        float pa = bf2f((u16)qa) * k0f + bf2f((u16)(qa >> 16)) * k1f;
        float pb = bf2f((u16)qb) * k0f + bf2f((u16)(qb >> 16)) * k1f;
        float pc = bf2f((u16)qc) * k0f + bf2f((u16)(qc >> 16)) * k1f;
        float pd = bf2f((u16)qd) * k0f + bf2f((u16)(qd >> 16)) * k1f;
#pragma unroll
        for (int off = 1; off < 8; off <<= 1) {
            pa += __shfl_xor(pa, off); pb += __shfl_xor(pb, off);
            pc += __shfl_xor(pc, off); pd += __shfl_xor(pd, off);
        }
        float wa = __expf(pa), wb = __expf(pb);
        float wc = __expf(pc), wd = __expf(pd);
        den += (wa + wb) + (wc + wd);
        num0 = fmaf(wa, bf2f((u16)va), num0);
        num1 = fmaf(wa, bf2f((u16)(va >> 16)), num1);
        num0 = fmaf(wb, bf2f((u16)vb), num0);
        num1 = fmaf(wb, bf2f((u16)(vb >> 16)), num1);
        num0 = fmaf(wc, bf2f((u16)vc), num0);
        num1 = fmaf(wc, bf2f((u16)(vc >> 16)), num1);
        num0 = fmaf(wd, bf2f((u16)vd), num0);
        num1 = fmaf(wd, bf2f((u16)(vd >> 16)), num1);
    }
    for (; e < end; ++e) {
        int s = csr[e];
        unsigned qv = *(const unsigned*)(q + (size_t)s * 384 + 2 * lane);
        float p = bf2f((u16)qv) * k0f + bf2f((u16)(qv >> 16)) * k1f;
        p += __shfl_xor(p, 1);
        p += __shfl_xor(p, 2);
        p += __shfl_xor(p, 4);
        float wt = __expf(p);
        den += wt;
        unsigned vv = *(const unsigned*)(v + (size_t)s * 384 + 2 * lane);
        num0 = fmaf(wt, bf2f((u16)vv), num0);
        num1 = fmaf(wt, bf2f((u16)(vv >> 16)), num1);
    }
    float inv = (end > beg) ? 1.f / den : 0.f;
    *(float2*)(out + ((size_t)w << 7) + 2 * lane) = make_float2(num0 * inv, num1 * inv);
}

// ---------------- attention layer 1 (one 2-head pass): d=64, accumulate mean ----------------
template <bool FIRST>
__global__ __launch_bounds__(256) void attn1_k(const u16* __restrict__ q, const u16* __restrict__ k,
                                               const u16* __restrict__ v,
                                               const int* __restrict__ row_off,
                                               const int* __restrict__ csr,
                                               float* __restrict__ out, int n) {
    int w = (blockIdx.x * 256 + threadIdx.x) >> 6;
    int lane = threadIdx.x & 63;
    if (w >= n) return;
    int beg = row_off[w], end = row_off[w + 1];
    unsigned kv = *(const unsigned*)(k + (size_t)w * 384 + 2 * lane);
    float k0f = bf2f((u16)kv) * 0.125f, k1f = bf2f((u16)(kv >> 16)) * 0.125f;  // fold 1/sqrt(64)
    float den = 0.f, num0 = 0.f, num1 = 0.f;
    int e = beg;
    for (; e + 4 <= end; e += 4) {
        int s0 = csr[e], s1 = csr[e + 1], s2 = csr[e + 2], s3 = csr[e + 3];
        unsigned qa = *(const unsigned*)(q + (size_t)s0 * 384 + 2 * lane);
        unsigned qb = *(const unsigned*)(q + (size_t)s1 * 384 + 2 * lane);
        unsigned qc = *(const unsigned*)(q + (size_t)s2 * 384 + 2 * lane);
        unsigned qd = *(const unsigned*)(q + (size_t)s3 * 384 + 2 * lane);
        unsigned va = *(const unsigned*)(v + (size_t)s0 * 384 + 2 * lane);
        unsigned vb = *(const unsigned*)(v + (size_t)s1 * 384 + 2 * lane);
        unsigned vc = *(const unsigned*)(v + (size_t)s2 * 384 + 2 * lane);
        unsigned vd = *(const unsigned*)(v + (size_t)s3 * 384 + 2 * lane);
        float pa = bf2f((u16)qa) * k0f + bf2f((u16)(qa >> 16)) * k1f;
        float pb = bf2f((u16)qb) * k0f + bf2f((u16)(qb >> 16)) * k1f;
        float pc = bf2f((u16)qc) * k0f + bf2f((u16)(qc >> 16)) * k1f;
        float pd = bf2f((u16)qd) * k0f + bf2f((u16)(qd >> 16)) * k1f;
#pragma unroll
        for (int off = 1; off < 32; off <<= 1) {
            pa += __shfl_xor(pa, off); pb += __shfl_xor(pb, off);
            pc += __shfl_xor(pc, off); pd += __shfl_xor(pd, off);
        }
        float wa = __expf(pa), wb = __expf(pb);
        float wc = __expf(pc), wd = __expf(pd);
        den += (wa + wb) + (wc + wd);
        num0 = fmaf(wa, bf2f((u16)va), num0);
        num1 = fmaf(wa, bf2f((u16)(va >> 16)), num1);
        num0 = fmaf(wb, bf2f((u16)vb), num0);
        num1 = fmaf(wb, bf2f((u16)(vb >> 16)), num1);
        num0 = fmaf(wc, bf2f((u16)vc), num0);
        num1 = fmaf(wc, bf2f((u16)(vc >> 16)), num1);
        num0 = fmaf(wd, bf2f((u16)vd), num0);
        num1 = fmaf(wd, bf2f((u16)(vd >> 16)), num1);
    }
    for (; e < end; ++e) {
        int s = csr[e];
        unsigned qv = *(const unsigned*)(q + (size_t)s * 384 + 2 * lane);
        float p = bf2f((u16)qv) * k0f + bf2f((u16)(qv >> 16)) * k1f;
#pragma unroll
        for (int off = 1; off < 32; off <<= 1) p += __shfl_xor(p, off);
        float wt = __expf(p);
        den += wt;
        unsigned vv = *(const unsigned*)(v + (size_t)s * 384 + 2 * lane);
        num0 = fmaf(wt, bf2f((u16)vv), num0);
        num1 = fmaf(wt, bf2f((u16)(vv >> 16)), num1);
    }
    float inv = (end > beg) ? 1.f / den : 0.f;
    float o0 = num0 * inv, o1 = num1 * inv;
    o0 += __shfl_xor(o0, 32);   // combine the two heads (same output dim)
    o1 += __shfl_xor(o1, 32);
    if (lane < 32) {
        float2* op = (float2*)(out + ((size_t)w << 6) + 2 * lane);
        if (FIRST) {
            *op = make_float2(o0 * 0.125f, o1 * 0.125f);
        } else {
            float2 tv = *op;
            tv.x += o0 * 0.125f; tv.y += o1 * 0.125f;
            *op = tv;
        }
    }
}

// ---------------- gated residual + LN + relu (layer 0), bf16 h1 out ----------------
__global__ __launch_bounds__(256) void gres0_k(const float* __restrict__ x, const float* __restrict__ res,
                                               const float* __restrict__ gw,
                                               const float* __restrict__ lng, const float* __restrict__ lnb,
                                               u16* __restrict__ h1, int n) {
    int w = (blockIdx.x * 256 + threadIdx.x) >> 6;
    int lane = threadIdx.x & 63;
    if (w >= n) return;
    size_t base = (size_t)w * 128;
    float x1 = x[base + lane], x2 = x[base + lane + 64];
    float r1 = res[base + lane], r2 = res[base + lane + 64];
    float ca1 = gw[lane] + gw[256 + lane];
    float ca2 = gw[lane + 64] + gw[256 + lane + 64];
    float cr1 = gw[128 + lane] - gw[256 + lane];
    float cr2 = gw[128 + lane + 64] - gw[256 + lane + 64];
    float dot = x1 * ca1 + x2 * ca2 + r1 * cr1 + r2 * cr2;
#pragma unroll
    for (int off = 1; off < 64; off <<= 1) dot += __shfl_xor(dot, off);
    float g = 1.f / (1.f + __expf(-dot));
    float o1 = x1 * g + r1 * (1.f - g);
    float o2 = x2 * g + r2 * (1.f - g);
    float s = o1 + o2;
#pragma unroll
    for (int off = 1; off < 64; off <<= 1) s += __shfl_xor(s, off);
    float mu = s * (1.f / 128.f);
    float d1 = o1 - mu, d2 = o2 - mu;
    float vs = d1 * d1 + d2 * d2;
#pragma unroll
    for (int off = 1; off < 64; off <<= 1) vs += __shfl_xor(vs, off);
    float rstd = rsqrtf(vs * (1.f / 128.f) + 1e-5f);
    float y1 = d1 * rstd * lng[lane] + lnb[lane];
    float y2 = d2 * rstd * lng[lane + 64] + lnb[lane + 64];
    h1[base + lane] = f2bf(fmaxf(y1, 0.f));
    h1[base + lane + 64] = f2bf(fmaxf(y2, 0.f));
}

// ---------------- gated residual only (layer 1, d=64) ----------------
__global__ __launch_bounds__(256) void gres1_k(const float* __restrict__ x, const float* __restrict__ res,
                                               const float* __restrict__ gw,
                                               float* __restrict__ out, int n) {
    int w = (blockIdx.x * 256 + threadIdx.x) >> 6;
    int lane = threadIdx.x & 63;
    if (w >= n) return;
    size_t base = (size_t)w * 64;
    float xv = x[base + lane];
    float rv = res[base + lane];
    float ca = gw[lane] + gw[128 + lane];
    float cr = gw[64 + lane] - gw[128 + lane];
    float dot = xv * ca + rv * cr;
#pragma unroll
    for (int off = 1; off < 64; off <<= 1) dot += __shfl_xor(dot, off);
    float g = 1.f / (1.f + __expf(-dot));
    out[base + lane] = xv * g + rv * (1.f - g);
}

extern "C" void kernel_launch(void* const* d_in, const int* in_sizes, int n_in,
                              void* d_out, int out_size, void* d_ws, size_t ws_size,
                              hipStream_t stream) {
    const float* x    = (const float*)d_in[0];
    const int*   src  = (const int*)d_in[1];
    const int*   dst  = (const int*)d_in[2];
    const float* in_W = (const float*)d_in[3];
    const float* in_b = (const float*)d_in[4];
    const float* q0W = (const float*)d_in[5];  const float* q0b = (const float*)d_in[6];
    const float* k0W = (const float*)d_in[7];  const float* k0b = (const float*)d_in[8];
    const float* v0W = (const float*)d_in[9];  const float* v0b = (const float*)d_in[10];
    const float* r0W = (const float*)d_in[11]; const float* r0b = (const float*)d_in[12];
    const float* g0W = (const float*)d_in[13];
    const float* ln0g = (const float*)d_in[14]; const float* ln0b = (const float*)d_in[15];
    const float* q1W = (const float*)d_in[16]; const float* q1b = (const float*)d_in[17];
    const float* k1W = (const float*)d_in[18]; const float* k1b = (const float*)d_in[19];
    const float* v1W = (const float*)d_in[20]; const float* v1b = (const float*)d_in[21];
    const float* r1W = (const float*)d_in[22]; const float* r1b = (const float*)d_in[23];
    const float* g1W = (const float*)d_in[24];

    const int N = in_sizes[0] / 256;   // 100000
    const int E = in_sizes[1];         // 1600000
    (void)ws_size; (void)n_in; (void)out_size;

    // ---- workspace layout with reuse: peak ~186 MB ----
    auto rnd = [](size_t b) { return (b + 255) & ~(size_t)255; };
    char* base = (char*)d_ws;
    const size_t S_bf = rnd((size_t)N * 128 * 2);   // 25.6 MB
    const size_t S_f  = rnd((size_t)N * 128 * 4);   // 51.2 MB
    size_t o = 0;
    int* row_off = (int*)(base + o); o += rnd(((size_t)N + 1) * 4);
    int* csr     = (int*)(base + o); o += rnd((size_t)E * 4);
    u16* warena  = (u16*)(base + o); o += rnd((size_t)303104 * 2);
    float* barena = (float*)(base + o); o += rnd((size_t)1920 * 4);
    const size_t R0 = o;                 // 51.2: cnt/cur/bsum -> h -> a0 -> {res1o, a1}
    const size_t R1 = R0 + S_f;          // 76.8: QKV0 -> h1 (+ PASS tail)
    const size_t R2 = R1 + 3 * S_bf;     // 51.2: res0o -> (PASS tail)
    int* cnt  = (int*)(base + R0);
    int* cur  = (int*)(base + R0 + rnd((size_t)N * 4));
    int* bsum = (int*)(base + R0 + 2 * rnd((size_t)N * 4));
    u16*   h     = (u16*)(base + R0);
    float* a0    = (float*)(base + R0);
    float* res1o = (float*)(base + R0);
    float* a1    = (float*)(base + R0 + rnd((size_t)N * 64 * 4));
    u16* QKV0 = (u16*)(base + R1);                 // N x 384 bf16
    u16* h1   = (u16*)(base + R1);                 // N x 128 bf16 (overlays QKV0, dead after attn0)
    u16* PASS = (u16*)(base + R1 + S_bf);          // N x 384 bf16, spans R1 slots 1-2 + R2 head
    float* res0o = (float*)(base + R2);            // dead after gres0 (before PASS written)

    // weight arena sections
    u16* inWt  = warena;
    u16* qkv0t = warena + 32768;
    u16* r0t   = warena + 81920;
    u16* qkv1t = warena + 98304;
    u16* r1t   = warena + 294912;
    float* qkv0b = barena;
    float* qkv1b = barena + 384;

    dim3 blk(256);
    int nwb = (N * 64 + 255) / 256;   // one wave per node
    int nb  = (N + 255) / 256;        // 391 (<= 512)
    int mb  = (N + 127) / 128;        // 782

    // ---- prep (weights/bias) ----
    prep_k<<<(303104 + 255) / 256, blk, 0, stream>>>(in_W, q0W, k0W, v0W, r0W,
                                                     q1W, k1W, v1W, r1W, warena);
    bias_k<<<8, blk, 0, stream>>>(q0b, k0b, v0b, q1b, k1b, v1b, barena);

    // ---- CSR build ----
    zero2_k<<<nb, blk, 0, stream>>>(cnt, cur, N);
    hist_k<<<(E + 255) / 256, blk, 0, stream>>>(dst, cnt, E);
    blocksum_k<<<nb, blk, 0, stream>>>(cnt, bsum, N);
    scanb_k<<<1, 512, 0, stream>>>(bsum, nb);
    scanc_k<<<nb, blk, 0, stream>>>(cnt, bsum, row_off, N, E);
    scatter_k<<<(E + 255) / 256, blk, 0, stream>>>(src, dst, row_off, cur, csr, E);

    // ---- layer 0 ----
    mgemm6<true, 256, 1, true><<<mb, blk, 0, stream>>>(x, inWt, in_b, h, N, 128, 128);
    mgemm6<true, 128, 3, false><<<mb, blk, 0, stream>>>(h, qkv0t, qkv0b, QKV0, N, 384, 384);
    mgemm6<false, 128, 1, false><<<mb, blk, 0, stream>>>(h, r0t, r0b, res0o, N, 128, 128);

    attn0_k<<<nwb, blk, 0, stream>>>(QKV0, QKV0 + 128, QKV0 + 256, row_off, csr, a0, N);
    gres0_k<<<nwb, blk, 0, stream>>>(a0, res0o, g0W, ln0g, ln0b, h1, N);

    // ---- layer 1: res path, then 4 passes of 2 heads each ----
    mgemm6<false, 128, 1, false><<<mb, blk, 0, stream>>>(h1, r1t, r1b, res1o, N, 64, 64);

    for (int p = 0; p < 4; ++p) {
        mgemm6<true, 128, 3, false><<<mb, blk, 0, stream>>>(
            h1, qkv1t + (size_t)p * 384 * 128, qkv1b + p * 384, PASS, N, 384, 384);
        if (p == 0) attn1_k<true><<<nwb, blk, 0, stream>>>(PASS, PASS + 128, PASS + 256,
                                                           row_off, csr, a1, N);
        else        attn1_k<false><<<nwb, blk, 0, stream>>>(PASS, PASS + 128, PASS + 256,
                                                            row_off, csr, a1, N);
    }

    gres1_k<<<nwb, blk, 0, stream>>>(a1, res1o, g1W, (float*)d_out, N);
}

// Round 11
// 1178.479 us; speedup vs baseline: 1.1277x; 1.1277x over previous
//
#include <hip/hip_runtime.h>

// GraphTransformerModel: 2-layer graph attention network.
// CSR build -> bf16 MFMA GEMMs (mgemm3, global_load_lds + XOR swizzle) -> attn0
// -> gres0+LN -> 4x {qkv1 GEMM (q/v fp8-e4m3 x16, k bf16; fused 512B rows)
// -> attn1 fp8-gather} -> gres1.  Peak workspace ~186 MB.

typedef unsigned short u16;
typedef __attribute__((ext_vector_type(8))) unsigned short ushort8;
typedef __attribute__((ext_vector_type(8))) short short8v;   // 8 bf16 (4 VGPRs)
typedef __attribute__((ext_vector_type(4))) float f32x4;
typedef __attribute__((ext_vector_type(2))) float f32x2;

__device__ __forceinline__ float bf2f(unsigned short u) {
    return __uint_as_float(((unsigned)u) << 16);
}
__device__ __forceinline__ unsigned short f2bf(float f) {
    unsigned u = __float_as_uint(f);
    unsigned r = 0x7fffu + ((u >> 16) & 1u);   // round-to-nearest-even
    return (unsigned short)((u + r) >> 16);
}
__device__ __forceinline__ unsigned char f2fp8(float f) {   // HW e4m3 encode
    return (unsigned char)__builtin_amdgcn_cvt_pk_fp8_f32(f, 0.f, 0, false);
}

// async global->LDS, 16B per lane; dest is wave-uniform base + lane*16 (HW).
__device__ __forceinline__ void gload16(const void* gp, const void* lp) {
    __builtin_amdgcn_global_load_lds(
        (const __attribute__((address_space(1))) unsigned*)(uintptr_t)gp,
        (__attribute__((address_space(3))) unsigned*)(unsigned)(uintptr_t)lp,
        16, 0, 0);
}

// ---------------- fused weight prep: all transposed bf16 weights in one kernel ----------------
// arena (u16): [0)=inWt[128][256]  [32768)=qkv0t[384][128]  [81920)=r0t[128][128]
//              [98304)=qkv1t[4][384][128]  [294912)=r1t[64][128]  total 303104
__global__ void prep_k(const float* __restrict__ inW,
                       const float* __restrict__ q0W, const float* __restrict__ k0W,
                       const float* __restrict__ v0W, const float* __restrict__ r0W,
                       const float* __restrict__ q1W, const float* __restrict__ k1W,
                       const float* __restrict__ v1W, const float* __restrict__ r1W,
                       u16* __restrict__ arena) {
    int i = blockIdx.x * 256 + threadIdx.x;
    if (i >= 303104) return;
    float val;
    if (i < 32768) {                       // inWt[n][k] = inW[k][n], K=256, N=128
        int n = i >> 8, k = i & 255;
        val = inW[k * 128 + n];
    } else if (i < 81920) {                // qkv0t
        int j = i - 32768;
        int r = j >> 7, kk = j & 127;
        int sec = r >> 7, c = r & 127;
        const float* s = (sec == 0) ? q0W : (sec == 1) ? k0W : v0W;
        val = s[kk * 128 + c];
    } else if (i < 98304) {                // r0t
        int j = i - 81920;
        int r = j >> 7, kk = j & 127;
        val = r0W[kk * 128 + r];
    } else if (i < 294912) {               // qkv1t[p][384][128]
        int j = i - 98304;
        int row = j >> 7, kk = j & 127;
        int p = row / 384, rr = row - p * 384;
        int sec = rr >> 7, c = p * 128 + (rr & 127);
        const float* s = (sec == 0) ? q1W : (sec == 1) ? k1W : v1W;
        val = s[kk * 512 + c];
    } else {                               // r1t[64][128]
        int j = i - 294912;
        int n = j >> 7, kk = j & 127;
        val = r1W[kk * 64 + n];
    }
    arena[i] = f2bf(val);
}

// fused biases: qkv0b[384] then qkv1b[4*384]
__global__ void bias_k(const float* __restrict__ q0b, const float* __restrict__ k0b,
                       const float* __restrict__ v0b,
                       const float* __restrict__ q1b, const float* __restrict__ k1b,
                       const float* __restrict__ v1b, float* __restrict__ out) {
    int i = blockIdx.x * 256 + threadIdx.x;
    if (i >= 1920) return;
    if (i < 384) {
        int sec = i >> 7, c = i & 127;
        out[i] = (sec == 0) ? q0b[c] : (sec == 1) ? k0b[c] : v0b[c];
    } else {
        int j = i - 384;
        int p = j / 384, rr = j - p * 384;
        int sec = rr >> 7, c = p * 128 + (rr & 127);
        out[i] = (sec == 0) ? q1b[c] : (sec == 1) ? k1b[c] : v1b[c];
    }
}

// ---------------- f32 -> bf16 convert (8 elems/thread) ----------------
__global__ void cvt_k(const float* __restrict__ in, u16* __restrict__ out, int n8) {
    int i = blockIdx.x * 256 + threadIdx.x;
    if (i >= n8) return;
    float4 a = *(const float4*)(in + (size_t)i * 8);
    float4 b = *(const float4*)(in + (size_t)i * 8 + 4);
    ushort8 o = {f2bf(a.x), f2bf(a.y), f2bf(a.z), f2bf(a.w),
                 f2bf(b.x), f2bf(b.y), f2bf(b.z), f2bf(b.w)};
    *(ushort8*)(out + (size_t)i * 8) = o;
}

// ---------------- MFMA GEMM v3: C = A[M,K](bf16) @ Bt[N,K](bf16)^T + bias ----------
// 128x128 tiles, BK=64 chunks via global_load_lds, XOR-swizzled LDS.
// OUTMODE: 0 = f32, 1 = bf16, 2 = fused qkv1 512B rows (q fp8x16 | k bf16 | v fp8x16).
template <int OUTMODE, int K>
__global__ __launch_bounds__(256) void mgemm3(const u16* __restrict__ A,
                                              const u16* __restrict__ Bt,
                                              const float* __restrict__ bias,
                                              void* __restrict__ C,
                                              int M, int Nvalid, int ldc) {
    __shared__ __align__(16) u16 As[128 * 64];
    __shared__ __align__(16) u16 Bs[128 * 64];
    const int bm = blockIdx.x * 128;
    const int bn = blockIdx.y * 128;
    const int t = threadIdx.x, lane = t & 63, wid = t >> 6;
    const int wm = (wid >> 1) * 64, wn = (wid & 1) * 64;
    const int jlog = ((lane & 7) ^ (lane >> 3)) * 8;
    f32x4 acc[4][4] = {};
    for (int k0 = 0; k0 < K; k0 += 64) {
#pragma unroll
        for (int c2 = 0; c2 < 4; ++c2) {
            int seg = c2 * 4 + wid;
            int row = seg * 8 + (lane >> 3);
            int ga = bm + row; if (ga >= M) ga = 0;
            gload16(A + (size_t)ga * K + k0 + jlog, (const char*)As + seg * 1024);
            int gb = bn + row; if (gb >= Nvalid) gb = 0;
            gload16(Bt + (size_t)gb * K + k0 + jlog, (const char*)Bs + seg * 1024);
        }
        __syncthreads();
#pragma unroll
        for (int ks = 0; ks < 2; ++ks) {
            const int jx = ks * 4 + (lane >> 4);
            short8v af[4], bfr[4];
#pragma unroll
            for (int i = 0; i < 4; ++i) {
                int ra = wm + i * 16 + (lane & 15);
                af[i] = *(const short8v*)((const char*)As + ra * 128 + ((jx ^ (ra & 7)) << 4));
                int rb = wn + i * 16 + (lane & 15);
                bfr[i] = *(const short8v*)((const char*)Bs + rb * 128 + ((jx ^ (rb & 7)) << 4));
            }
#pragma unroll
            for (int mi = 0; mi < 4; ++mi)
#pragma unroll
                for (int ni = 0; ni < 4; ++ni)
                    acc[mi][ni] = __builtin_amdgcn_mfma_f32_16x16x32_bf16(
                        af[mi], bfr[ni], acc[mi][ni], 0, 0, 0);
        }
        if (k0 + 64 < K) __syncthreads();
    }
    const int sec = blockIdx.y;   // for OUTMODE 2
#pragma unroll
    for (int ni = 0; ni < 4; ++ni) {
        int lcol = wn + ni * 16 + (lane & 15);   // 0..127 within section
        int ccol = bn + lcol;
        if (ccol >= Nvalid) continue;
        float bs = bias[ccol];
#pragma unroll
        for (int mi = 0; mi < 4; ++mi) {
#pragma unroll
            for (int j = 0; j < 4; ++j) {
                int crow = bm + wm + mi * 16 + (lane >> 4) * 4 + j;
                if (crow >= M) continue;
                float val = acc[mi][ni][j] + bs;
                if (OUTMODE == 0) {
                    ((float*)C)[(size_t)crow * ldc + ccol] = val;
                } else if (OUTMODE == 1) {
                    ((u16*)C)[(size_t)crow * ldc + ccol] = f2bf(val);
                } else {
                    unsigned char* rowp = (unsigned char*)C + (size_t)crow * 512;
                    if (sec == 0)      rowp[lcol] = f2fp8(val * 16.f);
                    else if (sec == 1) ((u16*)(rowp + 128))[lcol] = f2bf(val);
                    else               rowp[384 + lcol] = f2fp8(val * 16.f);
                }
            }
        }
    }
}

// ---------------- CSR build ----------------
__global__ void zero2_k(int* __restrict__ a, int* __restrict__ b, int n) {
    int i = blockIdx.x * 256 + threadIdx.x;
    if (i < n) { a[i] = 0; b[i] = 0; }
}

__global__ void hist_k(const int* __restrict__ dst, int* __restrict__ cnt, int E) {
    int i = blockIdx.x * 256 + threadIdx.x;
    if (i < E) atomicAdd(&cnt[dst[i]], 1);
}

__global__ void blocksum_k(const int* __restrict__ cnt, int* __restrict__ bsum, int n) {
    __shared__ int sd[256];
    int i = blockIdx.x * 256 + threadIdx.x;
    sd[threadIdx.x] = (i < n) ? cnt[i] : 0;
    __syncthreads();
    for (int off = 128; off > 0; off >>= 1) {
        if (threadIdx.x < off) sd[threadIdx.x] += sd[threadIdx.x + off];
        __syncthreads();
    }
    if (threadIdx.x == 0) bsum[blockIdx.x] = sd[0];
}

__global__ void scanb_k(int* bsum, int nb) {
    __shared__ int tmp[512];
    int t = threadIdx.x;
    tmp[t] = (t < nb) ? bsum[t] : 0;
    __syncthreads();
    for (int off = 1; off < 512; off <<= 1) {
        int v = (t >= off) ? tmp[t - off] : 0;
        __syncthreads();
        tmp[t] += v;
        __syncthreads();
    }
    if (t < nb) bsum[t] = (t ? tmp[t - 1] : 0);
}

__global__ void scanc_k(const int* __restrict__ cnt, const int* __restrict__ bsum,
                        int* __restrict__ row_off, int n, int E) {
    __shared__ int tmp[256];
    int b = blockIdx.x, t = threadIdx.x;
    int i = b * 256 + t;
    int own = (i < n) ? cnt[i] : 0;
    tmp[t] = own;
    __syncthreads();
    for (int off = 1; off < 256; off <<= 1) {
        int v = (t >= off) ? tmp[t - off] : 0;
        __syncthreads();
        tmp[t] += v;
        __syncthreads();
    }
    if (i < n) row_off[i] = bsum[b] + tmp[t] - own;
    if (b == 0 && t == 0) row_off[n] = E;
}

__global__ void scatter_k(const int* __restrict__ src, const int* __restrict__ dst,
                          const int* __restrict__ row_off, int* __restrict__ cur,
                          int* __restrict__ csr_src, int E) {
    int i = blockIdx.x * 256 + threadIdx.x;
    if (i < E) {
        int d = dst[i];
        int pos = row_off[d] + atomicAdd(&cur[d], 1);
        csr_src[pos] = src[i];
    }
}

// ---------------- attention layer 0: 8 heads x d=16, F=128, concat ----------------
// q/k/v at row stride 384 (fused bf16 buffer). lane l: feats 2l,2l+1; 8-lane reduce.
__global__ __launch_bounds__(256) void attn0_k(const u16* __restrict__ q, const u16* __restrict__ k,
                                               const u16* __restrict__ v,
                                               const int* __restrict__ row_off,
                                               const int* __restrict__ csr,
                                               float* __restrict__ out, int n) {
    int w = (blockIdx.x * 256 + threadIdx.x) >> 6;
    int lane = threadIdx.x & 63;
    if (w >= n) return;
    int beg = row_off[w], end = row_off[w + 1];
    unsigned kv = *(const unsigned*)(k + (size_t)w * 384 + 2 * lane);
    float k0f = bf2f((u16)kv) * 0.25f, k1f = bf2f((u16)(kv >> 16)) * 0.25f;  // fold 1/sqrt(16)
    float den = 0.f, num0 = 0.f, num1 = 0.f;
    int e = beg;
    for (; e + 4 <= end; e += 4) {
        int s0 = csr[e], s1 = csr[e + 1], s2 = csr[e + 2], s3 = csr[e + 3];
        unsigned qa = *(const unsigned*)(q + (size_t)s0 * 384 + 2 * lane);
        unsigned qb = *(const unsigned*)(q + (size_t)s1 * 384 + 2 * lane);
        unsigned qc = *(const unsigned*)(q + (size_t)s2 * 384 + 2 * lane);
        unsigned qd = *(const unsigned*)(q + (size_t)s3 * 384 + 2 * lane);
        unsigned va = *(const unsigned*)(v + (size_t)s0 * 384 + 2 * lane);
        unsigned vb = *(const unsigned*)(v + (size_t)s1 * 384 + 2 * lane);
        unsigned vc = *(const unsigned*)(v + (size_t)s2 * 384 + 2 * lane);
        unsigned vd = *(const unsigned*)(v + (size_t)s3 * 384 + 2 * lane);
        float pa = bf2f((u16)qa) * k0f + bf2f((u16)(qa >> 16)) * k1f;
        float pb = bf2f((u16)qb) * k0f + bf2f((u16)(qb >> 16)) * k1f;
        float pc = bf2f((u16)qc) * k0f + bf2f((u16)(qc >> 16)) * k1f;
        float pd = bf2f((u16)qd) * k0f + bf2f((u16)(qd >> 16)) * k1f;
#pragma unroll
        for (int off = 1; off < 8; off <<= 1) {
            pa += __shfl_xor(pa, off); pb += __shfl_xor(pb, off);
            pc += __shfl_xor(pc, off); pd += __shfl_xor(pd, off);
        }
        float wa = __expf(pa), wb = __expf(pb);
        float wc = __expf(pc), wd = __expf(pd);
        den += (wa + wb) + (wc + wd);
        num0 = fmaf(wa, bf2f((u16)va), num0);
        num1 = fmaf(wa, bf2f((u16)(va >> 16)), num1);
        num0 = fmaf(wb, bf2f((u16)vb), num0);
        num1 = fmaf(wb, bf2f((u16)(vb >> 16)), num1);
        num0 = fmaf(wc, bf2f((u16)vc), num0);
        num1 = fmaf(wc, bf2f((u16)(vc >> 16)), num1);
        num0 = fmaf(wd, bf2f((u16)vd), num0);
        num1 = fmaf(wd, bf2f((u16)(vd >> 16)), num1);
    }
    for (; e < end; ++e) {
        int s = csr[e];
        unsigned qv = *(const unsigned*)(q + (size_t)s * 384 + 2 * lane);
        float p = bf2f((u16)qv) * k0f + bf2f((u16)(qv >> 16)) * k1f;
        p += __shfl_xor(p, 1);
        p += __shfl_xor(p, 2);
        p += __shfl_xor(p, 4);
        float wt = __expf(p);
        den += wt;
        unsigned vv = *(const unsigned*)(v + (size_t)s * 384 + 2 * lane);
        num0 = fmaf(wt, bf2f((u16)vv), num0);
        num1 = fmaf(wt, bf2f((u16)(vv >> 16)), num1);
    }
    float inv = (end > beg) ? 1.f / den : 0.f;
    *(float2*)(out + ((size_t)w << 7) + 2 * lane) = make_float2(num0 * inv, num1 * inv);
}

// ---------------- attention layer 1 (one 2-head pass): fp8 q/v gathers ----------------
// Fused 512B rows: [q fp8(x16) 128B | k bf16 256B | v fp8(x16) 128B].
// lane l: feats 2l,2l+1; 32-lane head groups; HW fp8 decode.
template <bool FIRST>
__global__ __launch_bounds__(256) void attn1_k(const unsigned char* __restrict__ qkv,
                                               const int* __restrict__ row_off,
                                               const int* __restrict__ csr,
                                               float* __restrict__ out, int n) {
    int w = (blockIdx.x * 256 + threadIdx.x) >> 6;
    int lane = threadIdx.x & 63;
    if (w >= n) return;
    int beg = row_off[w], end = row_off[w + 1];
    unsigned kv = *(const unsigned*)(qkv + (size_t)w * 512 + 128 + 4 * lane);
    const float KS = 0.125f / 16.f;                       // 1/sqrt(64) / q-scale
    float k0f = bf2f((u16)kv) * KS, k1f = bf2f((u16)(kv >> 16)) * KS;
    float den = 0.f, num0 = 0.f, num1 = 0.f;
    int e = beg;
    for (; e + 4 <= end; e += 4) {
        int s0 = csr[e], s1 = csr[e + 1], s2 = csr[e + 2], s3 = csr[e + 3];
        const unsigned char* r0 = qkv + (size_t)s0 * 512;
        const unsigned char* r1 = qkv + (size_t)s1 * 512;
        const unsigned char* r2 = qkv + (size_t)s2 * 512;
        const unsigned char* r3 = qkv + (size_t)s3 * 512;
        int qa = *(const unsigned short*)(r0 + 2 * lane);
        int qb = *(const unsigned short*)(r1 + 2 * lane);
        int qc = *(const unsigned short*)(r2 + 2 * lane);
        int qd = *(const unsigned short*)(r3 + 2 * lane);
        int va = *(const unsigned short*)(r0 + 384 + 2 * lane);
        int vb = *(const unsigned short*)(r1 + 384 + 2 * lane);
        int vc = *(const unsigned short*)(r2 + 384 + 2 * lane);
        int vd = *(const unsigned short*)(r3 + 384 + 2 * lane);
        f32x2 qaf = __builtin_amdgcn_cvt_pk_f32_fp8(qa, false);
        f32x2 qbf = __builtin_amdgcn_cvt_pk_f32_fp8(qb, false);
        f32x2 qcf = __builtin_amdgcn_cvt_pk_f32_fp8(qc, false);
        f32x2 qdf = __builtin_amdgcn_cvt_pk_f32_fp8(qd, false);
        float pa = qaf.x * k0f + qaf.y * k1f;
        float pb = qbf.x * k0f + qbf.y * k1f;
        float pc = qcf.x * k0f + qcf.y * k1f;
        float pd = qdf.x * k0f + qdf.y * k1f;
#pragma unroll
        for (int off = 1; off < 32; off <<= 1) {
            pa += __shfl_xor(pa, off); pb += __shfl_xor(pb, off);
            pc += __shfl_xor(pc, off); pd += __shfl_xor(pd, off);
        }
        float wa = __expf(pa), wb = __expf(pb);
        float wc = __expf(pc), wd = __expf(pd);
        den += (wa + wb) + (wc + wd);
        f32x2 vaf = __builtin_amdgcn_cvt_pk_f32_fp8(va, false);
        f32x2 vbf = __builtin_amdgcn_cvt_pk_f32_fp8(vb, false);
        f32x2 vcf = __builtin_amdgcn_cvt_pk_f32_fp8(vc, false);
        f32x2 vdf = __builtin_amdgcn_cvt_pk_f32_fp8(vd, false);
        num0 = fmaf(wa, vaf.x, num0); num1 = fmaf(wa, vaf.y, num1);
        num0 = fmaf(wb, vbf.x, num0); num1 = fmaf(wb, vbf.y, num1);
        num0 = fmaf(wc, vcf.x, num0); num1 = fmaf(wc, vcf.y, num1);
        num0 = fmaf(wd, vdf.x, num0); num1 = fmaf(wd, vdf.y, num1);
    }
    for (; e < end; ++e) {
        int s = csr[e];
        const unsigned char* r = qkv + (size_t)s * 512;
        int qv = *(const unsigned short*)(r + 2 * lane);
        f32x2 qf = __builtin_amdgcn_cvt_pk_f32_fp8(qv, false);
        float p = qf.x * k0f + qf.y * k1f;
#pragma unroll
        for (int off = 1; off < 32; off <<= 1) p += __shfl_xor(p, off);
        float wt = __expf(p);
        den += wt;
        int vv = *(const unsigned short*)(r + 384 + 2 * lane);
        f32x2 vf = __builtin_amdgcn_cvt_pk_f32_fp8(vv, false);
        num0 = fmaf(wt, vf.x, num0); num1 = fmaf(wt, vf.y, num1);
    }
    float inv = (end > beg) ? 1.f / den : 0.f;
    float o0 = num0 * inv, o1 = num1 * inv;
    o0 += __shfl_xor(o0, 32);   // combine the two heads (same output dim)
    o1 += __shfl_xor(o1, 32);
    if (lane < 32) {
        const float HS = 0.125f / 16.f;   // head-mean / v-scale
        float2* op = (float2*)(out + ((size_t)w << 6) + 2 * lane);
        if (FIRST) {
            *op = make_float2(o0 * HS, o1 * HS);
        } else {
            float2 tv = *op;
            tv.x += o0 * HS; tv.y += o1 * HS;
            *op = tv;
        }
    }
}

// ---------------- gated residual + LN + relu (layer 0), bf16 h1 out ----------------
__global__ __launch_bounds__(256) void gres0_k(const float* __restrict__ x, const float* __restrict__ res,
                                               const float* __restrict__ gw,
                                               const float* __restrict__ lng, const float* __restrict__ lnb,
                                               u16* __restrict__ h1, int n) {
    int w = (blockIdx.x * 256 + threadIdx.x) >> 6;
    int lane = threadIdx.x & 63;
    if (w >= n) return;
    size_t base = (size_t)w * 128;
    float x1 = x[base + lane], x2 = x[base + lane + 64];
    float r1 = res[base + lane], r2 = res[base + lane + 64];
    float ca1 = gw[lane] + gw[256 + lane];
    float ca2 = gw[lane + 64] + gw[256 + lane + 64];
    float cr1 = gw[128 + lane] - gw[256 + lane];
    float cr2 = gw[128 + lane + 64] - gw[256 + lane + 64];
    float dot = x1 * ca1 + x2 * ca2 + r1 * cr1 + r2 * cr2;
#pragma unroll
    for (int off = 1; off < 64; off <<= 1) dot += __shfl_xor(dot, off);
    float g = 1.f / (1.f + __expf(-dot));
    float o1 = x1 * g + r1 * (1.f - g);
    float o2 = x2 * g + r2 * (1.f - g);
    float s = o1 + o2;
#pragma unroll
    for (int off = 1; off < 64; off <<= 1) s += __shfl_xor(s, off);
    float mu = s * (1.f / 128.f);
    float d1 = o1 - mu, d2 = o2 - mu;
    float vs = d1 * d1 + d2 * d2;
#pragma unroll
    for (int off = 1; off < 64; off <<= 1) vs += __shfl_xor(vs, off);
    float rstd = rsqrtf(vs * (1.f / 128.f) + 1e-5f);
    float y1 = d1 * rstd * lng[lane] + lnb[lane];
    float y2 = d2 * rstd * lng[lane + 64] + lnb[lane + 64];
    h1[base + lane] = f2bf(fmaxf(y1, 0.f));
    h1[base + lane + 64] = f2bf(fmaxf(y2, 0.f));
}

// ---------------- gated residual only (layer 1, d=64) ----------------
__global__ __launch_bounds__(256) void gres1_k(const float* __restrict__ x, const float* __restrict__ res,
                                               const float* __restrict__ gw,
                                               float* __restrict__ out, int n) {
    int w = (blockIdx.x * 256 + threadIdx.x) >> 6;
    int lane = threadIdx.x & 63;
    if (w >= n) return;
    size_t base = (size_t)w * 64;
    float xv = x[base + lane];
    float rv = res[base + lane];
    float ca = gw[lane] + gw[128 + lane];
    float cr = gw[64 + lane] - gw[128 + lane];
    float dot = xv * ca + rv * cr;
#pragma unroll
    for (int off = 1; off < 64; off <<= 1) dot += __shfl_xor(dot, off);
    float g = 1.f / (1.f + __expf(-dot));
    out[base + lane] = xv * g + rv * (1.f - g);
}

extern "C" void kernel_launch(void* const* d_in, const int* in_sizes, int n_in,
                              void* d_out, int out_size, void* d_ws, size_t ws_size,
                              hipStream_t stream) {
    const float* x    = (const float*)d_in[0];
    const int*   src  = (const int*)d_in[1];
    const int*   dst  = (const int*)d_in[2];
    const float* in_W = (const float*)d_in[3];
    const float* in_b = (const float*)d_in[4];
    const float* q0W = (const float*)d_in[5];  const float* q0b = (const float*)d_in[6];
    const float* k0W = (const float*)d_in[7];  const float* k0b = (const float*)d_in[8];
    const float* v0W = (const float*)d_in[9];  const float* v0b = (const float*)d_in[10];
    const float* r0W = (const float*)d_in[11]; const float* r0b = (const float*)d_in[12];
    const float* g0W = (const float*)d_in[13];
    const float* ln0g = (const float*)d_in[14]; const float* ln0b = (const float*)d_in[15];
    const float* q1W = (const float*)d_in[16]; const float* q1b = (const float*)d_in[17];
    const float* k1W = (const float*)d_in[18]; const float* k1b = (const float*)d_in[19];
    const float* v1W = (const float*)d_in[20]; const float* v1b = (const float*)d_in[21];
    const float* r1W = (const float*)d_in[22]; const float* r1b = (const float*)d_in[23];
    const float* g1W = (const float*)d_in[24];

    const int N = in_sizes[0] / 256;   // 100000
    const int E = in_sizes[1];         // 1600000
    (void)ws_size; (void)n_in; (void)out_size;

    // ---- workspace layout with reuse: peak ~186 MB ----
    auto rnd = [](size_t b) { return (b + 255) & ~(size_t)255; };
    char* base = (char*)d_ws;
    const size_t S_bf = rnd((size_t)N * 128 * 2);   // 25.6 MB
    const size_t S_f  = rnd((size_t)N * 128 * 4);   // 51.2 MB
    size_t o = 0;
    int* row_off = (int*)(base + o); o += rnd(((size_t)N + 1) * 4);
    int* csr     = (int*)(base + o); o += rnd((size_t)E * 4);
    u16* warena  = (u16*)(base + o); o += rnd((size_t)303104 * 2);
    float* barena = (float*)(base + o); o += rnd((size_t)1920 * 4);
    const size_t R0 = o;                 // 51.2: cnt/cur/bsum -> h -> a0 -> {res1o, a1}
    const size_t R1 = R0 + S_f;          // 76.8: x_bf -> QKV0 -> h1 (slot0) + PASS (slots 1-2)
    const size_t R2 = R1 + 3 * S_bf;     // 51.2: res0o
    int* cnt  = (int*)(base + R0);
    int* cur  = (int*)(base + R0 + rnd((size_t)N * 4));
    int* bsum = (int*)(base + R0 + 2 * rnd((size_t)N * 4));
    u16*   h     = (u16*)(base + R0);
    float* a0    = (float*)(base + R0);
    float* res1o = (float*)(base + R0);
    float* a1    = (float*)(base + R0 + rnd((size_t)N * 64 * 4));
    u16* x_bf = (u16*)(base + R1);                 // N x 256 bf16, dies after in-GEMM
    u16* QKV0 = (u16*)(base + R1);                 // N x 384 bf16 (overlays x_bf)
    u16* h1   = (u16*)(base + R1);                 // N x 128 bf16 (slot 0, dead after attn0... used after QKV0 dead)
    unsigned char* PASS = (unsigned char*)(base + R1 + S_bf);  // N x 512 B (slots 1-2)
    float* res0o = (float*)(base + R2);

    // weight arena sections
    u16* inWt  = warena;
    u16* qkv0t = warena + 32768;
    u16* r0t   = warena + 81920;
    u16* qkv1t = warena + 98304;
    u16* r1t   = warena + 294912;
    float* qkv0b = barena;
    float* qkv1b = barena + 384;

    dim3 blk(256);
    int nwb = (N * 64 + 255) / 256;   // one wave per node
    int nb  = (N + 255) / 256;        // 391 (<= 512)
    int mb  = (N + 127) / 128;        // 782

    // ---- prep (weights/bias/x convert) ----
    prep_k<<<(303104 + 255) / 256, blk, 0, stream>>>(in_W, q0W, k0W, v0W, r0W,
                                                     q1W, k1W, v1W, r1W, warena);
    bias_k<<<8, blk, 0, stream>>>(q0b, k0b, v0b, q1b, k1b, v1b, barena);
    cvt_k<<<(N * 32 + 255) / 256, blk, 0, stream>>>(x, x_bf, N * 32);

    // ---- CSR build ----
    zero2_k<<<nb, blk, 0, stream>>>(cnt, cur, N);
    hist_k<<<(E + 255) / 256, blk, 0, stream>>>(dst, cnt, E);
    blocksum_k<<<nb, blk, 0, stream>>>(cnt, bsum, N);
    scanb_k<<<1, 512, 0, stream>>>(bsum, nb);
    scanc_k<<<nb, blk, 0, stream>>>(cnt, bsum, row_off, N, E);
    scatter_k<<<(E + 255) / 256, blk, 0, stream>>>(src, dst, row_off, cur, csr, E);

    // ---- layer 0 ----
    mgemm3<1, 256><<<dim3(mb, 1), blk, 0, stream>>>(x_bf, inWt, in_b, h, N, 128, 128);
    mgemm3<1, 128><<<dim3(mb, 3), blk, 0, stream>>>(h, qkv0t, qkv0b, QKV0, N, 384, 384);
    mgemm3<0, 128><<<dim3(mb, 1), blk, 0, stream>>>(h, r0t, r0b, res0o, N, 128, 128);

    attn0_k<<<nwb, blk, 0, stream>>>(QKV0, QKV0 + 128, QKV0 + 256, row_off, csr, a0, N);
    gres0_k<<<nwb, blk, 0, stream>>>(a0, res0o, g0W, ln0g, ln0b, h1, N);

    // ---- layer 1: res path, then 4 passes of 2 heads each ----
    mgemm3<0, 128><<<dim3(mb, 1), blk, 0, stream>>>(h1, r1t, r1b, res1o, N, 64, 64);

    for (int p = 0; p < 4; ++p) {
        mgemm3<2, 128><<<dim3(mb, 3), blk, 0, stream>>>(
            h1, qkv1t + (size_t)p * 384 * 128, qkv1b + p * 384, PASS, N, 384, 0);
        if (p == 0) attn1_k<true><<<nwb, blk, 0, stream>>>(PASS, row_off, csr, a1, N);
        else        attn1_k<false><<<nwb, blk, 0, stream>>>(PASS, row_off, csr, a1, N);
    }

    gres1_k<<<nwb, blk, 0, stream>>>(a1, res1o, g1W, (float*)d_out, N);
}

// Round 12
// 919.701 us; speedup vs baseline: 1.4450x; 1.2814x over previous
//
#include <hip/hip_runtime.h>

// GraphTransformerModel: 2-layer graph attention network.
// CSR build -> bf16 MFMA GEMMs (mgemm3, global_load_lds + XOR swizzle)
// -> attn0 (fp8 q/v, 512B fused rows) -> gres0+LN
// -> 2x {qkv1 4-head GEMM (1024B fused rows) -> attn1 fused 4-head} -> gres1.
// fp8 = e4m3 x16 scale, HW encode/decode. Peak workspace ~186 MB.

typedef unsigned short u16;
typedef __attribute__((ext_vector_type(8))) unsigned short ushort8;
typedef __attribute__((ext_vector_type(8))) short short8v;   // 8 bf16 (4 VGPRs)
typedef __attribute__((ext_vector_type(4))) float f32x4;
typedef __attribute__((ext_vector_type(2))) float f32x2;

__device__ __forceinline__ float bf2f(unsigned short u) {
    return __uint_as_float(((unsigned)u) << 16);
}
__device__ __forceinline__ unsigned short f2bf(float f) {
    unsigned u = __float_as_uint(f);
    unsigned r = 0x7fffu + ((u >> 16) & 1u);   // round-to-nearest-even
    return (unsigned short)((u + r) >> 16);
}
__device__ __forceinline__ unsigned char f2fp8(float f) {   // HW e4m3 encode
    return (unsigned char)__builtin_amdgcn_cvt_pk_fp8_f32(f, 0.f, 0, false);
}

// async global->LDS, 16B per lane; dest is wave-uniform base + lane*16 (HW).
__device__ __forceinline__ void gload16(const void* gp, const void* lp) {
    __builtin_amdgcn_global_load_lds(
        (const __attribute__((address_space(1))) unsigned*)(uintptr_t)gp,
        (__attribute__((address_space(3))) unsigned*)(unsigned)(uintptr_t)lp,
        16, 0, 0);
}

// ---------------- fused weight prep ----------------
// arena (u16): [0)=inWt[128][256]  [32768)=qkv0t[384][128]  [81920)=r0t[128][128]
//              [98304)=qkv1t[2][768][128]  [294912)=r1t[64][128]  total 303104
__global__ void prep_k(const float* __restrict__ inW,
                       const float* __restrict__ q0W, const float* __restrict__ k0W,
                       const float* __restrict__ v0W, const float* __restrict__ r0W,
                       const float* __restrict__ q1W, const float* __restrict__ k1W,
                       const float* __restrict__ v1W, const float* __restrict__ r1W,
                       u16* __restrict__ arena) {
    int i = blockIdx.x * 256 + threadIdx.x;
    if (i >= 303104) return;
    float val;
    if (i < 32768) {                       // inWt[n][k] = inW[k][n], K=256, N=128
        int n = i >> 8, k = i & 255;
        val = inW[k * 128 + n];
    } else if (i < 81920) {                // qkv0t [384][128]
        int j = i - 32768;
        int r = j >> 7, kk = j & 127;
        int sec = r >> 7, c = r & 127;
        const float* s = (sec == 0) ? q0W : (sec == 1) ? k0W : v0W;
        val = s[kk * 128 + c];
    } else if (i < 98304) {                // r0t [128][128]
        int j = i - 81920;
        int r = j >> 7, kk = j & 127;
        val = r0W[kk * 128 + r];
    } else if (i < 294912) {               // qkv1t [2][768][128]: pass p covers cols p*256..+255
        int j = i - 98304;
        int row = j >> 7, kk = j & 127;
        int p = row / 768, rr = row - p * 768;
        int sec = rr >> 8, c = p * 256 + (rr & 255);
        const float* s = (sec == 0) ? q1W : (sec == 1) ? k1W : v1W;
        val = s[kk * 512 + c];
    } else {                               // r1t [64][128]
        int j = i - 294912;
        int n = j >> 7, kk = j & 127;
        val = r1W[kk * 64 + n];
    }
    arena[i] = f2bf(val);
}

// fused biases: qkv0b[384] then qkv1b[2*768]
__global__ void bias_k(const float* __restrict__ q0b, const float* __restrict__ k0b,
                       const float* __restrict__ v0b,
                       const float* __restrict__ q1b, const float* __restrict__ k1b,
                       const float* __restrict__ v1b, float* __restrict__ out) {
    int i = blockIdx.x * 256 + threadIdx.x;
    if (i >= 1920) return;
    if (i < 384) {
        int sec = i >> 7, c = i & 127;
        out[i] = (sec == 0) ? q0b[c] : (sec == 1) ? k0b[c] : v0b[c];
    } else {
        int j = i - 384;
        int p = j / 768, rr = j - p * 768;
        int sec = rr >> 8, c = p * 256 + (rr & 255);
        out[i] = (sec == 0) ? q1b[c] : (sec == 1) ? k1b[c] : v1b[c];
    }
}

// ---------------- f32 -> bf16 convert (8 elems/thread) ----------------
__global__ void cvt_k(const float* __restrict__ in, u16* __restrict__ out, int n8) {
    int i = blockIdx.x * 256 + threadIdx.x;
    if (i >= n8) return;
    float4 a = *(const float4*)(in + (size_t)i * 8);
    float4 b = *(const float4*)(in + (size_t)i * 8 + 4);
    ushort8 o = {f2bf(a.x), f2bf(a.y), f2bf(a.z), f2bf(a.w),
                 f2bf(b.x), f2bf(b.y), f2bf(b.z), f2bf(b.w)};
    *(ushort8*)(out + (size_t)i * 8) = o;
}

// ---------------- MFMA GEMM v3: C = A[M,K](bf16) @ Bt[N,K](bf16)^T + bias ----------
// 128x128 tiles, BK=64 via global_load_lds, XOR-swizzled LDS.
// OUTMODE: 0 = f32, 1 = bf16,
//          2 = layer-0 fused 512B rows  [q fp8x16 128B | k bf16 256B | v fp8x16 128B]
//          3 = layer-1 fused 1024B rows [q fp8x16 256B | k bf16 512B | v fp8x16 256B]
template <int OUTMODE, int K>
__global__ __launch_bounds__(256) void mgemm3(const u16* __restrict__ A,
                                              const u16* __restrict__ Bt,
                                              const float* __restrict__ bias,
                                              void* __restrict__ C,
                                              int M, int Nvalid, int ldc) {
    __shared__ __align__(16) u16 As[128 * 64];
    __shared__ __align__(16) u16 Bs[128 * 64];
    const int bm = blockIdx.x * 128;
    const int bn = blockIdx.y * 128;
    const int t = threadIdx.x, lane = t & 63, wid = t >> 6;
    const int wm = (wid >> 1) * 64, wn = (wid & 1) * 64;
    const int jlog = ((lane & 7) ^ (lane >> 3)) * 8;
    f32x4 acc[4][4] = {};
    for (int k0 = 0; k0 < K; k0 += 64) {
#pragma unroll
        for (int c2 = 0; c2 < 4; ++c2) {
            int seg = c2 * 4 + wid;
            int row = seg * 8 + (lane >> 3);
            int ga = bm + row; if (ga >= M) ga = 0;
            gload16(A + (size_t)ga * K + k0 + jlog, (const char*)As + seg * 1024);
            int gb = bn + row; if (gb >= Nvalid) gb = 0;
            gload16(Bt + (size_t)gb * K + k0 + jlog, (const char*)Bs + seg * 1024);
        }
        __syncthreads();
#pragma unroll
        for (int ks = 0; ks < 2; ++ks) {
            const int jx = ks * 4 + (lane >> 4);
            short8v af[4], bfr[4];
#pragma unroll
            for (int i = 0; i < 4; ++i) {
                int ra = wm + i * 16 + (lane & 15);
                af[i] = *(const short8v*)((const char*)As + ra * 128 + ((jx ^ (ra & 7)) << 4));
                int rb = wn + i * 16 + (lane & 15);
                bfr[i] = *(const short8v*)((const char*)Bs + rb * 128 + ((jx ^ (rb & 7)) << 4));
            }
#pragma unroll
            for (int mi = 0; mi < 4; ++mi)
#pragma unroll
                for (int ni = 0; ni < 4; ++ni)
                    acc[mi][ni] = __builtin_amdgcn_mfma_f32_16x16x32_bf16(
                        af[mi], bfr[ni], acc[mi][ni], 0, 0, 0);
        }
        if (k0 + 64 < K) __syncthreads();
    }
    const int sec = blockIdx.y;
#pragma unroll
    for (int ni = 0; ni < 4; ++ni) {
        int lcol = wn + ni * 16 + (lane & 15);   // 0..127 within section
        int ccol = bn + lcol;
        if (ccol >= Nvalid) continue;
        float bs = bias[ccol];
#pragma unroll
        for (int mi = 0; mi < 4; ++mi) {
#pragma unroll
            for (int j = 0; j < 4; ++j) {
                int crow = bm + wm + mi * 16 + (lane >> 4) * 4 + j;
                if (crow >= M) continue;
                float val = acc[mi][ni][j] + bs;
                if (OUTMODE == 0) {
                    ((float*)C)[(size_t)crow * ldc + ccol] = val;
                } else if (OUTMODE == 1) {
                    ((u16*)C)[(size_t)crow * ldc + ccol] = f2bf(val);
                } else if (OUTMODE == 2) {
                    unsigned char* rowp = (unsigned char*)C + (size_t)crow * 512;
                    if (sec == 0)      rowp[lcol] = f2fp8(val * 16.f);
                    else if (sec == 1) ((u16*)(rowp + 128))[lcol] = f2bf(val);
                    else               rowp[384 + lcol] = f2fp8(val * 16.f);
                } else {
                    unsigned char* rowp = (unsigned char*)C + (size_t)crow * 1024;
                    if (sec < 2)       rowp[sec * 128 + lcol] = f2fp8(val * 16.f);
                    else if (sec < 4)  ((u16*)(rowp + 256))[(sec - 2) * 128 + lcol] = f2bf(val);
                    else               rowp[768 + (sec - 4) * 128 + lcol] = f2fp8(val * 16.f);
                }
            }
        }
    }
}

// ---------------- CSR build ----------------
__global__ void zero2_k(int* __restrict__ a, int* __restrict__ b, int n) {
    int i = blockIdx.x * 256 + threadIdx.x;
    if (i < n) { a[i] = 0; b[i] = 0; }
}

__global__ void hist_k(const int* __restrict__ dst, int* __restrict__ cnt, int E) {
    int i = blockIdx.x * 256 + threadIdx.x;
    if (i < E) atomicAdd(&cnt[dst[i]], 1);
}

__global__ void blocksum_k(const int* __restrict__ cnt, int* __restrict__ bsum, int n) {
    __shared__ int sd[256];
    int i = blockIdx.x * 256 + threadIdx.x;
    sd[threadIdx.x] = (i < n) ? cnt[i] : 0;
    __syncthreads();
    for (int off = 128; off > 0; off >>= 1) {
        if (threadIdx.x < off) sd[threadIdx.x] += sd[threadIdx.x + off];
        __syncthreads();
    }
    if (threadIdx.x == 0) bsum[blockIdx.x] = sd[0];
}

__global__ void scanb_k(int* bsum, int nb) {
    __shared__ int tmp[512];
    int t = threadIdx.x;
    tmp[t] = (t < nb) ? bsum[t] : 0;
    __syncthreads();
    for (int off = 1; off < 512; off <<= 1) {
        int v = (t >= off) ? tmp[t - off] : 0;
        __syncthreads();
        tmp[t] += v;
        __syncthreads();
    }
    if (t < nb) bsum[t] = (t ? tmp[t - 1] : 0);
}

__global__ void scanc_k(const int* __restrict__ cnt, const int* __restrict__ bsum,
                        int* __restrict__ row_off, int n, int E) {
    __shared__ int tmp[256];
    int b = blockIdx.x, t = threadIdx.x;
    int i = b * 256 + t;
    int own = (i < n) ? cnt[i] : 0;
    tmp[t] = own;
    __syncthreads();
    for (int off = 1; off < 256; off <<= 1) {
        int v = (t >= off) ? tmp[t - off] : 0;
        __syncthreads();
        tmp[t] += v;
        __syncthreads();
    }
    if (i < n) row_off[i] = bsum[b] + tmp[t] - own;
    if (b == 0 && t == 0) row_off[n] = E;
}

__global__ void scatter_k(const int* __restrict__ src, const int* __restrict__ dst,
                          const int* __restrict__ row_off, int* __restrict__ cur,
                          int* __restrict__ csr_src, int E) {
    int i = blockIdx.x * 256 + threadIdx.x;
    if (i < E) {
        int d = dst[i];
        int pos = row_off[d] + atomicAdd(&cur[d], 1);
        csr_src[pos] = src[i];
    }
}

// ---------------- attention layer 0: 8 heads x d=16, fp8 q/v, 512B rows ----------------
// lane l: feats 2l,2l+1 (head l>>3); 8-lane head reduce (3 shuffles). Unroll 4.
__global__ __launch_bounds__(256) void attn0_k(const unsigned char* __restrict__ qkv,
                                               const int* __restrict__ row_off,
                                               const int* __restrict__ csr,
                                               float* __restrict__ out, int n) {
    int w = (blockIdx.x * 256 + threadIdx.x) >> 6;
    int lane = threadIdx.x & 63;
    if (w >= n) return;
    int beg = row_off[w], end = row_off[w + 1];
    unsigned kv = *(const unsigned*)(qkv + (size_t)w * 512 + 128 + 4 * lane);
    const float KS = 0.25f / 16.f;                        // 1/sqrt(16) / q-scale
    float k0f = bf2f((u16)kv) * KS, k1f = bf2f((u16)(kv >> 16)) * KS;
    float den = 0.f, num0 = 0.f, num1 = 0.f;
    int e = beg;
    for (; e + 4 <= end; e += 4) {
        int s0 = csr[e], s1 = csr[e + 1], s2 = csr[e + 2], s3 = csr[e + 3];
        const unsigned char* r0 = qkv + (size_t)s0 * 512;
        const unsigned char* r1 = qkv + (size_t)s1 * 512;
        const unsigned char* r2 = qkv + (size_t)s2 * 512;
        const unsigned char* r3 = qkv + (size_t)s3 * 512;
        int qa = *(const unsigned short*)(r0 + 2 * lane);
        int qb = *(const unsigned short*)(r1 + 2 * lane);
        int qc = *(const unsigned short*)(r2 + 2 * lane);
        int qd = *(const unsigned short*)(r3 + 2 * lane);
        int va = *(const unsigned short*)(r0 + 384 + 2 * lane);
        int vb = *(const unsigned short*)(r1 + 384 + 2 * lane);
        int vc = *(const unsigned short*)(r2 + 384 + 2 * lane);
        int vd = *(const unsigned short*)(r3 + 384 + 2 * lane);
        f32x2 qaf = __builtin_amdgcn_cvt_pk_f32_fp8(qa, false);
        f32x2 qbf = __builtin_amdgcn_cvt_pk_f32_fp8(qb, false);
        f32x2 qcf = __builtin_amdgcn_cvt_pk_f32_fp8(qc, false);
        f32x2 qdf = __builtin_amdgcn_cvt_pk_f32_fp8(qd, false);
        float pa = qaf.x * k0f + qaf.y * k1f;
        float pb = qbf.x * k0f + qbf.y * k1f;
        float pc = qcf.x * k0f + qcf.y * k1f;
        float pd = qdf.x * k0f + qdf.y * k1f;
#pragma unroll
        for (int off = 1; off < 8; off <<= 1) {
            pa += __shfl_xor(pa, off); pb += __shfl_xor(pb, off);
            pc += __shfl_xor(pc, off); pd += __shfl_xor(pd, off);
        }
        float wa = __expf(pa), wb = __expf(pb);
        float wc = __expf(pc), wd = __expf(pd);
        den += (wa + wb) + (wc + wd);
        f32x2 vaf = __builtin_amdgcn_cvt_pk_f32_fp8(va, false);
        f32x2 vbf = __builtin_amdgcn_cvt_pk_f32_fp8(vb, false);
        f32x2 vcf = __builtin_amdgcn_cvt_pk_f32_fp8(vc, false);
        f32x2 vdf = __builtin_amdgcn_cvt_pk_f32_fp8(vd, false);
        num0 = fmaf(wa, vaf.x, num0); num1 = fmaf(wa, vaf.y, num1);
        num0 = fmaf(wb, vbf.x, num0); num1 = fmaf(wb, vbf.y, num1);
        num0 = fmaf(wc, vcf.x, num0); num1 = fmaf(wc, vcf.y, num1);
        num0 = fmaf(wd, vdf.x, num0); num1 = fmaf(wd, vdf.y, num1);
    }
    for (; e < end; ++e) {
        int s = csr[e];
        const unsigned char* r = qkv + (size_t)s * 512;
        int qv = *(const unsigned short*)(r + 2 * lane);
        f32x2 qf = __builtin_amdgcn_cvt_pk_f32_fp8(qv, false);
        float p = qf.x * k0f + qf.y * k1f;
        p += __shfl_xor(p, 1);
        p += __shfl_xor(p, 2);
        p += __shfl_xor(p, 4);
        float wt = __expf(p);
        den += wt;
        int vv = *(const unsigned short*)(r + 384 + 2 * lane);
        f32x2 vf = __builtin_amdgcn_cvt_pk_f32_fp8(vv, false);
        num0 = fmaf(wt, vf.x, num0); num1 = fmaf(wt, vf.y, num1);
    }
    float inv = (end > beg) ? (1.f / den) * (1.f / 16.f) : 0.f;   // v descale
    *(float2*)(out + ((size_t)w << 7) + 2 * lane) = make_float2(num0 * inv, num1 * inv);
}

// ---------------- attention layer 1 fused (one 4-head pass): d=64, 1024B rows ----------
// lane l: feats 4l..4l+3 (head l>>4); 16-lane head reduce (4 shuffles). Unroll 4.
template <bool FIRST>
__global__ __launch_bounds__(256) void attn1f_k(const unsigned char* __restrict__ qkv,
                                                const int* __restrict__ row_off,
                                                const int* __restrict__ csr,
                                                float* __restrict__ out, int n) {
    int w = (blockIdx.x * 256 + threadIdx.x) >> 6;
    int lane = threadIdx.x & 63;
    if (w >= n) return;
    int beg = row_off[w], end = row_off[w + 1];
    const float KS = 0.125f / 16.f;                       // 1/sqrt(64) / q-scale
    float kr0, kr1, kr2, kr3;
    {
        uint2 kk2 = *(const uint2*)(qkv + (size_t)w * 1024 + 256 + 8 * lane);
        kr0 = bf2f((u16)kk2.x) * KS; kr1 = bf2f((u16)(kk2.x >> 16)) * KS;
        kr2 = bf2f((u16)kk2.y) * KS; kr3 = bf2f((u16)(kk2.y >> 16)) * KS;
    }
    float den = 0.f, num0 = 0.f, num1 = 0.f, num2 = 0.f, num3 = 0.f;
    int e = beg;
    for (; e + 4 <= end; e += 4) {
        int s0 = csr[e], s1 = csr[e + 1], s2 = csr[e + 2], s3 = csr[e + 3];
        const unsigned char* r0 = qkv + (size_t)s0 * 1024;
        const unsigned char* r1 = qkv + (size_t)s1 * 1024;
        const unsigned char* r2 = qkv + (size_t)s2 * 1024;
        const unsigned char* r3 = qkv + (size_t)s3 * 1024;
        unsigned qa = *(const unsigned*)(r0 + 4 * lane);
        unsigned qb = *(const unsigned*)(r1 + 4 * lane);
        unsigned qc = *(const unsigned*)(r2 + 4 * lane);
        unsigned qd = *(const unsigned*)(r3 + 4 * lane);
        unsigned va = *(const unsigned*)(r0 + 768 + 4 * lane);
        unsigned vb = *(const unsigned*)(r1 + 768 + 4 * lane);
        unsigned vc = *(const unsigned*)(r2 + 768 + 4 * lane);
        unsigned vd = *(const unsigned*)(r3 + 768 + 4 * lane);
        f32x2 qa0 = __builtin_amdgcn_cvt_pk_f32_fp8((int)qa, false);
        f32x2 qa1 = __builtin_amdgcn_cvt_pk_f32_fp8((int)qa, true);
        f32x2 qb0 = __builtin_amdgcn_cvt_pk_f32_fp8((int)qb, false);
        f32x2 qb1 = __builtin_amdgcn_cvt_pk_f32_fp8((int)qb, true);
        f32x2 qc0 = __builtin_amdgcn_cvt_pk_f32_fp8((int)qc, false);
        f32x2 qc1 = __builtin_amdgcn_cvt_pk_f32_fp8((int)qc, true);
        f32x2 qd0 = __builtin_amdgcn_cvt_pk_f32_fp8((int)qd, false);
        f32x2 qd1 = __builtin_amdgcn_cvt_pk_f32_fp8((int)qd, true);
        float pa = qa0.x * kr0 + qa0.y * kr1 + qa1.x * kr2 + qa1.y * kr3;
        float pb = qb0.x * kr0 + qb0.y * kr1 + qb1.x * kr2 + qb1.y * kr3;
        float pc = qc0.x * kr0 + qc0.y * kr1 + qc1.x * kr2 + qc1.y * kr3;
        float pd = qd0.x * kr0 + qd0.y * kr1 + qd1.x * kr2 + qd1.y * kr3;
#pragma unroll
        for (int off = 1; off < 16; off <<= 1) {
            pa += __shfl_xor(pa, off); pb += __shfl_xor(pb, off);
            pc += __shfl_xor(pc, off); pd += __shfl_xor(pd, off);
        }
        float wa = __expf(pa), wb = __expf(pb);
        float wc = __expf(pc), wd = __expf(pd);
        den += (wa + wb) + (wc + wd);
        f32x2 va0 = __builtin_amdgcn_cvt_pk_f32_fp8((int)va, false);
        f32x2 va1 = __builtin_amdgcn_cvt_pk_f32_fp8((int)va, true);
        f32x2 vb0 = __builtin_amdgcn_cvt_pk_f32_fp8((int)vb, false);
        f32x2 vb1 = __builtin_amdgcn_cvt_pk_f32_fp8((int)vb, true);
        f32x2 vc0 = __builtin_amdgcn_cvt_pk_f32_fp8((int)vc, false);
        f32x2 vc1 = __builtin_amdgcn_cvt_pk_f32_fp8((int)vc, true);
        f32x2 vd0 = __builtin_amdgcn_cvt_pk_f32_fp8((int)vd, false);
        f32x2 vd1 = __builtin_amdgcn_cvt_pk_f32_fp8((int)vd, true);
        num0 = fmaf(wa, va0.x, num0); num1 = fmaf(wa, va0.y, num1);
        num2 = fmaf(wa, va1.x, num2); num3 = fmaf(wa, va1.y, num3);
        num0 = fmaf(wb, vb0.x, num0); num1 = fmaf(wb, vb0.y, num1);
        num2 = fmaf(wb, vb1.x, num2); num3 = fmaf(wb, vb1.y, num3);
        num0 = fmaf(wc, vc0.x, num0); num1 = fmaf(wc, vc0.y, num1);
        num2 = fmaf(wc, vc1.x, num2); num3 = fmaf(wc, vc1.y, num3);
        num0 = fmaf(wd, vd0.x, num0); num1 = fmaf(wd, vd0.y, num1);
        num2 = fmaf(wd, vd1.x, num2); num3 = fmaf(wd, vd1.y, num3);
    }
    for (; e < end; ++e) {
        int s = csr[e];
        const unsigned char* r = qkv + (size_t)s * 1024;
        unsigned qv = *(const unsigned*)(r + 4 * lane);
        f32x2 q0 = __builtin_amdgcn_cvt_pk_f32_fp8((int)qv, false);
        f32x2 q1 = __builtin_amdgcn_cvt_pk_f32_fp8((int)qv, true);
        float p = q0.x * kr0 + q0.y * kr1 + q1.x * kr2 + q1.y * kr3;
#pragma unroll
        for (int off = 1; off < 16; off <<= 1) p += __shfl_xor(p, off);
        float wt = __expf(p);
        den += wt;
        unsigned vv = *(const unsigned*)(r + 768 + 4 * lane);
        f32x2 v0 = __builtin_amdgcn_cvt_pk_f32_fp8((int)vv, false);
        f32x2 v1 = __builtin_amdgcn_cvt_pk_f32_fp8((int)vv, true);
        num0 = fmaf(wt, v0.x, num0); num1 = fmaf(wt, v0.y, num1);
        num2 = fmaf(wt, v1.x, num2); num3 = fmaf(wt, v1.y, num3);
    }
    float inv = (end > beg) ? 1.f / den : 0.f;
    float o0 = num0 * inv, o1 = num1 * inv, o2 = num2 * inv, o3 = num3 * inv;
    // sum the 4 heads (16-lane groups) at the same dim position
    o0 += __shfl_xor(o0, 16); o1 += __shfl_xor(o1, 16);
    o2 += __shfl_xor(o2, 16); o3 += __shfl_xor(o3, 16);
    o0 += __shfl_xor(o0, 32); o1 += __shfl_xor(o1, 32);
    o2 += __shfl_xor(o2, 32); o3 += __shfl_xor(o3, 32);
    if (lane < 16) {
        const float HS = 1.f / 128.f;   // head-mean (1/8) * v descale (1/16)
        float4* op = (float4*)(out + ((size_t)w << 6) + lane * 4);
        if (FIRST) {
            *op = make_float4(o0 * HS, o1 * HS, o2 * HS, o3 * HS);
        } else {
            float4 tv = *op;
            tv.x += o0 * HS; tv.y += o1 * HS; tv.z += o2 * HS; tv.w += o3 * HS;
            *op = tv;
        }
    }
}

// ---------------- gated residual + LN + relu (layer 0), bf16 h1 out ----------------
__global__ __launch_bounds__(256) void gres0_k(const float* __restrict__ x, const float* __restrict__ res,
                                               const float* __restrict__ gw,
                                               const float* __restrict__ lng, const float* __restrict__ lnb,
                                               u16* __restrict__ h1, int n) {
    int w = (blockIdx.x * 256 + threadIdx.x) >> 6;
    int lane = threadIdx.x & 63;
    if (w >= n) return;
    size_t base = (size_t)w * 128;
    float x1 = x[base + lane], x2 = x[base + lane + 64];
    float r1 = res[base + lane], r2 = res[base + lane + 64];
    float ca1 = gw[lane] + gw[256 + lane];
    float ca2 = gw[lane + 64] + gw[256 + lane + 64];
    float cr1 = gw[128 + lane] - gw[256 + lane];
    float cr2 = gw[128 + lane + 64] - gw[256 + lane + 64];
    float dot = x1 * ca1 + x2 * ca2 + r1 * cr1 + r2 * cr2;
#pragma unroll
    for (int off = 1; off < 64; off <<= 1) dot += __shfl_xor(dot, off);
    float g = 1.f / (1.f + __expf(-dot));
    float o1 = x1 * g + r1 * (1.f - g);
    float o2 = x2 * g + r2 * (1.f - g);
    float s = o1 + o2;
#pragma unroll
    for (int off = 1; off < 64; off <<= 1) s += __shfl_xor(s, off);
    float mu = s * (1.f / 128.f);
    float d1 = o1 - mu, d2 = o2 - mu;
    float vs = d1 * d1 + d2 * d2;
#pragma unroll
    for (int off = 1; off < 64; off <<= 1) vs += __shfl_xor(vs, off);
    float rstd = rsqrtf(vs * (1.f / 128.f) + 1e-5f);
    float y1 = d1 * rstd * lng[lane] + lnb[lane];
    float y2 = d2 * rstd * lng[lane + 64] + lnb[lane + 64];
    h1[base + lane] = f2bf(fmaxf(y1, 0.f));
    h1[base + lane + 64] = f2bf(fmaxf(y2, 0.f));
}

// ---------------- gated residual only (layer 1, d=64) ----------------
__global__ __launch_bounds__(256) void gres1_k(const float* __restrict__ x, const float* __restrict__ res,
                                               const float* __restrict__ gw,
                                               float* __restrict__ out, int n) {
    int w = (blockIdx.x * 256 + threadIdx.x) >> 6;
    int lane = threadIdx.x & 63;
    if (w >= n) return;
    size_t base = (size_t)w * 64;
    float xv = x[base + lane];
    float rv = res[base + lane];
    float ca = gw[lane] + gw[128 + lane];
    float cr = gw[64 + lane] - gw[128 + lane];
    float dot = xv * ca + rv * cr;
#pragma unroll
    for (int off = 1; off < 64; off <<= 1) dot += __shfl_xor(dot, off);
    float g = 1.f / (1.f + __expf(-dot));
    out[base + lane] = xv * g + rv * (1.f - g);
}

extern "C" void kernel_launch(void* const* d_in, const int* in_sizes, int n_in,
                              void* d_out, int out_size, void* d_ws, size_t ws_size,
                              hipStream_t stream) {
    const float* x    = (const float*)d_in[0];
    const int*   src  = (const int*)d_in[1];
    const int*   dst  = (const int*)d_in[2];
    const float* in_W = (const float*)d_in[3];
    const float* in_b = (const float*)d_in[4];
    const float* q0W = (const float*)d_in[5];  const float* q0b = (const float*)d_in[6];
    const float* k0W = (const float*)d_in[7];  const float* k0b = (const float*)d_in[8];
    const float* v0W = (const float*)d_in[9];  const float* v0b = (const float*)d_in[10];
    const float* r0W = (const float*)d_in[11]; const float* r0b = (const float*)d_in[12];
    const float* g0W = (const float*)d_in[13];
    const float* ln0g = (const float*)d_in[14]; const float* ln0b = (const float*)d_in[15];
    const float* q1W = (const float*)d_in[16]; const float* q1b = (const float*)d_in[17];
    const float* k1W = (const float*)d_in[18]; const float* k1b = (const float*)d_in[19];
    const float* v1W = (const float*)d_in[20]; const float* v1b = (const float*)d_in[21];
    const float* r1W = (const float*)d_in[22]; const float* r1b = (const float*)d_in[23];
    const float* g1W = (const float*)d_in[24];

    const int N = in_sizes[0] / 256;   // 100000
    const int E = in_sizes[1];         // 1600000
    (void)ws_size; (void)n_in; (void)out_size;

    // ---- workspace layout with reuse: peak ~186 MB ----
    auto rnd = [](size_t b) { return (b + 255) & ~(size_t)255; };
    char* base = (char*)d_ws;
    const size_t S_bf = rnd((size_t)N * 128 * 2);   // 25.6 MB
    const size_t S_f  = rnd((size_t)N * 128 * 4);   // 51.2 MB
    size_t o = 0;
    int* row_off = (int*)(base + o); o += rnd(((size_t)N + 1) * 4);
    int* csr     = (int*)(base + o); o += rnd((size_t)E * 4);
    u16* warena  = (u16*)(base + o); o += rnd((size_t)303104 * 2);
    float* barena = (float*)(base + o); o += rnd((size_t)1920 * 4);
    const size_t R0 = o;                 // 51.2: cnt/cur/bsum -> h -> a0 -> {res1o, a1}
    const size_t R1 = R0 + S_f;          // 76.8: x_bf(slots0-1) -> QKV0(slots0-1) -> h1(slot0)+PASS(slots1-2..)
    const size_t R2 = R1 + 3 * S_bf;     // 51.2: res0o -> PASS tail
    int* cnt  = (int*)(base + R0);
    int* cur  = (int*)(base + R0 + rnd((size_t)N * 4));
    int* bsum = (int*)(base + R0 + 2 * rnd((size_t)N * 4));
    u16*   h     = (u16*)(base + R0);
    float* a0    = (float*)(base + R0);
    float* res1o = (float*)(base + R0);
    float* a1    = (float*)(base + R0 + rnd((size_t)N * 64 * 4));
    u16* x_bf = (u16*)(base + R1);                       // N x 256 bf16, dies after in-GEMM
    unsigned char* QKV0 = (unsigned char*)(base + R1);   // N x 512 B (slots 0-1)
    u16* h1   = (u16*)(base + R1);                       // N x 128 bf16 (slot 0, after QKV0 dead)
    unsigned char* PASS = (unsigned char*)(base + R1 + S_bf);  // N x 1024 B (slots 1-2 + R2)
    float* res0o = (float*)(base + R2);                  // dead after gres0 (before PASS written)

    // weight arena sections
    u16* inWt  = warena;
    u16* qkv0t = warena + 32768;
    u16* r0t   = warena + 81920;
    u16* qkv1t = warena + 98304;
    u16* r1t   = warena + 294912;
    float* qkv0b = barena;
    float* qkv1b = barena + 384;

    dim3 blk(256);
    int nwb = (N * 64 + 255) / 256;   // one wave per node
    int nb  = (N + 255) / 256;        // 391 (<= 512)
    int mb  = (N + 127) / 128;        // 782

    // ---- prep (weights/bias/x convert) ----
    prep_k<<<(303104 + 255) / 256, blk, 0, stream>>>(in_W, q0W, k0W, v0W, r0W,
                                                     q1W, k1W, v1W, r1W, warena);
    bias_k<<<8, blk, 0, stream>>>(q0b, k0b, v0b, q1b, k1b, v1b, barena);
    cvt_k<<<(N * 32 + 255) / 256, blk, 0, stream>>>(x, x_bf, N * 32);

    // ---- CSR build ----
    zero2_k<<<nb, blk, 0, stream>>>(cnt, cur, N);
    hist_k<<<(E + 255) / 256, blk, 0, stream>>>(dst, cnt, E);
    blocksum_k<<<nb, blk, 0, stream>>>(cnt, bsum, N);
    scanb_k<<<1, 512, 0, stream>>>(bsum, nb);
    scanc_k<<<nb, blk, 0, stream>>>(cnt, bsum, row_off, N, E);
    scatter_k<<<(E + 255) / 256, blk, 0, stream>>>(src, dst, row_off, cur, csr, E);

    // ---- layer 0 ----
    mgemm3<1, 256><<<dim3(mb, 1), blk, 0, stream>>>(x_bf, inWt, in_b, h, N, 128, 128);
    mgemm3<2, 128><<<dim3(mb, 3), blk, 0, stream>>>(h, qkv0t, qkv0b, QKV0, N, 384, 0);
    mgemm3<0, 128><<<dim3(mb, 1), blk, 0, stream>>>(h, r0t, r0b, res0o, N, 128, 128);

    attn0_k<<<nwb, blk, 0, stream>>>(QKV0, row_off, csr, a0, N);
    gres0_k<<<nwb, blk, 0, stream>>>(a0, res0o, g0W, ln0g, ln0b, h1, N);

    // ---- layer 1: res path, then 2 fused passes of 4 heads each ----
    mgemm3<0, 128><<<dim3(mb, 1), blk, 0, stream>>>(h1, r1t, r1b, res1o, N, 64, 64);

    for (int p = 0; p < 2; ++p) {
        mgemm3<3, 128><<<dim3(mb, 6), blk, 0, stream>>>(
            h1, qkv1t + (size_t)p * 768 * 128, qkv1b + p * 768, PASS, N, 768, 0);
        if (p == 0) attn1f_k<true><<<nwb, blk, 0, stream>>>(PASS, row_off, csr, a1, N);
        else        attn1f_k<false><<<nwb, blk, 0, stream>>>(PASS, row_off, csr, a1, N);
    }

    gres1_k<<<nwb, blk, 0, stream>>>(a1, res1o, g1W, (float*)d_out, N);
}

// Round 13
// 907.956 us; speedup vs baseline: 1.4637x; 1.0129x over previous
//
#include <hip/hip_runtime.h>

// GraphTransformerModel: 2-layer graph attention network.
// CSR build -> bf16 MFMA GEMMs (mgemm7: XCD-swizzled blocks, fused dispatches,
// global_load_lds + XOR swizzle) -> attn0 (fp8 q/v, 512B rows) -> gres0+LN
// -> 2x {qkv1 4-head GEMM (1024B rows) -> attn1f} -> gres1.
// fp8 = e4m3 x16 scale, HW encode/decode. Peak workspace ~186 MB.

typedef unsigned short u16;
typedef __attribute__((ext_vector_type(8))) unsigned short ushort8;
typedef __attribute__((ext_vector_type(8))) short short8v;   // 8 bf16 (4 VGPRs)
typedef __attribute__((ext_vector_type(4))) float f32x4;
typedef __attribute__((ext_vector_type(2))) float f32x2;

__device__ __forceinline__ float bf2f(unsigned short u) {
    return __uint_as_float(((unsigned)u) << 16);
}
__device__ __forceinline__ unsigned short f2bf(float f) {
    unsigned u = __float_as_uint(f);
    unsigned r = 0x7fffu + ((u >> 16) & 1u);   // round-to-nearest-even
    return (unsigned short)((u + r) >> 16);
}
__device__ __forceinline__ unsigned char f2fp8(float f) {   // HW e4m3 encode
    return (unsigned char)__builtin_amdgcn_cvt_pk_fp8_f32(f, 0.f, 0, false);
}

// async global->LDS, 16B per lane; dest is wave-uniform base + lane*16 (HW).
__device__ __forceinline__ void gload16(const void* gp, const void* lp) {
    __builtin_amdgcn_global_load_lds(
        (const __attribute__((address_space(1))) unsigned*)(uintptr_t)gp,
        (__attribute__((address_space(3))) unsigned*)(unsigned)(uintptr_t)lp,
        16, 0, 0);
}

// ---------------- fused weight prep ----------------
// arena (u16): [0)=inWt[128][256]  [32768)=qkv0t[384][128]  [81920)=r0t[128][128]
//              [98304)=qkv1t[2][768][128]  [294912)=r1t[64][128]  total 303104
// NOTE: contiguity is exploited: {qkv0t,r0t} form 512 rows; {qkv1t_p1,r1t} form 832 rows.
__global__ void prep_k(const float* __restrict__ inW,
                       const float* __restrict__ q0W, const float* __restrict__ k0W,
                       const float* __restrict__ v0W, const float* __restrict__ r0W,
                       const float* __restrict__ q1W, const float* __restrict__ k1W,
                       const float* __restrict__ v1W, const float* __restrict__ r1W,
                       u16* __restrict__ arena) {
    int i = blockIdx.x * 256 + threadIdx.x;
    if (i >= 303104) return;
    float val;
    if (i < 32768) {                       // inWt[n][k] = inW[k][n], K=256, N=128
        int n = i >> 8, k = i & 255;
        val = inW[k * 128 + n];
    } else if (i < 81920) {                // qkv0t [384][128]
        int j = i - 32768;
        int r = j >> 7, kk = j & 127;
        int sec = r >> 7, c = r & 127;
        const float* s = (sec == 0) ? q0W : (sec == 1) ? k0W : v0W;
        val = s[kk * 128 + c];
    } else if (i < 98304) {                // r0t [128][128]
        int j = i - 81920;
        int r = j >> 7, kk = j & 127;
        val = r0W[kk * 128 + r];
    } else if (i < 294912) {               // qkv1t [2][768][128]: pass p covers cols p*256..+255
        int j = i - 98304;
        int row = j >> 7, kk = j & 127;
        int p = row / 768, rr = row - p * 768;
        int sec = rr >> 8, c = p * 256 + (rr & 255);
        const float* s = (sec == 0) ? q1W : (sec == 1) ? k1W : v1W;
        val = s[kk * 512 + c];
    } else {                               // r1t [64][128]
        int j = i - 294912;
        int n = j >> 7, kk = j & 127;
        val = r1W[kk * 64 + n];
    }
    arena[i] = f2bf(val);
}

// fused biases (2112 floats):
// [0)=qkv0b[384] [384)=r0b[128] [512)=qkv1b_p0[768] [1280)=qkv1b_p1[768] [2048)=r1b[64]
__global__ void bias_k(const float* __restrict__ q0b, const float* __restrict__ k0b,
                       const float* __restrict__ v0b, const float* __restrict__ r0b,
                       const float* __restrict__ q1b, const float* __restrict__ k1b,
                       const float* __restrict__ v1b, const float* __restrict__ r1b,
                       float* __restrict__ out) {
    int i = blockIdx.x * 256 + threadIdx.x;
    if (i >= 2112) return;
    if (i < 384) {
        int sec = i >> 7, c = i & 127;
        out[i] = (sec == 0) ? q0b[c] : (sec == 1) ? k0b[c] : v0b[c];
    } else if (i < 512) {
        out[i] = r0b[i - 384];
    } else if (i < 2048) {
        int j = i - 512;
        int p = j / 768, rr = j - p * 768;
        int sec = rr >> 8, c = p * 256 + (rr & 255);
        out[i] = (sec == 0) ? q1b[c] : (sec == 1) ? k1b[c] : v1b[c];
    } else {
        out[i] = r1b[i - 2048];
    }
}

// ---------------- f32 -> bf16 convert (8 elems/thread) ----------------
__global__ void cvt_k(const float* __restrict__ in, u16* __restrict__ out, int n8) {
    int i = blockIdx.x * 256 + threadIdx.x;
    if (i >= n8) return;
    float4 a = *(const float4*)(in + (size_t)i * 8);
    float4 b = *(const float4*)(in + (size_t)i * 8 + 4);
    ushort8 o = {f2bf(a.x), f2bf(a.y), f2bf(a.z), f2bf(a.w),
                 f2bf(b.x), f2bf(b.y), f2bf(b.z), f2bf(b.w)};
    *(ushort8*)(out + (size_t)i * 8) = o;
}

// ---------------- MFMA GEMM v7: XCD-swizzled, fused multi-section ----------------
// C_cols = A[M,K](bf16) @ Bt[Nvalid,K](bf16)^T + bias.  1D grid = 8*ny*ceil(MB/8);
// block id decodes so all ny column-blocks of one A-tile share id%8 (same XCD ->
// A-tile L2-resident).  128x128 tiles, BK=64 via global_load_lds, XOR swizzle.
// MODE 0: bf16 C [M,128]
// MODE 1: layer0 combo: sec 0-2 -> 512B fused rows (C); sec 3 -> f32 C2 [M,128]
// MODE 2: layer1 pass:  sec 0-5 -> 1024B fused rows (C)
// MODE 3: layer1 pass+aux: sec 0-5 -> 1024B rows; sec 6 -> f32 C2 [M,64]
template <int MODE, int K>
__global__ __launch_bounds__(256) void mgemm7(const u16* __restrict__ A,
                                              const u16* __restrict__ Bt,
                                              const float* __restrict__ bias,
                                              void* __restrict__ C,
                                              float* __restrict__ C2,
                                              int M, int MB, int ny, int Nvalid) {
    __shared__ __align__(16) u16 As[128 * 64];
    __shared__ __align__(16) u16 Bs[128 * 64];
    {
        int id = blockIdx.x;
        int xcd = id & 7, rest = id >> 3;
        int y = rest % ny;
        int x = (rest / ny) * 8 + xcd;
        if (x >= MB) return;
        const int bm = x * 128;
        const int bn = y * 128;
        const int t = threadIdx.x, lane = t & 63, wid = t >> 6;
        const int wm = (wid >> 1) * 64, wn = (wid & 1) * 64;
        const int jlog = ((lane & 7) ^ (lane >> 3)) * 8;
        f32x4 acc[4][4] = {};
        for (int k0 = 0; k0 < K; k0 += 64) {
#pragma unroll
            for (int c2 = 0; c2 < 4; ++c2) {
                int seg = c2 * 4 + wid;
                int row = seg * 8 + (lane >> 3);
                int ga = bm + row; if (ga >= M) ga = 0;
                gload16(A + (size_t)ga * K + k0 + jlog, (const char*)As + seg * 1024);
                int gb = bn + row; if (gb >= Nvalid) gb = 0;
                gload16(Bt + (size_t)gb * K + k0 + jlog, (const char*)Bs + seg * 1024);
            }
            __syncthreads();
#pragma unroll
            for (int ks = 0; ks < 2; ++ks) {
                const int jx = ks * 4 + (lane >> 4);
                short8v af[4], bfr[4];
#pragma unroll
                for (int i = 0; i < 4; ++i) {
                    int ra = wm + i * 16 + (lane & 15);
                    af[i] = *(const short8v*)((const char*)As + ra * 128 + ((jx ^ (ra & 7)) << 4));
                    int rb = wn + i * 16 + (lane & 15);
                    bfr[i] = *(const short8v*)((const char*)Bs + rb * 128 + ((jx ^ (rb & 7)) << 4));
                }
#pragma unroll
                for (int mi = 0; mi < 4; ++mi)
#pragma unroll
                    for (int ni = 0; ni < 4; ++ni)
                        acc[mi][ni] = __builtin_amdgcn_mfma_f32_16x16x32_bf16(
                            af[mi], bfr[ni], acc[mi][ni], 0, 0, 0);
            }
            if (k0 + 64 < K) __syncthreads();
        }
        const int sec = y;
#pragma unroll
        for (int ni = 0; ni < 4; ++ni) {
            int lcol = wn + ni * 16 + (lane & 15);   // 0..127 within section
            int ccol = bn + lcol;
            if (ccol >= Nvalid) continue;
            float bs = bias[ccol];
#pragma unroll
            for (int mi = 0; mi < 4; ++mi) {
#pragma unroll
                for (int j = 0; j < 4; ++j) {
                    int crow = bm + wm + mi * 16 + (lane >> 4) * 4 + j;
                    if (crow >= M) continue;
                    float val = acc[mi][ni][j] + bs;
                    if (MODE == 0) {
                        ((u16*)C)[(size_t)crow * 128 + ccol] = f2bf(val);
                    } else if (MODE == 1) {
                        if (sec < 3) {
                            unsigned char* rowp = (unsigned char*)C + (size_t)crow * 512;
                            if (sec == 0)      rowp[lcol] = f2fp8(val * 16.f);
                            else if (sec == 1) ((u16*)(rowp + 128))[lcol] = f2bf(val);
                            else               rowp[384 + lcol] = f2fp8(val * 16.f);
                        } else {
                            C2[(size_t)crow * 128 + lcol] = val;
                        }
                    } else {
                        if (MODE == 3 && sec == 6) {
                            C2[(size_t)crow * 64 + lcol] = val;
                        } else {
                            unsigned char* rowp = (unsigned char*)C + (size_t)crow * 1024;
                            if (sec < 2)       rowp[sec * 128 + lcol] = f2fp8(val * 16.f);
                            else if (sec < 4)  ((u16*)(rowp + 256))[(sec - 2) * 128 + lcol] = f2bf(val);
                            else               rowp[768 + (sec - 4) * 128 + lcol] = f2fp8(val * 16.f);
                        }
                    }
                }
            }
        }
    }
}

// ---------------- CSR build ----------------
__global__ void zero2_k(int* __restrict__ a, int* __restrict__ b, int n) {
    int i = blockIdx.x * 256 + threadIdx.x;
    if (i < n) { a[i] = 0; b[i] = 0; }
}

__global__ void hist_k(const int* __restrict__ dst, int* __restrict__ cnt, int E) {
    int i = blockIdx.x * 256 + threadIdx.x;
    if (i < E) atomicAdd(&cnt[dst[i]], 1);
}

__global__ void blocksum_k(const int* __restrict__ cnt, int* __restrict__ bsum, int n) {
    __shared__ int sd[256];
    int i = blockIdx.x * 256 + threadIdx.x;
    sd[threadIdx.x] = (i < n) ? cnt[i] : 0;
    __syncthreads();
    for (int off = 128; off > 0; off >>= 1) {
        if (threadIdx.x < off) sd[threadIdx.x] += sd[threadIdx.x + off];
        __syncthreads();
    }
    if (threadIdx.x == 0) bsum[blockIdx.x] = sd[0];
}

__global__ void scanb_k(int* bsum, int nb) {
    __shared__ int tmp[512];
    int t = threadIdx.x;
    tmp[t] = (t < nb) ? bsum[t] : 0;
    __syncthreads();
    for (int off = 1; off < 512; off <<= 1) {
        int v = (t >= off) ? tmp[t - off] : 0;
        __syncthreads();
        tmp[t] += v;
        __syncthreads();
    }
    if (t < nb) bsum[t] = (t ? tmp[t - 1] : 0);
}

__global__ void scanc_k(const int* __restrict__ cnt, const int* __restrict__ bsum,
                        int* __restrict__ row_off, int n, int E) {
    __shared__ int tmp[256];
    int b = blockIdx.x, t = threadIdx.x;
    int i = b * 256 + t;
    int own = (i < n) ? cnt[i] : 0;
    tmp[t] = own;
    __syncthreads();
    for (int off = 1; off < 256; off <<= 1) {
        int v = (t >= off) ? tmp[t - off] : 0;
        __syncthreads();
        tmp[t] += v;
        __syncthreads();
    }
    if (i < n) row_off[i] = bsum[b] + tmp[t] - own;
    if (b == 0 && t == 0) row_off[n] = E;
}

__global__ void scatter_k(const int* __restrict__ src, const int* __restrict__ dst,
                          const int* __restrict__ row_off, int* __restrict__ cur,
                          int* __restrict__ csr_src, int E) {
    int i = blockIdx.x * 256 + threadIdx.x;
    if (i < E) {
        int d = dst[i];
        int pos = row_off[d] + atomicAdd(&cur[d], 1);
        csr_src[pos] = src[i];
    }
}

// ---------------- attention layer 0: 8 heads x d=16, fp8 q/v, 512B rows ----------------
// lane l: feats 2l,2l+1 (head l>>3); 8-lane head reduce (3 shuffles). Unroll 4.
__global__ __launch_bounds__(256) void attn0_k(const unsigned char* __restrict__ qkv,
                                               const int* __restrict__ row_off,
                                               const int* __restrict__ csr,
                                               float* __restrict__ out, int n) {
    int w = (blockIdx.x * 256 + threadIdx.x) >> 6;
    int lane = threadIdx.x & 63;
    if (w >= n) return;
    int beg = row_off[w], end = row_off[w + 1];
    unsigned kv = *(const unsigned*)(qkv + (size_t)w * 512 + 128 + 4 * lane);
    const float KS = 0.25f / 16.f;                        // 1/sqrt(16) / q-scale
    float k0f = bf2f((u16)kv) * KS, k1f = bf2f((u16)(kv >> 16)) * KS;
    float den = 0.f, num0 = 0.f, num1 = 0.f;
    int e = beg;
    for (; e + 4 <= end; e += 4) {
        int s0 = csr[e], s1 = csr[e + 1], s2 = csr[e + 2], s3 = csr[e + 3];
        const unsigned char* r0 = qkv + (size_t)s0 * 512;
        const unsigned char* r1 = qkv + (size_t)s1 * 512;
        const unsigned char* r2 = qkv + (size_t)s2 * 512;
        const unsigned char* r3 = qkv + (size_t)s3 * 512;
        int qa = *(const unsigned short*)(r0 + 2 * lane);
        int qb = *(const unsigned short*)(r1 + 2 * lane);
        int qc = *(const unsigned short*)(r2 + 2 * lane);
        int qd = *(const unsigned short*)(r3 + 2 * lane);
        int va = *(const unsigned short*)(r0 + 384 + 2 * lane);
        int vb = *(const unsigned short*)(r1 + 384 + 2 * lane);
        int vc = *(const unsigned short*)(r2 + 384 + 2 * lane);
        int vd = *(const unsigned short*)(r3 + 384 + 2 * lane);
        f32x2 qaf = __builtin_amdgcn_cvt_pk_f32_fp8(qa, false);
        f32x2 qbf = __builtin_amdgcn_cvt_pk_f32_fp8(qb, false);
        f32x2 qcf = __builtin_amdgcn_cvt_pk_f32_fp8(qc, false);
        f32x2 qdf = __builtin_amdgcn_cvt_pk_f32_fp8(qd, false);
        float pa = qaf.x * k0f + qaf.y * k1f;
        float pb = qbf.x * k0f + qbf.y * k1f;
        float pc = qcf.x * k0f + qcf.y * k1f;
        float pd = qdf.x * k0f + qdf.y * k1f;
#pragma unroll
        for (int off = 1; off < 8; off <<= 1) {
            pa += __shfl_xor(pa, off); pb += __shfl_xor(pb, off);
            pc += __shfl_xor(pc, off); pd += __shfl_xor(pd, off);
        }
        float wa = __expf(pa), wb = __expf(pb);
        float wc = __expf(pc), wd = __expf(pd);
        den += (wa + wb) + (wc + wd);
        f32x2 vaf = __builtin_amdgcn_cvt_pk_f32_fp8(va, false);
        f32x2 vbf = __builtin_amdgcn_cvt_pk_f32_fp8(vb, false);
        f32x2 vcf = __builtin_amdgcn_cvt_pk_f32_fp8(vc, false);
        f32x2 vdf = __builtin_amdgcn_cvt_pk_f32_fp8(vd, false);
        num0 = fmaf(wa, vaf.x, num0); num1 = fmaf(wa, vaf.y, num1);
        num0 = fmaf(wb, vbf.x, num0); num1 = fmaf(wb, vbf.y, num1);
        num0 = fmaf(wc, vcf.x, num0); num1 = fmaf(wc, vcf.y, num1);
        num0 = fmaf(wd, vdf.x, num0); num1 = fmaf(wd, vdf.y, num1);
    }
    for (; e < end; ++e) {
        int s = csr[e];
        const unsigned char* r = qkv + (size_t)s * 512;
        int qv = *(const unsigned short*)(r + 2 * lane);
        f32x2 qf = __builtin_amdgcn_cvt_pk_f32_fp8(qv, false);
        float p = qf.x * k0f + qf.y * k1f;
        p += __shfl_xor(p, 1);
        p += __shfl_xor(p, 2);
        p += __shfl_xor(p, 4);
        float wt = __expf(p);
        den += wt;
        int vv = *(const unsigned short*)(r + 384 + 2 * lane);
        f32x2 vf = __builtin_amdgcn_cvt_pk_f32_fp8(vv, false);
        num0 = fmaf(wt, vf.x, num0); num1 = fmaf(wt, vf.y, num1);
    }
    float inv = (end > beg) ? (1.f / den) * (1.f / 16.f) : 0.f;   // v descale
    *(float2*)(out + ((size_t)w << 7) + 2 * lane) = make_float2(num0 * inv, num1 * inv);
}

// ---------------- attention layer 1 fused (one 4-head pass): d=64, 1024B rows ----------
// lane l: feats 4l..4l+3 (head l>>4); 16-lane head reduce (4 shuffles). Unroll 4.
template <bool FIRST>
__global__ __launch_bounds__(256) void attn1f_k(const unsigned char* __restrict__ qkv,
                                                const int* __restrict__ row_off,
                                                const int* __restrict__ csr,
                                                float* __restrict__ out, int n) {
    int w = (blockIdx.x * 256 + threadIdx.x) >> 6;
    int lane = threadIdx.x & 63;
    if (w >= n) return;
    int beg = row_off[w], end = row_off[w + 1];
    const float KS = 0.125f / 16.f;                       // 1/sqrt(64) / q-scale
    float kr0, kr1, kr2, kr3;
    {
        uint2 kk2 = *(const uint2*)(qkv + (size_t)w * 1024 + 256 + 8 * lane);
        kr0 = bf2f((u16)kk2.x) * KS; kr1 = bf2f((u16)(kk2.x >> 16)) * KS;
        kr2 = bf2f((u16)kk2.y) * KS; kr3 = bf2f((u16)(kk2.y >> 16)) * KS;
    }
    float den = 0.f, num0 = 0.f, num1 = 0.f, num2 = 0.f, num3 = 0.f;
    int e = beg;
    for (; e + 4 <= end; e += 4) {
        int s0 = csr[e], s1 = csr[e + 1], s2 = csr[e + 2], s3 = csr[e + 3];
        const unsigned char* r0 = qkv + (size_t)s0 * 1024;
        const unsigned char* r1 = qkv + (size_t)s1 * 1024;
        const unsigned char* r2 = qkv + (size_t)s2 * 1024;
        const unsigned char* r3 = qkv + (size_t)s3 * 1024;
        unsigned qa = *(const unsigned*)(r0 + 4 * lane);
        unsigned qb = *(const unsigned*)(r1 + 4 * lane);
        unsigned qc = *(const unsigned*)(r2 + 4 * lane);
        unsigned qd = *(const unsigned*)(r3 + 4 * lane);
        unsigned va = *(const unsigned*)(r0 + 768 + 4 * lane);
        unsigned vb = *(const unsigned*)(r1 + 768 + 4 * lane);
        unsigned vc = *(const unsigned*)(r2 + 768 + 4 * lane);
        unsigned vd = *(const unsigned*)(r3 + 768 + 4 * lane);
        f32x2 qa0 = __builtin_amdgcn_cvt_pk_f32_fp8((int)qa, false);
        f32x2 qa1 = __builtin_amdgcn_cvt_pk_f32_fp8((int)qa, true);
        f32x2 qb0 = __builtin_amdgcn_cvt_pk_f32_fp8((int)qb, false);
        f32x2 qb1 = __builtin_amdgcn_cvt_pk_f32_fp8((int)qb, true);
        f32x2 qc0 = __builtin_amdgcn_cvt_pk_f32_fp8((int)qc, false);
        f32x2 qc1 = __builtin_amdgcn_cvt_pk_f32_fp8((int)qc, true);
        f32x2 qd0 = __builtin_amdgcn_cvt_pk_f32_fp8((int)qd, false);
        f32x2 qd1 = __builtin_amdgcn_cvt_pk_f32_fp8((int)qd, true);
        float pa = qa0.x * kr0 + qa0.y * kr1 + qa1.x * kr2 + qa1.y * kr3;
        float pb = qb0.x * kr0 + qb0.y * kr1 + qb1.x * kr2 + qb1.y * kr3;
        float pc = qc0.x * kr0 + qc0.y * kr1 + qc1.x * kr2 + qc1.y * kr3;
        float pd = qd0.x * kr0 + qd0.y * kr1 + qd1.x * kr2 + qd1.y * kr3;
#pragma unroll
        for (int off = 1; off < 16; off <<= 1) {
            pa += __shfl_xor(pa, off); pb += __shfl_xor(pb, off);
            pc += __shfl_xor(pc, off); pd += __shfl_xor(pd, off);
        }
        float wa = __expf(pa), wb = __expf(pb);
        float wc = __expf(pc), wd = __expf(pd);
        den += (wa + wb) + (wc + wd);
        f32x2 va0 = __builtin_amdgcn_cvt_pk_f32_fp8((int)va, false);
        f32x2 va1 = __builtin_amdgcn_cvt_pk_f32_fp8((int)va, true);
        f32x2 vb0 = __builtin_amdgcn_cvt_pk_f32_fp8((int)vb, false);
        f32x2 vb1 = __builtin_amdgcn_cvt_pk_f32_fp8((int)vb, true);
        f32x2 vc0 = __builtin_amdgcn_cvt_pk_f32_fp8((int)vc, false);
        f32x2 vc1 = __builtin_amdgcn_cvt_pk_f32_fp8((int)vc, true);
        f32x2 vd0 = __builtin_amdgcn_cvt_pk_f32_fp8((int)vd, false);
        f32x2 vd1 = __builtin_amdgcn_cvt_pk_f32_fp8((int)vd, true);
        num0 = fmaf(wa, va0.x, num0); num1 = fmaf(wa, va0.y, num1);
        num2 = fmaf(wa, va1.x, num2); num3 = fmaf(wa, va1.y, num3);
        num0 = fmaf(wb, vb0.x, num0); num1 = fmaf(wb, vb0.y, num1);
        num2 = fmaf(wb, vb1.x, num2); num3 = fmaf(wb, vb1.y, num3);
        num0 = fmaf(wc, vc0.x, num0); num1 = fmaf(wc, vc0.y, num1);
        num2 = fmaf(wc, vc1.x, num2); num3 = fmaf(wc, vc1.y, num3);
        num0 = fmaf(wd, vd0.x, num0); num1 = fmaf(wd, vd0.y, num1);
        num2 = fmaf(wd, vd1.x, num2); num3 = fmaf(wd, vd1.y, num3);
    }
    for (; e < end; ++e) {
        int s = csr[e];
        const unsigned char* r = qkv + (size_t)s * 1024;
        unsigned qv = *(const unsigned*)(r + 4 * lane);
        f32x2 q0 = __builtin_amdgcn_cvt_pk_f32_fp8((int)qv, false);
        f32x2 q1 = __builtin_amdgcn_cvt_pk_f32_fp8((int)qv, true);
        float p = q0.x * kr0 + q0.y * kr1 + q1.x * kr2 + q1.y * kr3;
#pragma unroll
        for (int off = 1; off < 16; off <<= 1) p += __shfl_xor(p, off);
        float wt = __expf(p);
        den += wt;
        unsigned vv = *(const unsigned*)(r + 768 + 4 * lane);
        f32x2 v0 = __builtin_amdgcn_cvt_pk_f32_fp8((int)vv, false);
        f32x2 v1 = __builtin_amdgcn_cvt_pk_f32_fp8((int)vv, true);
        num0 = fmaf(wt, v0.x, num0); num1 = fmaf(wt, v0.y, num1);
        num2 = fmaf(wt, v1.x, num2); num3 = fmaf(wt, v1.y, num3);
    }
    float inv = (end > beg) ? 1.f / den : 0.f;
    float o0 = num0 * inv, o1 = num1 * inv, o2 = num2 * inv, o3 = num3 * inv;
    // sum the 4 heads (16-lane groups) at the same dim position
    o0 += __shfl_xor(o0, 16); o1 += __shfl_xor(o1, 16);
    o2 += __shfl_xor(o2, 16); o3 += __shfl_xor(o3, 16);
    o0 += __shfl_xor(o0, 32); o1 += __shfl_xor(o1, 32);
    o2 += __shfl_xor(o2, 32); o3 += __shfl_xor(o3, 32);
    if (lane < 16) {
        const float HS = 1.f / 128.f;   // head-mean (1/8) * v descale (1/16)
        float4* op = (float4*)(out + ((size_t)w << 6) + lane * 4);
        if (FIRST) {
            *op = make_float4(o0 * HS, o1 * HS, o2 * HS, o3 * HS);
        } else {
            float4 tv = *op;
            tv.x += o0 * HS; tv.y += o1 * HS; tv.z += o2 * HS; tv.w += o3 * HS;
            *op = tv;
        }
    }
}

// ---------------- gated residual + LN + relu (layer 0), bf16 h1 out ----------------
__global__ __launch_bounds__(256) void gres0_k(const float* __restrict__ x, const float* __restrict__ res,
                                               const float* __restrict__ gw,
                                               const float* __restrict__ lng, const float* __restrict__ lnb,
                                               u16* __restrict__ h1, int n) {
    int w = (blockIdx.x * 256 + threadIdx.x) >> 6;
    int lane = threadIdx.x & 63;
    if (w >= n) return;
    size_t base = (size_t)w * 128;
    float x1 = x[base + lane], x2 = x[base + lane + 64];
    float r1 = res[base + lane], r2 = res[base + lane + 64];
    float ca1 = gw[lane] + gw[256 + lane];
    float ca2 = gw[lane + 64] + gw[256 + lane + 64];
    float cr1 = gw[128 + lane] - gw[256 + lane];
    float cr2 = gw[128 + lane + 64] - gw[256 + lane + 64];
    float dot = x1 * ca1 + x2 * ca2 + r1 * cr1 + r2 * cr2;
#pragma unroll
    for (int off = 1; off < 64; off <<= 1) dot += __shfl_xor(dot, off);
    float g = 1.f / (1.f + __expf(-dot));
    float o1 = x1 * g + r1 * (1.f - g);
    float o2 = x2 * g + r2 * (1.f - g);
    float s = o1 + o2;
#pragma unroll
    for (int off = 1; off < 64; off <<= 1) s += __shfl_xor(s, off);
    float mu = s * (1.f / 128.f);
    float d1 = o1 - mu, d2 = o2 - mu;
    float vs = d1 * d1 + d2 * d2;
#pragma unroll
    for (int off = 1; off < 64; off <<= 1) vs += __shfl_xor(vs, off);
    float rstd = rsqrtf(vs * (1.f / 128.f) + 1e-5f);
    float y1 = d1 * rstd * lng[lane] + lnb[lane];
    float y2 = d2 * rstd * lng[lane + 64] + lnb[lane + 64];
    h1[base + lane] = f2bf(fmaxf(y1, 0.f));
    h1[base + lane + 64] = f2bf(fmaxf(y2, 0.f));
}

// ---------------- gated residual only (layer 1, d=64) ----------------
__global__ __launch_bounds__(256) void gres1_k(const float* __restrict__ x, const float* __restrict__ res,
                                               const float* __restrict__ gw,
                                               float* __restrict__ out, int n) {
    int w = (blockIdx.x * 256 + threadIdx.x) >> 6;
    int lane = threadIdx.x & 63;
    if (w >= n) return;
    size_t base = (size_t)w * 64;
    float xv = x[base + lane];
    float rv = res[base + lane];
    float ca = gw[lane] + gw[128 + lane];
    float cr = gw[64 + lane] - gw[128 + lane];
    float dot = xv * ca + rv * cr;
#pragma unroll
    for (int off = 1; off < 64; off <<= 1) dot += __shfl_xor(dot, off);
    float g = 1.f / (1.f + __expf(-dot));
    out[base + lane] = xv * g + rv * (1.f - g);
}

extern "C" void kernel_launch(void* const* d_in, const int* in_sizes, int n_in,
                              void* d_out, int out_size, void* d_ws, size_t ws_size,
                              hipStream_t stream) {
    const float* x    = (const float*)d_in[0];
    const int*   src  = (const int*)d_in[1];
    const int*   dst  = (const int*)d_in[2];
    const float* in_W = (const float*)d_in[3];
    const float* in_b = (const float*)d_in[4];
    const float* q0W = (const float*)d_in[5];  const float* q0b = (const float*)d_in[6];
    const float* k0W = (const float*)d_in[7];  const float* k0b = (const float*)d_in[8];
    const float* v0W = (const float*)d_in[9];  const float* v0b = (const float*)d_in[10];
    const float* r0W = (const float*)d_in[11]; const float* r0b = (const float*)d_in[12];
    const float* g0W = (const float*)d_in[13];
    const float* ln0g = (const float*)d_in[14]; const float* ln0b = (const float*)d_in[15];
    const float* q1W = (const float*)d_in[16]; const float* q1b = (const float*)d_in[17];
    const float* k1W = (const float*)d_in[18]; const float* k1b = (const float*)d_in[19];
    const float* v1W = (const float*)d_in[20]; const float* v1b = (const float*)d_in[21];
    const float* r1W = (const float*)d_in[22]; const float* r1b = (const float*)d_in[23];
    const float* g1W = (const float*)d_in[24];

    const int N = in_sizes[0] / 256;   // 100000
    const int E = in_sizes[1];         // 1600000
    (void)ws_size; (void)n_in; (void)out_size;

    // ---- workspace layout with reuse: peak ~186 MB ----
    auto rnd = [](size_t b) { return (b + 255) & ~(size_t)255; };
    char* base = (char*)d_ws;
    const size_t S_bf = rnd((size_t)N * 128 * 2);   // 25.6 MB
    const size_t S_f  = rnd((size_t)N * 128 * 4);   // 51.2 MB
    size_t o = 0;
    int* row_off = (int*)(base + o); o += rnd(((size_t)N + 1) * 4);
    int* csr     = (int*)(base + o); o += rnd((size_t)E * 4);
    u16* warena  = (u16*)(base + o); o += rnd((size_t)303104 * 2);
    float* barena = (float*)(base + o); o += rnd((size_t)2112 * 4);
    const size_t R0 = o;                 // 51.2: cnt/cur/bsum -> h -> a0 -> {res1o, a1}
    const size_t R1 = R0 + S_f;          // 76.8: x_bf(slots0-1) -> QKV0(slots0-1) -> h1(slot0)+PASS(slots1-2..)
    const size_t R2 = R1 + 3 * S_bf;     // 51.2: res0o -> PASS tail
    int* cnt  = (int*)(base + R0);
    int* cur  = (int*)(base + R0 + rnd((size_t)N * 4));
    int* bsum = (int*)(base + R0 + 2 * rnd((size_t)N * 4));
    u16*   h     = (u16*)(base + R0);
    float* a0    = (float*)(base + R0);
    float* res1o = (float*)(base + R0);
    float* a1    = (float*)(base + R0 + rnd((size_t)N * 64 * 4));
    u16* x_bf = (u16*)(base + R1);                       // N x 256 bf16, dies after in-GEMM
    unsigned char* QKV0 = (unsigned char*)(base + R1);   // N x 512 B (slots 0-1)
    u16* h1   = (u16*)(base + R1);                       // N x 128 bf16 (slot 0, after QKV0 dead)
    unsigned char* PASS = (unsigned char*)(base + R1 + S_bf);  // N x 1024 B (slots 1-2 + R2)
    float* res0o = (float*)(base + R2);                  // dead after gres0 (before PASS written)

    // weight arena sections
    u16* inWt   = warena;
    u16* qkv0t  = warena + 32768;      // rows 0..383 qkv0, 384..511 r0 (contiguous)
    u16* qkv1t0 = warena + 98304;      // pass0 rows 0..767
    u16* qkv1t1 = warena + 196608;     // pass1 rows 0..767, 768..831 = r1t (contiguous)

    dim3 blk(256);
    int nwb = (N * 64 + 255) / 256;   // one wave per node
    int nb  = (N + 255) / 256;        // 391 (<= 512)
    int mb  = (N + 127) / 128;        // 782
    int xch = (mb + 7) / 8;           // 98 (XCD-swizzled grid chunk count)

    // ---- prep (weights/bias/x convert) ----
    prep_k<<<(303104 + 255) / 256, blk, 0, stream>>>(in_W, q0W, k0W, v0W, r0W,
                                                     q1W, k1W, v1W, r1W, warena);
    bias_k<<<9, blk, 0, stream>>>(q0b, k0b, v0b, r0b, q1b, k1b, v1b, r1b, barena);
    cvt_k<<<(N * 32 + 255) / 256, blk, 0, stream>>>(x, x_bf, N * 32);

    // ---- CSR build ----
    zero2_k<<<nb, blk, 0, stream>>>(cnt, cur, N);
    hist_k<<<(E + 255) / 256, blk, 0, stream>>>(dst, cnt, E);
    blocksum_k<<<nb, blk, 0, stream>>>(cnt, bsum, N);
    scanb_k<<<1, 512, 0, stream>>>(bsum, nb);
    scanc_k<<<nb, blk, 0, stream>>>(cnt, bsum, row_off, N, E);
    scatter_k<<<(E + 255) / 256, blk, 0, stream>>>(src, dst, row_off, cur, csr, E);

    // ---- layer 0 ----
    mgemm7<0, 256><<<8 * 1 * xch, blk, 0, stream>>>(x_bf, inWt, in_b, h, nullptr,
                                                    N, mb, 1, 128);
    mgemm7<1, 128><<<8 * 4 * xch, blk, 0, stream>>>(h, qkv0t, barena, QKV0, res0o,
                                                    N, mb, 4, 512);
    attn0_k<<<nwb, blk, 0, stream>>>(QKV0, row_off, csr, a0, N);
    gres0_k<<<nwb, blk, 0, stream>>>(a0, res0o, g0W, ln0g, ln0b, h1, N);

    // ---- layer 1: pass0 (qkv), attn; pass1 (qkv + r1), attn; gres ----
    mgemm7<2, 128><<<8 * 6 * xch, blk, 0, stream>>>(h1, qkv1t0, barena + 512, PASS,
                                                    nullptr, N, mb, 6, 768);
    attn1f_k<true><<<nwb, blk, 0, stream>>>(PASS, row_off, csr, a1, N);

    mgemm7<3, 128><<<8 * 7 * xch, blk, 0, stream>>>(h1, qkv1t1, barena + 1280, PASS,
                                                    res1o, N, mb, 7, 832);
    attn1f_k<false><<<nwb, blk, 0, stream>>>(PASS, row_off, csr, a1, N);

    gres1_k<<<nwb, blk, 0, stream>>>(a1, res1o, g1W, (float*)d_out, N);
}

// Round 14
// 803.153 us; speedup vs baseline: 1.6547x; 1.1305x over previous
//
#include <hip/hip_runtime.h>

// GraphTransformerModel: 2-layer graph attention network.
// CSR build -> bf16 MFMA GEMMs (mgemm7: XCD-swizzled blocks, fused dispatches,
// global_load_lds + XOR swizzle, LDS-staged coalesced fp8 epilogue)
// -> attn0 (fp8 q/v, 512B rows) -> gres0+LN
// -> 2x {qkv1 4-head GEMM (1024B rows) -> attn1f} -> gres1.
// fp8 = e4m3 x16 scale, HW encode/decode. Peak workspace ~186 MB.

typedef unsigned short u16;
typedef __attribute__((ext_vector_type(8))) unsigned short ushort8;
typedef __attribute__((ext_vector_type(8))) short short8v;   // 8 bf16 (4 VGPRs)
typedef __attribute__((ext_vector_type(4))) float f32x4;
typedef __attribute__((ext_vector_type(2))) float f32x2;

__device__ __forceinline__ float bf2f(unsigned short u) {
    return __uint_as_float(((unsigned)u) << 16);
}
__device__ __forceinline__ unsigned short f2bf(float f) {
    unsigned u = __float_as_uint(f);
    unsigned r = 0x7fffu + ((u >> 16) & 1u);   // round-to-nearest-even
    return (unsigned short)((u + r) >> 16);
}
__device__ __forceinline__ unsigned char f2fp8(float f) {   // HW e4m3 encode
    return (unsigned char)__builtin_amdgcn_cvt_pk_fp8_f32(f, 0.f, 0, false);
}

// async global->LDS, 16B per lane; dest is wave-uniform base + lane*16 (HW).
__device__ __forceinline__ void gload16(const void* gp, const void* lp) {
    __builtin_amdgcn_global_load_lds(
        (const __attribute__((address_space(1))) unsigned*)(uintptr_t)gp,
        (__attribute__((address_space(3))) unsigned*)(unsigned)(uintptr_t)lp,
        16, 0, 0);
}

// ---------------- fused weight prep ----------------
// arena (u16): [0)=inWt[128][256]  [32768)=qkv0t[384][128]  [81920)=r0t[128][128]
//              [98304)=qkv1t[2][768][128]  [294912)=r1t[64][128]  total 303104
// Contiguity exploited: {qkv0t,r0t} = 512 rows; {qkv1t_p1,r1t} = 832 rows.
__global__ void prep_k(const float* __restrict__ inW,
                       const float* __restrict__ q0W, const float* __restrict__ k0W,
                       const float* __restrict__ v0W, const float* __restrict__ r0W,
                       const float* __restrict__ q1W, const float* __restrict__ k1W,
                       const float* __restrict__ v1W, const float* __restrict__ r1W,
                       u16* __restrict__ arena) {
    int i = blockIdx.x * 256 + threadIdx.x;
    if (i >= 303104) return;
    float val;
    if (i < 32768) {                       // inWt[n][k] = inW[k][n], K=256, N=128
        int n = i >> 8, k = i & 255;
        val = inW[k * 128 + n];
    } else if (i < 81920) {                // qkv0t [384][128]
        int j = i - 32768;
        int r = j >> 7, kk = j & 127;
        int sec = r >> 7, c = r & 127;
        const float* s = (sec == 0) ? q0W : (sec == 1) ? k0W : v0W;
        val = s[kk * 128 + c];
    } else if (i < 98304) {                // r0t [128][128]
        int j = i - 81920;
        int r = j >> 7, kk = j & 127;
        val = r0W[kk * 128 + r];
    } else if (i < 294912) {               // qkv1t [2][768][128]: pass p covers cols p*256..+255
        int j = i - 98304;
        int row = j >> 7, kk = j & 127;
        int p = row / 768, rr = row - p * 768;
        int sec = rr >> 8, c = p * 256 + (rr & 255);
        const float* s = (sec == 0) ? q1W : (sec == 1) ? k1W : v1W;
        val = s[kk * 512 + c];
    } else {                               // r1t [64][128]
        int j = i - 294912;
        int n = j >> 7, kk = j & 127;
        val = r1W[kk * 64 + n];
    }
    arena[i] = f2bf(val);
}

// fused biases (2112 floats):
// [0)=qkv0b[384] [384)=r0b[128] [512)=qkv1b_p0[768] [1280)=qkv1b_p1[768] [2048)=r1b[64]
__global__ void bias_k(const float* __restrict__ q0b, const float* __restrict__ k0b,
                       const float* __restrict__ v0b, const float* __restrict__ r0b,
                       const float* __restrict__ q1b, const float* __restrict__ k1b,
                       const float* __restrict__ v1b, const float* __restrict__ r1b,
                       float* __restrict__ out) {
    int i = blockIdx.x * 256 + threadIdx.x;
    if (i >= 2112) return;
    if (i < 384) {
        int sec = i >> 7, c = i & 127;
        out[i] = (sec == 0) ? q0b[c] : (sec == 1) ? k0b[c] : v0b[c];
    } else if (i < 512) {
        out[i] = r0b[i - 384];
    } else if (i < 2048) {
        int j = i - 512;
        int p = j / 768, rr = j - p * 768;
        int sec = rr >> 8, c = p * 256 + (rr & 255);
        out[i] = (sec == 0) ? q1b[c] : (sec == 1) ? k1b[c] : v1b[c];
    } else {
        out[i] = r1b[i - 2048];
    }
}

// ---------------- f32 -> bf16 convert (8 elems/thread) ----------------
__global__ void cvt_k(const float* __restrict__ in, u16* __restrict__ out, int n8) {
    int i = blockIdx.x * 256 + threadIdx.x;
    if (i >= n8) return;
    float4 a = *(const float4*)(in + (size_t)i * 8);
    float4 b = *(const float4*)(in + (size_t)i * 8 + 4);
    ushort8 o = {f2bf(a.x), f2bf(a.y), f2bf(a.z), f2bf(a.w),
                 f2bf(b.x), f2bf(b.y), f2bf(b.z), f2bf(b.w)};
    *(ushort8*)(out + (size_t)i * 8) = o;
}

// ---------------- MFMA GEMM v7: XCD-swizzled, fused multi-section ----------------
// C_cols = A[M,K](bf16) @ Bt[Nvalid,K](bf16)^T + bias.  1D grid = 8*ny*ceil(MB/8);
// block id decodes so all ny column-blocks of one A-tile share id%8 (same XCD ->
// A-tile L2-resident).  128x128 tiles, BK=64 via global_load_lds, XOR swizzle.
// fp8 sections use an LDS-staged transposing epilogue: byte tile [128][144]
// (16B-chunk XOR swizzle by row&7), then full 128B-row float4 bursts.
// MODE 0: bf16 C [M,128]
// MODE 1: layer0 combo: sec 0-2 -> 512B fused rows (C); sec 3 -> f32 C2 [M,128]
// MODE 2: layer1 pass:  sec 0-5 -> 1024B fused rows (C)
// MODE 3: layer1 pass+aux: sec 0-5 -> 1024B rows; sec 6 -> f32 C2 [M,64]
template <int MODE, int K>
__global__ __launch_bounds__(256) void mgemm7(const u16* __restrict__ A,
                                              const u16* __restrict__ Bt,
                                              const float* __restrict__ bias,
                                              void* __restrict__ C,
                                              float* __restrict__ C2,
                                              int M, int MB, int ny, int Nvalid) {
    __shared__ __align__(16) u16 As[128 * 64];
    __shared__ __align__(16) u16 Bs[128 * 64];
    int id = blockIdx.x;
    int xcd = id & 7, rest = id >> 3;
    int y = rest % ny;
    int x = (rest / ny) * 8 + xcd;
    if (x >= MB) return;
    const int bm = x * 128;
    const int bn = y * 128;
    const int t = threadIdx.x, lane = t & 63, wid = t >> 6;
    const int wm = (wid >> 1) * 64, wn = (wid & 1) * 64;
    const int jlog = ((lane & 7) ^ (lane >> 3)) * 8;
    f32x4 acc[4][4] = {};
    for (int k0 = 0; k0 < K; k0 += 64) {
#pragma unroll
        for (int c2 = 0; c2 < 4; ++c2) {
            int seg = c2 * 4 + wid;
            int row = seg * 8 + (lane >> 3);
            int ga = bm + row; if (ga >= M) ga = 0;
            gload16(A + (size_t)ga * K + k0 + jlog, (const char*)As + seg * 1024);
            int gb = bn + row; if (gb >= Nvalid) gb = 0;
            gload16(Bt + (size_t)gb * K + k0 + jlog, (const char*)Bs + seg * 1024);
        }
        __syncthreads();
#pragma unroll
        for (int ks = 0; ks < 2; ++ks) {
            const int jx = ks * 4 + (lane >> 4);
            short8v af[4], bfr[4];
#pragma unroll
            for (int i = 0; i < 4; ++i) {
                int ra = wm + i * 16 + (lane & 15);
                af[i] = *(const short8v*)((const char*)As + ra * 128 + ((jx ^ (ra & 7)) << 4));
                int rb = wn + i * 16 + (lane & 15);
                bfr[i] = *(const short8v*)((const char*)Bs + rb * 128 + ((jx ^ (rb & 7)) << 4));
            }
#pragma unroll
            for (int mi = 0; mi < 4; ++mi)
#pragma unroll
                for (int ni = 0; ni < 4; ++ni)
                    acc[mi][ni] = __builtin_amdgcn_mfma_f32_16x16x32_bf16(
                        af[mi], bfr[ni], acc[mi][ni], 0, 0, 0);
        }
        if (k0 + 64 < K) __syncthreads();
    }
    const int sec = y;
    // ---- fp8 fused-row sections: LDS-staged coalesced epilogue ----
    bool fp8lds = false;
    int gsecoff = 0, rowbytes = 0;
    if (MODE == 1) {
        if (sec == 0)      { fp8lds = true; gsecoff = 0;   rowbytes = 512; }
        else if (sec == 2) { fp8lds = true; gsecoff = 384; rowbytes = 512; }
    } else if (MODE >= 2) {
        if (sec < 2)                  { fp8lds = true; gsecoff = sec * 128;         rowbytes = 1024; }
        else if (sec >= 4 && sec < 6) { fp8lds = true; gsecoff = 768 + (sec - 4) * 128; rowbytes = 1024; }
    }
    if (fp8lds) {
        unsigned char* tile = (unsigned char*)As;   // 128 rows x 144B stride = 18 KB
        __syncthreads();                            // all waves done with As/Bs reads
#pragma unroll
        for (int ni = 0; ni < 4; ++ni) {
            int lcol = wn + ni * 16 + (lane & 15);
            float bs = bias[bn + lcol];
#pragma unroll
            for (int mi = 0; mi < 4; ++mi) {
#pragma unroll
                for (int j = 0; j < 4; ++j) {
                    int lrow = wm + mi * 16 + (lane >> 4) * 4 + j;
                    float val = acc[mi][ni][j] + bs;
                    tile[lrow * 144 + ((((lcol >> 4) ^ (lrow & 7)) << 4) | (lcol & 15))] =
                        f2fp8(val * 16.f);
                }
            }
        }
        __syncthreads();
#pragma unroll
        for (int it = 0; it < 4; ++it) {            // 1024 chunks of 16B
            int lin = it * 256 + t;
            int row = lin >> 3, ch = lin & 7;
            int crow = bm + row;
            if (crow < M) {
                const float4 vsrc = *(const float4*)(tile + row * 144 + ((ch ^ (row & 7)) << 4));
                *(float4*)((unsigned char*)C + (size_t)crow * rowbytes + gsecoff + ch * 16) = vsrc;
            }
        }
        return;
    }
    // ---- remaining sections: direct stores ----
#pragma unroll
    for (int ni = 0; ni < 4; ++ni) {
        int lcol = wn + ni * 16 + (lane & 15);   // 0..127 within section
        int ccol = bn + lcol;
        if (ccol >= Nvalid) continue;
        float bs = bias[ccol];
#pragma unroll
        for (int mi = 0; mi < 4; ++mi) {
#pragma unroll
            for (int j = 0; j < 4; ++j) {
                int crow = bm + wm + mi * 16 + (lane >> 4) * 4 + j;
                if (crow >= M) continue;
                float val = acc[mi][ni][j] + bs;
                if (MODE == 0) {
                    ((u16*)C)[(size_t)crow * 128 + ccol] = f2bf(val);
                } else if (MODE == 1) {
                    if (sec == 1) {
                        ((u16*)((unsigned char*)C + (size_t)crow * 512 + 128))[lcol] = f2bf(val);
                    } else {   // sec == 3
                        C2[(size_t)crow * 128 + lcol] = val;
                    }
                } else {
                    if (MODE == 3 && sec == 6) {
                        C2[(size_t)crow * 64 + lcol] = val;
                    } else {   // sec 2,3: k bf16
                        ((u16*)((unsigned char*)C + (size_t)crow * 1024 + 256))[(sec - 2) * 128 + lcol] = f2bf(val);
                    }
                }
            }
        }
    }
}

// ---------------- CSR build ----------------
__global__ void zero2_k(int* __restrict__ a, int* __restrict__ b, int n) {
    int i = blockIdx.x * 256 + threadIdx.x;
    if (i < n) { a[i] = 0; b[i] = 0; }
}

__global__ void hist_k(const int* __restrict__ dst, int* __restrict__ cnt, int E) {
    int i = blockIdx.x * 256 + threadIdx.x;
    if (i < E) atomicAdd(&cnt[dst[i]], 1);
}

__global__ void blocksum_k(const int* __restrict__ cnt, int* __restrict__ bsum, int n) {
    __shared__ int sd[256];
    int i = blockIdx.x * 256 + threadIdx.x;
    sd[threadIdx.x] = (i < n) ? cnt[i] : 0;
    __syncthreads();
    for (int off = 128; off > 0; off >>= 1) {
        if (threadIdx.x < off) sd[threadIdx.x] += sd[threadIdx.x + off];
        __syncthreads();
    }
    if (threadIdx.x == 0) bsum[blockIdx.x] = sd[0];
}

__global__ void scanb_k(int* bsum, int nb) {
    __shared__ int tmp[512];
    int t = threadIdx.x;
    tmp[t] = (t < nb) ? bsum[t] : 0;
    __syncthreads();
    for (int off = 1; off < 512; off <<= 1) {
        int v = (t >= off) ? tmp[t - off] : 0;
        __syncthreads();
        tmp[t] += v;
        __syncthreads();
    }
    if (t < nb) bsum[t] = (t ? tmp[t - 1] : 0);
}

__global__ void scanc_k(const int* __restrict__ cnt, const int* __restrict__ bsum,
                        int* __restrict__ row_off, int n, int E) {
    __shared__ int tmp[256];
    int b = blockIdx.x, t = threadIdx.x;
    int i = b * 256 + t;
    int own = (i < n) ? cnt[i] : 0;
    tmp[t] = own;
    __syncthreads();
    for (int off = 1; off < 256; off <<= 1) {
        int v = (t >= off) ? tmp[t - off] : 0;
        __syncthreads();
        tmp[t] += v;
        __syncthreads();
    }
    if (i < n) row_off[i] = bsum[b] + tmp[t] - own;
    if (b == 0 && t == 0) row_off[n] = E;
}

__global__ void scatter_k(const int* __restrict__ src, const int* __restrict__ dst,
                          const int* __restrict__ row_off, int* __restrict__ cur,
                          int* __restrict__ csr_src, int E) {
    int i = blockIdx.x * 256 + threadIdx.x;
    if (i < E) {
        int d = dst[i];
        int pos = row_off[d] + atomicAdd(&cur[d], 1);
        csr_src[pos] = src[i];
    }
}

// ---------------- attention layer 0: 8 heads x d=16, fp8 q/v, 512B rows ----------------
// lane l: feats 2l,2l+1 (head l>>3); 8-lane head reduce (3 shuffles). Unroll 4.
__global__ __launch_bounds__(256) void attn0_k(const unsigned char* __restrict__ qkv,
                                               const int* __restrict__ row_off,
                                               const int* __restrict__ csr,
                                               float* __restrict__ out, int n) {
    int w = (blockIdx.x * 256 + threadIdx.x) >> 6;
    int lane = threadIdx.x & 63;
    if (w >= n) return;
    int beg = row_off[w], end = row_off[w + 1];
    unsigned kv = *(const unsigned*)(qkv + (size_t)w * 512 + 128 + 4 * lane);
    const float KS = 0.25f / 16.f;                        // 1/sqrt(16) / q-scale
    float k0f = bf2f((u16)kv) * KS, k1f = bf2f((u16)(kv >> 16)) * KS;
    float den = 0.f, num0 = 0.f, num1 = 0.f;
    int e = beg;
    for (; e + 4 <= end; e += 4) {
        int s0 = csr[e], s1 = csr[e + 1], s2 = csr[e + 2], s3 = csr[e + 3];
        const unsigned char* r0 = qkv + (size_t)s0 * 512;
        const unsigned char* r1 = qkv + (size_t)s1 * 512;
        const unsigned char* r2 = qkv + (size_t)s2 * 512;
        const unsigned char* r3 = qkv + (size_t)s3 * 512;
        int qa = *(const unsigned short*)(r0 + 2 * lane);
        int qb = *(const unsigned short*)(r1 + 2 * lane);
        int qc = *(const unsigned short*)(r2 + 2 * lane);
        int qd = *(const unsigned short*)(r3 + 2 * lane);
        int va = *(const unsigned short*)(r0 + 384 + 2 * lane);
        int vb = *(const unsigned short*)(r1 + 384 + 2 * lane);
        int vc = *(const unsigned short*)(r2 + 384 + 2 * lane);
        int vd = *(const unsigned short*)(r3 + 384 + 2 * lane);
        f32x2 qaf = __builtin_amdgcn_cvt_pk_f32_fp8(qa, false);
        f32x2 qbf = __builtin_amdgcn_cvt_pk_f32_fp8(qb, false);
        f32x2 qcf = __builtin_amdgcn_cvt_pk_f32_fp8(qc, false);
        f32x2 qdf = __builtin_amdgcn_cvt_pk_f32_fp8(qd, false);
        float pa = qaf.x * k0f + qaf.y * k1f;
        float pb = qbf.x * k0f + qbf.y * k1f;
        float pc = qcf.x * k0f + qcf.y * k1f;
        float pd = qdf.x * k0f + qdf.y * k1f;
#pragma unroll
        for (int off = 1; off < 8; off <<= 1) {
            pa += __shfl_xor(pa, off); pb += __shfl_xor(pb, off);
            pc += __shfl_xor(pc, off); pd += __shfl_xor(pd, off);
        }
        float wa = __expf(pa), wb = __expf(pb);
        float wc = __expf(pc), wd = __expf(pd);
        den += (wa + wb) + (wc + wd);
        f32x2 vaf = __builtin_amdgcn_cvt_pk_f32_fp8(va, false);
        f32x2 vbf = __builtin_amdgcn_cvt_pk_f32_fp8(vb, false);
        f32x2 vcf = __builtin_amdgcn_cvt_pk_f32_fp8(vc, false);
        f32x2 vdf = __builtin_amdgcn_cvt_pk_f32_fp8(vd, false);
        num0 = fmaf(wa, vaf.x, num0); num1 = fmaf(wa, vaf.y, num1);
        num0 = fmaf(wb, vbf.x, num0); num1 = fmaf(wb, vbf.y, num1);
        num0 = fmaf(wc, vcf.x, num0); num1 = fmaf(wc, vcf.y, num1);
        num0 = fmaf(wd, vdf.x, num0); num1 = fmaf(wd, vdf.y, num1);
    }
    for (; e < end; ++e) {
        int s = csr[e];
        const unsigned char* r = qkv + (size_t)s * 512;
        int qv = *(const unsigned short*)(r + 2 * lane);
        f32x2 qf = __builtin_amdgcn_cvt_pk_f32_fp8(qv, false);
        float p = qf.x * k0f + qf.y * k1f;
        p += __shfl_xor(p, 1);
        p += __shfl_xor(p, 2);
        p += __shfl_xor(p, 4);
        float wt = __expf(p);
        den += wt;
        int vv = *(const unsigned short*)(r + 384 + 2 * lane);
        f32x2 vf = __builtin_amdgcn_cvt_pk_f32_fp8(vv, false);
        num0 = fmaf(wt, vf.x, num0); num1 = fmaf(wt, vf.y, num1);
    }
    float inv = (end > beg) ? (1.f / den) * (1.f / 16.f) : 0.f;   // v descale
    *(float2*)(out + ((size_t)w << 7) + 2 * lane) = make_float2(num0 * inv, num1 * inv);
}

// ---------------- attention layer 1 fused (one 4-head pass): d=64, 1024B rows ----------
// lane l: feats 4l..4l+3 (head l>>4); 16-lane head reduce (4 shuffles). Unroll 4.
template <bool FIRST>
__global__ __launch_bounds__(256) void attn1f_k(const unsigned char* __restrict__ qkv,
                                                const int* __restrict__ row_off,
                                                const int* __restrict__ csr,
                                                float* __restrict__ out, int n) {
    int w = (blockIdx.x * 256 + threadIdx.x) >> 6;
    int lane = threadIdx.x & 63;
    if (w >= n) return;
    int beg = row_off[w], end = row_off[w + 1];
    const float KS = 0.125f / 16.f;                       // 1/sqrt(64) / q-scale
    float kr0, kr1, kr2, kr3;
    {
        uint2 kk2 = *(const uint2*)(qkv + (size_t)w * 1024 + 256 + 8 * lane);
        kr0 = bf2f((u16)kk2.x) * KS; kr1 = bf2f((u16)(kk2.x >> 16)) * KS;
        kr2 = bf2f((u16)kk2.y) * KS; kr3 = bf2f((u16)(kk2.y >> 16)) * KS;
    }
    float den = 0.f, num0 = 0.f, num1 = 0.f, num2 = 0.f, num3 = 0.f;
    int e = beg;
    for (; e + 4 <= end; e += 4) {
        int s0 = csr[e], s1 = csr[e + 1], s2 = csr[e + 2], s3 = csr[e + 3];
        const unsigned char* r0 = qkv + (size_t)s0 * 1024;
        const unsigned char* r1 = qkv + (size_t)s1 * 1024;
        const unsigned char* r2 = qkv + (size_t)s2 * 1024;
        const unsigned char* r3 = qkv + (size_t)s3 * 1024;
        unsigned qa = *(const unsigned*)(r0 + 4 * lane);
        unsigned qb = *(const unsigned*)(r1 + 4 * lane);
        unsigned qc = *(const unsigned*)(r2 + 4 * lane);
        unsigned qd = *(const unsigned*)(r3 + 4 * lane);
        unsigned va = *(const unsigned*)(r0 + 768 + 4 * lane);
        unsigned vb = *(const unsigned*)(r1 + 768 + 4 * lane);
        unsigned vc = *(const unsigned*)(r2 + 768 + 4 * lane);
        unsigned vd = *(const unsigned*)(r3 + 768 + 4 * lane);
        f32x2 qa0 = __builtin_amdgcn_cvt_pk_f32_fp8((int)qa, false);
        f32x2 qa1 = __builtin_amdgcn_cvt_pk_f32_fp8((int)qa, true);
        f32x2 qb0 = __builtin_amdgcn_cvt_pk_f32_fp8((int)qb, false);
        f32x2 qb1 = __builtin_amdgcn_cvt_pk_f32_fp8((int)qb, true);
        f32x2 qc0 = __builtin_amdgcn_cvt_pk_f32_fp8((int)qc, false);
        f32x2 qc1 = __builtin_amdgcn_cvt_pk_f32_fp8((int)qc, true);
        f32x2 qd0 = __builtin_amdgcn_cvt_pk_f32_fp8((int)qd, false);
        f32x2 qd1 = __builtin_amdgcn_cvt_pk_f32_fp8((int)qd, true);
        float pa = qa0.x * kr0 + qa0.y * kr1 + qa1.x * kr2 + qa1.y * kr3;
        float pb = qb0.x * kr0 + qb0.y * kr1 + qb1.x * kr2 + qb1.y * kr3;
        float pc = qc0.x * kr0 + qc0.y * kr1 + qc1.x * kr2 + qc1.y * kr3;
        float pd = qd0.x * kr0 + qd0.y * kr1 + qd1.x * kr2 + qd1.y * kr3;
#pragma unroll
        for (int off = 1; off < 16; off <<= 1) {
            pa += __shfl_xor(pa, off); pb += __shfl_xor(pb, off);
            pc += __shfl_xor(pc, off); pd += __shfl_xor(pd, off);
        }
        float wa = __expf(pa), wb = __expf(pb);
        float wc = __expf(pc), wd = __expf(pd);
        den += (wa + wb) + (wc + wd);
        f32x2 va0 = __builtin_amdgcn_cvt_pk_f32_fp8((int)va, false);
        f32x2 va1 = __builtin_amdgcn_cvt_pk_f32_fp8((int)va, true);
        f32x2 vb0 = __builtin_amdgcn_cvt_pk_f32_fp8((int)vb, false);
        f32x2 vb1 = __builtin_amdgcn_cvt_pk_f32_fp8((int)vb, true);
        f32x2 vc0 = __builtin_amdgcn_cvt_pk_f32_fp8((int)vc, false);
        f32x2 vc1 = __builtin_amdgcn_cvt_pk_f32_fp8((int)vc, true);
        f32x2 vd0 = __builtin_amdgcn_cvt_pk_f32_fp8((int)vd, false);
        f32x2 vd1 = __builtin_amdgcn_cvt_pk_f32_fp8((int)vd, true);
        num0 = fmaf(wa, va0.x, num0); num1 = fmaf(wa, va0.y, num1);
        num2 = fmaf(wa, va1.x, num2); num3 = fmaf(wa, va1.y, num3);
        num0 = fmaf(wb, vb0.x, num0); num1 = fmaf(wb, vb0.y, num1);
        num2 = fmaf(wb, vb1.x, num2); num3 = fmaf(wb, vb1.y, num3);
        num0 = fmaf(wc, vc0.x, num0); num1 = fmaf(wc, vc0.y, num1);
        num2 = fmaf(wc, vc1.x, num2); num3 = fmaf(wc, vc1.y, num3);
        num0 = fmaf(wd, vd0.x, num0); num1 = fmaf(wd, vd0.y, num1);
        num2 = fmaf(wd, vd1.x, num2); num3 = fmaf(wd, vd1.y, num3);
    }
    for (; e < end; ++e) {
        int s = csr[e];
        const unsigned char* r = qkv + (size_t)s * 1024;
        unsigned qv = *(const unsigned*)(r + 4 * lane);
        f32x2 q0 = __builtin_amdgcn_cvt_pk_f32_fp8((int)qv, false);
        f32x2 q1 = __builtin_amdgcn_cvt_pk_f32_fp8((int)qv, true);
        float p = q0.x * kr0 + q0.y * kr1 + q1.x * kr2 + q1.y * kr3;
#pragma unroll
        for (int off = 1; off < 16; off <<= 1) p += __shfl_xor(p, off);
        float wt = __expf(p);
        den += wt;
        unsigned vv = *(const unsigned*)(r + 768 + 4 * lane);
        f32x2 v0 = __builtin_amdgcn_cvt_pk_f32_fp8((int)vv, false);
        f32x2 v1 = __builtin_amdgcn_cvt_pk_f32_fp8((int)vv, true);
        num0 = fmaf(wt, v0.x, num0); num1 = fmaf(wt, v0.y, num1);
        num2 = fmaf(wt, v1.x, num2); num3 = fmaf(wt, v1.y, num3);
    }
    float inv = (end > beg) ? 1.f / den : 0.f;
    float o0 = num0 * inv, o1 = num1 * inv, o2 = num2 * inv, o3 = num3 * inv;
    // sum the 4 heads (16-lane groups) at the same dim position
    o0 += __shfl_xor(o0, 16); o1 += __shfl_xor(o1, 16);
    o2 += __shfl_xor(o2, 16); o3 += __shfl_xor(o3, 16);
    o0 += __shfl_xor(o0, 32); o1 += __shfl_xor(o1, 32);
    o2 += __shfl_xor(o2, 32); o3 += __shfl_xor(o3, 32);
    if (lane < 16) {
        const float HS = 1.f / 128.f;   // head-mean (1/8) * v descale (1/16)
        float4* op = (float4*)(out + ((size_t)w << 6) + lane * 4);
        if (FIRST) {
            *op = make_float4(o0 * HS, o1 * HS, o2 * HS, o3 * HS);
        } else {
            float4 tv = *op;
            tv.x += o0 * HS; tv.y += o1 * HS; tv.z += o2 * HS; tv.w += o3 * HS;
            *op = tv;
        }
    }
}

// ---------------- gated residual + LN + relu (layer 0), bf16 h1 out ----------------
__global__ __launch_bounds__(256) void gres0_k(const float* __restrict__ x, const float* __restrict__ res,
                                               const float* __restrict__ gw,
                                               const float* __restrict__ lng, const float* __restrict__ lnb,
                                               u16* __restrict__ h1, int n) {
    int w = (blockIdx.x * 256 + threadIdx.x) >> 6;
    int lane = threadIdx.x & 63;
    if (w >= n) return;
    size_t base = (size_t)w * 128;
    float x1 = x[base + lane], x2 = x[base + lane + 64];
    float r1 = res[base + lane], r2 = res[base + lane + 64];
    float ca1 = gw[lane] + gw[256 + lane];
    float ca2 = gw[lane + 64] + gw[256 + lane + 64];
    float cr1 = gw[128 + lane] - gw[256 + lane];
    float cr2 = gw[128 + lane + 64] - gw[256 + lane + 64];
    float dot = x1 * ca1 + x2 * ca2 + r1 * cr1 + r2 * cr2;
#pragma unroll
    for (int off = 1; off < 64; off <<= 1) dot += __shfl_xor(dot, off);
    float g = 1.f / (1.f + __expf(-dot));
    float o1 = x1 * g + r1 * (1.f - g);
    float o2 = x2 * g + r2 * (1.f - g);
    float s = o1 + o2;
#pragma unroll
    for (int off = 1; off < 64; off <<= 1) s += __shfl_xor(s, off);
    float mu = s * (1.f / 128.f);
    float d1 = o1 - mu, d2 = o2 - mu;
    float vs = d1 * d1 + d2 * d2;
#pragma unroll
    for (int off = 1; off < 64; off <<= 1) vs += __shfl_xor(vs, off);
    float rstd = rsqrtf(vs * (1.f / 128.f) + 1e-5f);
    float y1 = d1 * rstd * lng[lane] + lnb[lane];
    float y2 = d2 * rstd * lng[lane + 64] + lnb[lane + 64];
    h1[base + lane] = f2bf(fmaxf(y1, 0.f));
    h1[base + lane + 64] = f2bf(fmaxf(y2, 0.f));
}

// ---------------- gated residual only (layer 1, d=64) ----------------
__global__ __launch_bounds__(256) void gres1_k(const float* __restrict__ x, const float* __restrict__ res,
                                               const float* __restrict__ gw,
                                               float* __restrict__ out, int n) {
    int w = (blockIdx.x * 256 + threadIdx.x) >> 6;
    int lane = threadIdx.x & 63;
    if (w >= n) return;
    size_t base = (size_t)w * 64;
    float xv = x[base + lane];
    float rv = res[base + lane];
    float ca = gw[lane] + gw[128 + lane];
    float cr = gw[64 + lane] - gw[128 + lane];
    float dot = xv * ca + rv * cr;
#pragma unroll
    for (int off = 1; off < 64; off <<= 1) dot += __shfl_xor(dot, off);
    float g = 1.f / (1.f + __expf(-dot));
    out[base + lane] = xv * g + rv * (1.f - g);
}

extern "C" void kernel_launch(void* const* d_in, const int* in_sizes, int n_in,
                              void* d_out, int out_size, void* d_ws, size_t ws_size,
                              hipStream_t stream) {
    const float* x    = (const float*)d_in[0];
    const int*   src  = (const int*)d_in[1];
    const int*   dst  = (const int*)d_in[2];
    const float* in_W = (const float*)d_in[3];
    const float* in_b = (const float*)d_in[4];
    const float* q0W = (const float*)d_in[5];  const float* q0b = (const float*)d_in[6];
    const float* k0W = (const float*)d_in[7];  const float* k0b = (const float*)d_in[8];
    const float* v0W = (const float*)d_in[9];  const float* v0b = (const float*)d_in[10];
    const float* r0W = (const float*)d_in[11]; const float* r0b = (const float*)d_in[12];
    const float* g0W = (const float*)d_in[13];
    const float* ln0g = (const float*)d_in[14]; const float* ln0b = (const float*)d_in[15];
    const float* q1W = (const float*)d_in[16]; const float* q1b = (const float*)d_in[17];
    const float* k1W = (const float*)d_in[18]; const float* k1b = (const float*)d_in[19];
    const float* v1W = (const float*)d_in[20]; const float* v1b = (const float*)d_in[21];
    const float* r1W = (const float*)d_in[22]; const float* r1b = (const float*)d_in[23];
    const float* g1W = (const float*)d_in[24];

    const int N = in_sizes[0] / 256;   // 100000
    const int E = in_sizes[1];         // 1600000
    (void)ws_size; (void)n_in; (void)out_size;

    // ---- workspace layout with reuse: peak ~186 MB ----
    auto rnd = [](size_t b) { return (b + 255) & ~(size_t)255; };
    char* base = (char*)d_ws;
    const size_t S_bf = rnd((size_t)N * 128 * 2);   // 25.6 MB
    const size_t S_f  = rnd((size_t)N * 128 * 4);   // 51.2 MB
    size_t o = 0;
    int* row_off = (int*)(base + o); o += rnd(((size_t)N + 1) * 4);
    int* csr     = (int*)(base + o); o += rnd((size_t)E * 4);
    u16* warena  = (u16*)(base + o); o += rnd((size_t)303104 * 2);
    float* barena = (float*)(base + o); o += rnd((size_t)2112 * 4);
    const size_t R0 = o;                 // 51.2: cnt/cur/bsum -> h -> a0 -> {res1o, a1}
    const size_t R1 = R0 + S_f;          // 76.8: x_bf(slots0-1) -> QKV0(slots0-1) -> h1(slot0)+PASS(slots1-2..)
    const size_t R2 = R1 + 3 * S_bf;     // 51.2: res0o -> PASS tail
    int* cnt  = (int*)(base + R0);
    int* cur  = (int*)(base + R0 + rnd((size_t)N * 4));
    int* bsum = (int*)(base + R0 + 2 * rnd((size_t)N * 4));
    u16*   h     = (u16*)(base + R0);
    float* a0    = (float*)(base + R0);
    float* res1o = (float*)(base + R0);
    float* a1    = (float*)(base + R0 + rnd((size_t)N * 64 * 4));
    u16* x_bf = (u16*)(base + R1);                       // N x 256 bf16, dies after in-GEMM
    unsigned char* QKV0 = (unsigned char*)(base + R1);   // N x 512 B (slots 0-1)
    u16* h1   = (u16*)(base + R1);                       // N x 128 bf16 (slot 0, after QKV0 dead)
    unsigned char* PASS = (unsigned char*)(base + R1 + S_bf);  // N x 1024 B (slots 1-2 + R2)
    float* res0o = (float*)(base + R2);                  // dead after gres0 (before PASS written)

    // weight arena sections
    u16* inWt   = warena;
    u16* qkv0t  = warena + 32768;      // rows 0..383 qkv0, 384..511 r0 (contiguous)
    u16* qkv1t0 = warena + 98304;      // pass0 rows 0..767
    u16* qkv1t1 = warena + 196608;     // pass1 rows 0..767, 768..831 = r1t (contiguous)

    dim3 blk(256);
    int nwb = (N * 64 + 255) / 256;   // one wave per node
    int nb  = (N + 255) / 256;        // 391 (<= 512)
    int mb  = (N + 127) / 128;        // 782
    int xch = (mb + 7) / 8;           // 98 (XCD-swizzled grid chunk count)

    // ---- prep (weights/bias/x convert) ----
    prep_k<<<(303104 + 255) / 256, blk, 0, stream>>>(in_W, q0W, k0W, v0W, r0W,
                                                     q1W, k1W, v1W, r1W, warena);
    bias_k<<<9, blk, 0, stream>>>(q0b, k0b, v0b, r0b, q1b, k1b, v1b, r1b, barena);
    cvt_k<<<(N * 32 + 255) / 256, blk, 0, stream>>>(x, x_bf, N * 32);

    // ---- CSR build ----
    zero2_k<<<nb, blk, 0, stream>>>(cnt, cur, N);
    hist_k<<<(E + 255) / 256, blk, 0, stream>>>(dst, cnt, E);
    blocksum_k<<<nb, blk, 0, stream>>>(cnt, bsum, N);
    scanb_k<<<1, 512, 0, stream>>>(bsum, nb);
    scanc_k<<<nb, blk, 0, stream>>>(cnt, bsum, row_off, N, E);
    scatter_k<<<(E + 255) / 256, blk, 0, stream>>>(src, dst, row_off, cur, csr, E);

    // ---- layer 0 ----
    mgemm7<0, 256><<<8 * 1 * xch, blk, 0, stream>>>(x_bf, inWt, in_b, h, nullptr,
                                                    N, mb, 1, 128);
    mgemm7<1, 128><<<8 * 4 * xch, blk, 0, stream>>>(h, qkv0t, barena, QKV0, res0o,
                                                    N, mb, 4, 512);
    attn0_k<<<nwb, blk, 0, stream>>>(QKV0, row_off, csr, a0, N);
    gres0_k<<<nwb, blk, 0, stream>>>(a0, res0o, g0W, ln0g, ln0b, h1, N);

    // ---- layer 1: pass0 (qkv), attn; pass1 (qkv + r1), attn; gres ----
    mgemm7<2, 128><<<8 * 6 * xch, blk, 0, stream>>>(h1, qkv1t0, barena + 512, PASS,
                                                    nullptr, N, mb, 6, 768);
    attn1f_k<true><<<nwb, blk, 0, stream>>>(PASS, row_off, csr, a1, N);

    mgemm7<3, 128><<<8 * 7 * xch, blk, 0, stream>>>(h1, qkv1t1, barena + 1280, PASS,
                                                    res1o, N, mb, 7, 832);
    attn1f_k<false><<<nwb, blk, 0, stream>>>(PASS, row_off, csr, a1, N);

    gres1_k<<<nwb, blk, 0, stream>>>(a1, res1o, g1W, (float*)d_out, N);
}

// Round 15
// 773.782 us; speedup vs baseline: 1.7175x; 1.0380x over previous
//
#include <hip/hip_runtime.h>

// GraphTransformerModel: 2-layer graph attention network.
// CSR build -> bf16 MFMA GEMMs (mgemm7: XCD-swizzled blocks, fused dispatches,
// global_load_lds + XOR swizzle, LDS-staged coalesced fp8+bf16 epilogues)
// -> attn0 (fp8 q/v, 512B rows) -> gres0+LN
// -> 2x {qkv1 4-head GEMM (1024B rows) -> attn1f} -> gres1.
// fp8 = e4m3 x16 scale, HW encode/decode. Peak workspace ~186 MB.

typedef unsigned short u16;
typedef __attribute__((ext_vector_type(8))) unsigned short ushort8;
typedef __attribute__((ext_vector_type(8))) short short8v;   // 8 bf16 (4 VGPRs)
typedef __attribute__((ext_vector_type(4))) float f32x4;
typedef __attribute__((ext_vector_type(2))) float f32x2;

__device__ __forceinline__ float bf2f(unsigned short u) {
    return __uint_as_float(((unsigned)u) << 16);
}
__device__ __forceinline__ unsigned short f2bf(float f) {
    unsigned u = __float_as_uint(f);
    unsigned r = 0x7fffu + ((u >> 16) & 1u);   // round-to-nearest-even
    return (unsigned short)((u + r) >> 16);
}
__device__ __forceinline__ unsigned char f2fp8(float f) {   // HW e4m3 encode
    return (unsigned char)__builtin_amdgcn_cvt_pk_fp8_f32(f, 0.f, 0, false);
}

// async global->LDS, 16B per lane; dest is wave-uniform base + lane*16 (HW).
__device__ __forceinline__ void gload16(const void* gp, const void* lp) {
    __builtin_amdgcn_global_load_lds(
        (const __attribute__((address_space(1))) unsigned*)(uintptr_t)gp,
        (__attribute__((address_space(3))) unsigned*)(unsigned)(uintptr_t)lp,
        16, 0, 0);
}

// ---------------- fused weight prep ----------------
// arena (u16): [0)=inWt[128][256]  [32768)=qkv0t[384][128]  [81920)=r0t[128][128]
//              [98304)=qkv1t[2][768][128]  [294912)=r1t[64][128]  total 303104
// Contiguity exploited: {qkv0t,r0t} = 512 rows; {qkv1t_p1,r1t} = 832 rows.
__global__ void prep_k(const float* __restrict__ inW,
                       const float* __restrict__ q0W, const float* __restrict__ k0W,
                       const float* __restrict__ v0W, const float* __restrict__ r0W,
                       const float* __restrict__ q1W, const float* __restrict__ k1W,
                       const float* __restrict__ v1W, const float* __restrict__ r1W,
                       u16* __restrict__ arena) {
    int i = blockIdx.x * 256 + threadIdx.x;
    if (i >= 303104) return;
    float val;
    if (i < 32768) {                       // inWt[n][k] = inW[k][n], K=256, N=128
        int n = i >> 8, k = i & 255;
        val = inW[k * 128 + n];
    } else if (i < 81920) {                // qkv0t [384][128]
        int j = i - 32768;
        int r = j >> 7, kk = j & 127;
        int sec = r >> 7, c = r & 127;
        const float* s = (sec == 0) ? q0W : (sec == 1) ? k0W : v0W;
        val = s[kk * 128 + c];
    } else if (i < 98304) {                // r0t [128][128]
        int j = i - 81920;
        int r = j >> 7, kk = j & 127;
        val = r0W[kk * 128 + r];
    } else if (i < 294912) {               // qkv1t [2][768][128]: pass p covers cols p*256..+255
        int j = i - 98304;
        int row = j >> 7, kk = j & 127;
        int p = row / 768, rr = row - p * 768;
        int sec = rr >> 8, c = p * 256 + (rr & 255);
        const float* s = (sec == 0) ? q1W : (sec == 1) ? k1W : v1W;
        val = s[kk * 512 + c];
    } else {                               // r1t [64][128]
        int j = i - 294912;
        int n = j >> 7, kk = j & 127;
        val = r1W[kk * 64 + n];
    }
    arena[i] = f2bf(val);
}

// fused biases (2112 floats):
// [0)=qkv0b[384] [384)=r0b[128] [512)=qkv1b_p0[768] [1280)=qkv1b_p1[768] [2048)=r1b[64]
__global__ void bias_k(const float* __restrict__ q0b, const float* __restrict__ k0b,
                       const float* __restrict__ v0b, const float* __restrict__ r0b,
                       const float* __restrict__ q1b, const float* __restrict__ k1b,
                       const float* __restrict__ v1b, const float* __restrict__ r1b,
                       float* __restrict__ out) {
    int i = blockIdx.x * 256 + threadIdx.x;
    if (i >= 2112) return;
    if (i < 384) {
        int sec = i >> 7, c = i & 127;
        out[i] = (sec == 0) ? q0b[c] : (sec == 1) ? k0b[c] : v0b[c];
    } else if (i < 512) {
        out[i] = r0b[i - 384];
    } else if (i < 2048) {
        int j = i - 512;
        int p = j / 768, rr = j - p * 768;
        int sec = rr >> 8, c = p * 256 + (rr & 255);
        out[i] = (sec == 0) ? q1b[c] : (sec == 1) ? k1b[c] : v1b[c];
    } else {
        out[i] = r1b[i - 2048];
    }
}

// ---------------- f32 -> bf16 convert (8 elems/thread) ----------------
__global__ void cvt_k(const float* __restrict__ in, u16* __restrict__ out, int n8) {
    int i = blockIdx.x * 256 + threadIdx.x;
    if (i >= n8) return;
    float4 a = *(const float4*)(in + (size_t)i * 8);
    float4 b = *(const float4*)(in + (size_t)i * 8 + 4);
    ushort8 o = {f2bf(a.x), f2bf(a.y), f2bf(a.z), f2bf(a.w),
                 f2bf(b.x), f2bf(b.y), f2bf(b.z), f2bf(b.w)};
    *(ushort8*)(out + (size_t)i * 8) = o;
}

// ---------------- MFMA GEMM v7: XCD-swizzled, fused multi-section ----------------
// C_cols = A[M,K](bf16) @ Bt[Nvalid,K](bf16)^T + bias.  1D grid = 8*ny*ceil(MB/8);
// block id decodes so all ny column-blocks of one A-tile share id%8 (same XCD ->
// A-tile L2-resident).  128x128 tiles, BK=64 via global_load_lds, XOR swizzle.
// fp8 sections: LDS byte tile [128][144] (16B-chunk XOR swizzle), 128B-row bursts.
// bf16 sections: LDS tile [128][272B], 256B-row bursts (16 chunks).
// MODE 0: bf16 C [M,128] (staged)
// MODE 1: layer0 combo: sec 0,2 fp8; sec 1 bf16 k (staged); sec 3 -> f32 C2 [M,128]
// MODE 2: layer1 pass:  sec 0-1,4-5 fp8; sec 2-3 bf16 k (staged)
// MODE 3: layer1 pass+aux: like MODE2; sec 6 -> f32 C2 [M,64]
template <int MODE, int K>
__global__ __launch_bounds__(256) void mgemm7(const u16* __restrict__ A,
                                              const u16* __restrict__ Bt,
                                              const float* __restrict__ bias,
                                              void* __restrict__ C,
                                              float* __restrict__ C2,
                                              int M, int MB, int ny, int Nvalid) {
    __shared__ __align__(16) unsigned char smem[36864];   // As 16K | Bs 16K; epi tile reuse
    u16* As = (u16*)smem;
    u16* Bs = (u16*)(smem + 16384);
    int id = blockIdx.x;
    int xcd = id & 7, rest = id >> 3;
    int y = rest % ny;
    int x = (rest / ny) * 8 + xcd;
    if (x >= MB) return;
    const int bm = x * 128;
    const int bn = y * 128;
    const int t = threadIdx.x, lane = t & 63, wid = t >> 6;
    const int wm = (wid >> 1) * 64, wn = (wid & 1) * 64;
    const int jlog = ((lane & 7) ^ (lane >> 3)) * 8;
    f32x4 acc[4][4] = {};
    for (int k0 = 0; k0 < K; k0 += 64) {
#pragma unroll
        for (int c2 = 0; c2 < 4; ++c2) {
            int seg = c2 * 4 + wid;
            int row = seg * 8 + (lane >> 3);
            int ga = bm + row; if (ga >= M) ga = 0;
            gload16(A + (size_t)ga * K + k0 + jlog, (const char*)As + seg * 1024);
            int gb = bn + row; if (gb >= Nvalid) gb = 0;
            gload16(Bt + (size_t)gb * K + k0 + jlog, (const char*)Bs + seg * 1024);
        }
        __syncthreads();
#pragma unroll
        for (int ks = 0; ks < 2; ++ks) {
            const int jx = ks * 4 + (lane >> 4);
            short8v af[4], bfr[4];
#pragma unroll
            for (int i = 0; i < 4; ++i) {
                int ra = wm + i * 16 + (lane & 15);
                af[i] = *(const short8v*)((const char*)As + ra * 128 + ((jx ^ (ra & 7)) << 4));
                int rb = wn + i * 16 + (lane & 15);
                bfr[i] = *(const short8v*)((const char*)Bs + rb * 128 + ((jx ^ (rb & 7)) << 4));
            }
#pragma unroll
            for (int mi = 0; mi < 4; ++mi)
#pragma unroll
                for (int ni = 0; ni < 4; ++ni)
                    acc[mi][ni] = __builtin_amdgcn_mfma_f32_16x16x32_bf16(
                        af[mi], bfr[ni], acc[mi][ni], 0, 0, 0);
        }
        if (k0 + 64 < K) __syncthreads();
    }
    const int sec = y;
    // ---- classify section ----
    // fp8 staged sections
    bool fp8lds = false;
    int gsecoff = 0, rowbytes = 0;
    if (MODE == 1) {
        if (sec == 0)      { fp8lds = true; gsecoff = 0;   rowbytes = 512; }
        else if (sec == 2) { fp8lds = true; gsecoff = 384; rowbytes = 512; }
    } else if (MODE >= 2) {
        if (sec < 2)                  { fp8lds = true; gsecoff = sec * 128;             rowbytes = 1024; }
        else if (sec >= 4 && sec < 6) { fp8lds = true; gsecoff = 768 + (sec - 4) * 128; rowbytes = 1024; }
    }
    if (fp8lds) {
        unsigned char* tile = smem;                 // 128 rows x 144B stride = 18 KB
        __syncthreads();                            // all waves done with As/Bs reads
#pragma unroll
        for (int ni = 0; ni < 4; ++ni) {
            int lcol = wn + ni * 16 + (lane & 15);
            float bs = bias[bn + lcol];
#pragma unroll
            for (int mi = 0; mi < 4; ++mi) {
#pragma unroll
                for (int j = 0; j < 4; ++j) {
                    int lrow = wm + mi * 16 + (lane >> 4) * 4 + j;
                    float val = acc[mi][ni][j] + bs;
                    tile[lrow * 144 + ((((lcol >> 4) ^ (lrow & 7)) << 4) | (lcol & 15))] =
                        f2fp8(val * 16.f);
                }
            }
        }
        __syncthreads();
#pragma unroll
        for (int it = 0; it < 4; ++it) {            // 1024 chunks of 16B
            int lin = it * 256 + t;
            int row = lin >> 3, ch = lin & 7;
            int crow = bm + row;
            if (crow < M) {
                const float4 vsrc = *(const float4*)(tile + row * 144 + ((ch ^ (row & 7)) << 4));
                *(float4*)((unsigned char*)C + (size_t)crow * rowbytes + gsecoff + ch * 16) = vsrc;
            }
        }
        return;
    }
    // bf16 staged sections (full 256B rows)
    bool bf16lds = false;
    if (MODE == 0)                         { bf16lds = true; gsecoff = 0;   rowbytes = 256; }
    else if (MODE == 1 && sec == 1)        { bf16lds = true; gsecoff = 128; rowbytes = 512; }
    else if (MODE >= 2 && sec >= 2 && sec < 4) {
        bf16lds = true; gsecoff = 256 + (sec - 2) * 256; rowbytes = 1024;
    }
    if (bf16lds) {
        unsigned char* tile = smem;                 // 128 rows x 272B stride = 34.8 KB
        __syncthreads();
#pragma unroll
        for (int ni = 0; ni < 4; ++ni) {
            int lcol = wn + ni * 16 + (lane & 15);
            float bs = bias[bn + lcol];
            int by = lcol * 2, ch = by >> 4;
#pragma unroll
            for (int mi = 0; mi < 4; ++mi) {
#pragma unroll
                for (int j = 0; j < 4; ++j) {
                    int lrow = wm + mi * 16 + (lane >> 4) * 4 + j;
                    float val = acc[mi][ni][j] + bs;
                    *(u16*)(tile + lrow * 272 + ((ch ^ (lrow & 7)) << 4) + (by & 15)) = f2bf(val);
                }
            }
        }
        __syncthreads();
#pragma unroll
        for (int it = 0; it < 8; ++it) {            // 2048 chunks of 16B
            int lin = it * 256 + t;
            int row = lin >> 4, ch = lin & 15;
            int crow = bm + row;
            if (crow < M) {
                const float4 vsrc = *(const float4*)(tile + row * 272 + ((ch ^ (row & 7)) << 4));
                *(float4*)((unsigned char*)C + (size_t)crow * rowbytes + gsecoff + ch * 16) = vsrc;
            }
        }
        return;
    }
    // ---- remaining sections: direct f32 stores ----
#pragma unroll
    for (int ni = 0; ni < 4; ++ni) {
        int lcol = wn + ni * 16 + (lane & 15);   // 0..127 within section
        int ccol = bn + lcol;
        if (ccol >= Nvalid) continue;
        float bs = bias[ccol];
#pragma unroll
        for (int mi = 0; mi < 4; ++mi) {
#pragma unroll
            for (int j = 0; j < 4; ++j) {
                int crow = bm + wm + mi * 16 + (lane >> 4) * 4 + j;
                if (crow >= M) continue;
                float val = acc[mi][ni][j] + bs;
                if (MODE == 1) {          // sec == 3: res0o f32 [M,128]
                    C2[(size_t)crow * 128 + lcol] = val;
                } else {                  // MODE 3, sec == 6: res1o f32 [M,64]
                    C2[(size_t)crow * 64 + lcol] = val;
                }
            }
        }
    }
}

// ---------------- CSR build ----------------
__global__ void zero2_k(int* __restrict__ a, int* __restrict__ b, int n) {
    int i = blockIdx.x * 256 + threadIdx.x;
    if (i < n) { a[i] = 0; b[i] = 0; }
}

__global__ void hist_k(const int* __restrict__ dst, int* __restrict__ cnt, int E) {
    int i = blockIdx.x * 256 + threadIdx.x;
    if (i < E) atomicAdd(&cnt[dst[i]], 1);
}

__global__ void blocksum_k(const int* __restrict__ cnt, int* __restrict__ bsum, int n) {
    __shared__ int sd[256];
    int i = blockIdx.x * 256 + threadIdx.x;
    sd[threadIdx.x] = (i < n) ? cnt[i] : 0;
    __syncthreads();
    for (int off = 128; off > 0; off >>= 1) {
        if (threadIdx.x < off) sd[threadIdx.x] += sd[threadIdx.x + off];
        __syncthreads();
    }
    if (threadIdx.x == 0) bsum[blockIdx.x] = sd[0];
}

__global__ void scanb_k(int* bsum, int nb) {
    __shared__ int tmp[512];
    int t = threadIdx.x;
    tmp[t] = (t < nb) ? bsum[t] : 0;
    __syncthreads();
    for (int off = 1; off < 512; off <<= 1) {
        int v = (t >= off) ? tmp[t - off] : 0;
        __syncthreads();
        tmp[t] += v;
        __syncthreads();
    }
    if (t < nb) bsum[t] = (t ? tmp[t - 1] : 0);
}

__global__ void scanc_k(const int* __restrict__ cnt, const int* __restrict__ bsum,
                        int* __restrict__ row_off, int n, int E) {
    __shared__ int tmp[256];
    int b = blockIdx.x, t = threadIdx.x;
    int i = b * 256 + t;
    int own = (i < n) ? cnt[i] : 0;
    tmp[t] = own;
    __syncthreads();
    for (int off = 1; off < 256; off <<= 1) {
        int v = (t >= off) ? tmp[t - off] : 0;
        __syncthreads();
        tmp[t] += v;
        __syncthreads();
    }
    if (i < n) row_off[i] = bsum[b] + tmp[t] - own;
    if (b == 0 && t == 0) row_off[n] = E;
}

__global__ void scatter_k(const int* __restrict__ src, const int* __restrict__ dst,
                          const int* __restrict__ row_off, int* __restrict__ cur,
                          int* __restrict__ csr_src, int E) {
    int i = blockIdx.x * 256 + threadIdx.x;
    if (i < E) {
        int d = dst[i];
        int pos = row_off[d] + atomicAdd(&cur[d], 1);
        csr_src[pos] = src[i];
    }
}

// ---------------- attention layer 0: 8 heads x d=16, fp8 q/v, 512B rows ----------------
// lane l: feats 2l,2l+1 (head l>>3); 8-lane head reduce (3 shuffles). Unroll 4.
__global__ __launch_bounds__(256) void attn0_k(const unsigned char* __restrict__ qkv,
                                               const int* __restrict__ row_off,
                                               const int* __restrict__ csr,
                                               float* __restrict__ out, int n) {
    int w = (blockIdx.x * 256 + threadIdx.x) >> 6;
    int lane = threadIdx.x & 63;
    if (w >= n) return;
    int beg = row_off[w], end = row_off[w + 1];
    unsigned kv = *(const unsigned*)(qkv + (size_t)w * 512 + 128 + 4 * lane);
    const float KS = 0.25f / 16.f;                        // 1/sqrt(16) / q-scale
    float k0f = bf2f((u16)kv) * KS, k1f = bf2f((u16)(kv >> 16)) * KS;
    float den = 0.f, num0 = 0.f, num1 = 0.f;
    int e = beg;
    for (; e + 4 <= end; e += 4) {
        int s0 = csr[e], s1 = csr[e + 1], s2 = csr[e + 2], s3 = csr[e + 3];
        const unsigned char* r0 = qkv + (size_t)s0 * 512;
        const unsigned char* r1 = qkv + (size_t)s1 * 512;
        const unsigned char* r2 = qkv + (size_t)s2 * 512;
        const unsigned char* r3 = qkv + (size_t)s3 * 512;
        int qa = *(const unsigned short*)(r0 + 2 * lane);
        int qb = *(const unsigned short*)(r1 + 2 * lane);
        int qc = *(const unsigned short*)(r2 + 2 * lane);
        int qd = *(const unsigned short*)(r3 + 2 * lane);
        int va = *(const unsigned short*)(r0 + 384 + 2 * lane);
        int vb = *(const unsigned short*)(r1 + 384 + 2 * lane);
        int vc = *(const unsigned short*)(r2 + 384 + 2 * lane);
        int vd = *(const unsigned short*)(r3 + 384 + 2 * lane);
        f32x2 qaf = __builtin_amdgcn_cvt_pk_f32_fp8(qa, false);
        f32x2 qbf = __builtin_amdgcn_cvt_pk_f32_fp8(qb, false);
        f32x2 qcf = __builtin_amdgcn_cvt_pk_f32_fp8(qc, false);
        f32x2 qdf = __builtin_amdgcn_cvt_pk_f32_fp8(qd, false);
        float pa = qaf.x * k0f + qaf.y * k1f;
        float pb = qbf.x * k0f + qbf.y * k1f;
        float pc = qcf.x * k0f + qcf.y * k1f;
        float pd = qdf.x * k0f + qdf.y * k1f;
#pragma unroll
        for (int off = 1; off < 8; off <<= 1) {
            pa += __shfl_xor(pa, off); pb += __shfl_xor(pb, off);
            pc += __shfl_xor(pc, off); pd += __shfl_xor(pd, off);
        }
        float wa = __expf(pa), wb = __expf(pb);
        float wc = __expf(pc), wd = __expf(pd);
        den += (wa + wb) + (wc + wd);
        f32x2 vaf = __builtin_amdgcn_cvt_pk_f32_fp8(va, false);
        f32x2 vbf = __builtin_amdgcn_cvt_pk_f32_fp8(vb, false);
        f32x2 vcf = __builtin_amdgcn_cvt_pk_f32_fp8(vc, false);
        f32x2 vdf = __builtin_amdgcn_cvt_pk_f32_fp8(vd, false);
        num0 = fmaf(wa, vaf.x, num0); num1 = fmaf(wa, vaf.y, num1);
        num0 = fmaf(wb, vbf.x, num0); num1 = fmaf(wb, vbf.y, num1);
        num0 = fmaf(wc, vcf.x, num0); num1 = fmaf(wc, vcf.y, num1);
        num0 = fmaf(wd, vdf.x, num0); num1 = fmaf(wd, vdf.y, num1);
    }
    for (; e < end; ++e) {
        int s = csr[e];
        const unsigned char* r = qkv + (size_t)s * 512;
        int qv = *(const unsigned short*)(r + 2 * lane);
        f32x2 qf = __builtin_amdgcn_cvt_pk_f32_fp8(qv, false);
        float p = qf.x * k0f + qf.y * k1f;
        p += __shfl_xor(p, 1);
        p += __shfl_xor(p, 2);
        p += __shfl_xor(p, 4);
        float wt = __expf(p);
        den += wt;
        int vv = *(const unsigned short*)(r + 384 + 2 * lane);
        f32x2 vf = __builtin_amdgcn_cvt_pk_f32_fp8(vv, false);
        num0 = fmaf(wt, vf.x, num0); num1 = fmaf(wt, vf.y, num1);
    }
    float inv = (end > beg) ? (1.f / den) * (1.f / 16.f) : 0.f;   // v descale
    *(float2*)(out + ((size_t)w << 7) + 2 * lane) = make_float2(num0 * inv, num1 * inv);
}

// ---------------- attention layer 1 fused (one 4-head pass): d=64, 1024B rows ----------
// lane l: feats 4l..4l+3 (head l>>4); 16-lane head reduce (4 shuffles). Unroll 4.
template <bool FIRST>
__global__ __launch_bounds__(256) void attn1f_k(const unsigned char* __restrict__ qkv,
                                                const int* __restrict__ row_off,
                                                const int* __restrict__ csr,
                                                float* __restrict__ out, int n) {
    int w = (blockIdx.x * 256 + threadIdx.x) >> 6;
    int lane = threadIdx.x & 63;
    if (w >= n) return;
    int beg = row_off[w], end = row_off[w + 1];
    const float KS = 0.125f / 16.f;                       // 1/sqrt(64) / q-scale
    float kr0, kr1, kr2, kr3;
    {
        uint2 kk2 = *(const uint2*)(qkv + (size_t)w * 1024 + 256 + 8 * lane);
        kr0 = bf2f((u16)kk2.x) * KS; kr1 = bf2f((u16)(kk2.x >> 16)) * KS;
        kr2 = bf2f((u16)kk2.y) * KS; kr3 = bf2f((u16)(kk2.y >> 16)) * KS;
    }
    float den = 0.f, num0 = 0.f, num1 = 0.f, num2 = 0.f, num3 = 0.f;
    int e = beg;
    for (; e + 4 <= end; e += 4) {
        int s0 = csr[e], s1 = csr[e + 1], s2 = csr[e + 2], s3 = csr[e + 3];
        const unsigned char* r0 = qkv + (size_t)s0 * 1024;
        const unsigned char* r1 = qkv + (size_t)s1 * 1024;
        const unsigned char* r2 = qkv + (size_t)s2 * 1024;
        const unsigned char* r3 = qkv + (size_t)s3 * 1024;
        unsigned qa = *(const unsigned*)(r0 + 4 * lane);
        unsigned qb = *(const unsigned*)(r1 + 4 * lane);
        unsigned qc = *(const unsigned*)(r2 + 4 * lane);
        unsigned qd = *(const unsigned*)(r3 + 4 * lane);
        unsigned va = *(const unsigned*)(r0 + 768 + 4 * lane);
        unsigned vb = *(const unsigned*)(r1 + 768 + 4 * lane);
        unsigned vc = *(const unsigned*)(r2 + 768 + 4 * lane);
        unsigned vd = *(const unsigned*)(r3 + 768 + 4 * lane);
        f32x2 qa0 = __builtin_amdgcn_cvt_pk_f32_fp8((int)qa, false);
        f32x2 qa1 = __builtin_amdgcn_cvt_pk_f32_fp8((int)qa, true);
        f32x2 qb0 = __builtin_amdgcn_cvt_pk_f32_fp8((int)qb, false);
        f32x2 qb1 = __builtin_amdgcn_cvt_pk_f32_fp8((int)qb, true);
        f32x2 qc0 = __builtin_amdgcn_cvt_pk_f32_fp8((int)qc, false);
        f32x2 qc1 = __builtin_amdgcn_cvt_pk_f32_fp8((int)qc, true);
        f32x2 qd0 = __builtin_amdgcn_cvt_pk_f32_fp8((int)qd, false);
        f32x2 qd1 = __builtin_amdgcn_cvt_pk_f32_fp8((int)qd, true);
        float pa = qa0.x * kr0 + qa0.y * kr1 + qa1.x * kr2 + qa1.y * kr3;
        float pb = qb0.x * kr0 + qb0.y * kr1 + qb1.x * kr2 + qb1.y * kr3;
        float pc = qc0.x * kr0 + qc0.y * kr1 + qc1.x * kr2 + qc1.y * kr3;
        float pd = qd0.x * kr0 + qd0.y * kr1 + qd1.x * kr2 + qd1.y * kr3;
#pragma unroll
        for (int off = 1; off < 16; off <<= 1) {
            pa += __shfl_xor(pa, off); pb += __shfl_xor(pb, off);
            pc += __shfl_xor(pc, off); pd += __shfl_xor(pd, off);
        }
        float wa = __expf(pa), wb = __expf(pb);
        float wc = __expf(pc), wd = __expf(pd);
        den += (wa + wb) + (wc + wd);
        f32x2 va0 = __builtin_amdgcn_cvt_pk_f32_fp8((int)va, false);
        f32x2 va1 = __builtin_amdgcn_cvt_pk_f32_fp8((int)va, true);
        f32x2 vb0 = __builtin_amdgcn_cvt_pk_f32_fp8((int)vb, false);
        f32x2 vb1 = __builtin_amdgcn_cvt_pk_f32_fp8((int)vb, true);
        f32x2 vc0 = __builtin_amdgcn_cvt_pk_f32_fp8((int)vc, false);
        f32x2 vc1 = __builtin_amdgcn_cvt_pk_f32_fp8((int)vc, true);
        f32x2 vd0 = __builtin_amdgcn_cvt_pk_f32_fp8((int)vd, false);
        f32x2 vd1 = __builtin_amdgcn_cvt_pk_f32_fp8((int)vd, true);
        num0 = fmaf(wa, va0.x, num0); num1 = fmaf(wa, va0.y, num1);
        num2 = fmaf(wa, va1.x, num2); num3 = fmaf(wa, va1.y, num3);
        num0 = fmaf(wb, vb0.x, num0); num1 = fmaf(wb, vb0.y, num1);
        num2 = fmaf(wb, vb1.x, num2); num3 = fmaf(wb, vb1.y, num3);
        num0 = fmaf(wc, vc0.x, num0); num1 = fmaf(wc, vc0.y, num1);
        num2 = fmaf(wc, vc1.x, num2); num3 = fmaf(wc, vc1.y, num3);
        num0 = fmaf(wd, vd0.x, num0); num1 = fmaf(wd, vd0.y, num1);
        num2 = fmaf(wd, vd1.x, num2); num3 = fmaf(wd, vd1.y, num3);
    }
    for (; e < end; ++e) {
        int s = csr[e];
        const unsigned char* r = qkv + (size_t)s * 1024;
        unsigned qv = *(const unsigned*)(r + 4 * lane);
        f32x2 q0 = __builtin_amdgcn_cvt_pk_f32_fp8((int)qv, false);
        f32x2 q1 = __builtin_amdgcn_cvt_pk_f32_fp8((int)qv, true);
        float p = q0.x * kr0 + q0.y * kr1 + q1.x * kr2 + q1.y * kr3;
#pragma unroll
        for (int off = 1; off < 16; off <<= 1) p += __shfl_xor(p, off);
        float wt = __expf(p);
        den += wt;
        unsigned vv = *(const unsigned*)(r + 768 + 4 * lane);
        f32x2 v0 = __builtin_amdgcn_cvt_pk_f32_fp8((int)vv, false);
        f32x2 v1 = __builtin_amdgcn_cvt_pk_f32_fp8((int)vv, true);
        num0 = fmaf(wt, v0.x, num0); num1 = fmaf(wt, v0.y, num1);
        num2 = fmaf(wt, v1.x, num2); num3 = fmaf(wt, v1.y, num3);
    }
    float inv = (end > beg) ? 1.f / den : 0.f;
    float o0 = num0 * inv, o1 = num1 * inv, o2 = num2 * inv, o3 = num3 * inv;
    // sum the 4 heads (16-lane groups) at the same dim position
    o0 += __shfl_xor(o0, 16); o1 += __shfl_xor(o1, 16);
    o2 += __shfl_xor(o2, 16); o3 += __shfl_xor(o3, 16);
    o0 += __shfl_xor(o0, 32); o1 += __shfl_xor(o1, 32);
    o2 += __shfl_xor(o2, 32); o3 += __shfl_xor(o3, 32);
    if (lane < 16) {
        const float HS = 1.f / 128.f;   // head-mean (1/8) * v descale (1/16)
        float4* op = (float4*)(out + ((size_t)w << 6) + lane * 4);
        if (FIRST) {
            *op = make_float4(o0 * HS, o1 * HS, o2 * HS, o3 * HS);
        } else {
            float4 tv = *op;
            tv.x += o0 * HS; tv.y += o1 * HS; tv.z += o2 * HS; tv.w += o3 * HS;
            *op = tv;
        }
    }
}

// ---------------- gated residual + LN + relu (layer 0), bf16 h1 out ----------------
__global__ __launch_bounds__(256) void gres0_k(const float* __restrict__ x, const float* __restrict__ res,
                                               const float* __restrict__ gw,
                                               const float* __restrict__ lng, const float* __restrict__ lnb,
                                               u16* __restrict__ h1, int n) {
    int w = (blockIdx.x * 256 + threadIdx.x) >> 6;
    int lane = threadIdx.x & 63;
    if (w >= n) return;
    size_t base = (size_t)w * 128;
    float x1 = x[base + lane], x2 = x[base + lane + 64];
    float r1 = res[base + lane], r2 = res[base + lane + 64];
    float ca1 = gw[lane] + gw[256 + lane];
    float ca2 = gw[lane + 64] + gw[256 + lane + 64];
    float cr1 = gw[128 + lane] - gw[256 + lane];
    float cr2 = gw[128 + lane + 64] - gw[256 + lane + 64];
    float dot = x1 * ca1 + x2 * ca2 + r1 * cr1 + r2 * cr2;
#pragma unroll
    for (int off = 1; off < 64; off <<= 1) dot += __shfl_xor(dot, off);
    float g = 1.f / (1.f + __expf(-dot));
    float o1 = x1 * g + r1 * (1.f - g);
    float o2 = x2 * g + r2 * (1.f - g);
    float s = o1 + o2;
#pragma unroll
    for (int off = 1; off < 64; off <<= 1) s += __shfl_xor(s, off);
    float mu = s * (1.f / 128.f);
    float d1 = o1 - mu, d2 = o2 - mu;
    float vs = d1 * d1 + d2 * d2;
#pragma unroll
    for (int off = 1; off < 64; off <<= 1) vs += __shfl_xor(vs, off);
    float rstd = rsqrtf(vs * (1.f / 128.f) + 1e-5f);
    float y1 = d1 * rstd * lng[lane] + lnb[lane];
    float y2 = d2 * rstd * lng[lane + 64] + lnb[lane + 64];
    h1[base + lane] = f2bf(fmaxf(y1, 0.f));
    h1[base + lane + 64] = f2bf(fmaxf(y2, 0.f));
}

// ---------------- gated residual only (layer 1, d=64) ----------------
__global__ __launch_bounds__(256) void gres1_k(const float* __restrict__ x, const float* __restrict__ res,
                                               const float* __restrict__ gw,
                                               float* __restrict__ out, int n) {
    int w = (blockIdx.x * 256 + threadIdx.x) >> 6;
    int lane = threadIdx.x & 63;
    if (w >= n) return;
    size_t base = (size_t)w * 64;
    float xv = x[base + lane];
    float rv = res[base + lane];
    float ca = gw[lane] + gw[128 + lane];
    float cr = gw[64 + lane] - gw[128 + lane];
    float dot = xv * ca + rv * cr;
#pragma unroll
    for (int off = 1; off < 64; off <<= 1) dot += __shfl_xor(dot, off);
    float g = 1.f / (1.f + __expf(-dot));
    out[base + lane] = xv * g + rv * (1.f - g);
}

extern "C" void kernel_launch(void* const* d_in, const int* in_sizes, int n_in,
                              void* d_out, int out_size, void* d_ws, size_t ws_size,
                              hipStream_t stream) {
    const float* x    = (const float*)d_in[0];
    const int*   src  = (const int*)d_in[1];
    const int*   dst  = (const int*)d_in[2];
    const float* in_W = (const float*)d_in[3];
    const float* in_b = (const float*)d_in[4];
    const float* q0W = (const float*)d_in[5];  const float* q0b = (const float*)d_in[6];
    const float* k0W = (const float*)d_in[7];  const float* k0b = (const float*)d_in[8];
    const float* v0W = (const float*)d_in[9];  const float* v0b = (const float*)d_in[10];
    const float* r0W = (const float*)d_in[11]; const float* r0b = (const float*)d_in[12];
    const float* g0W = (const float*)d_in[13];
    const float* ln0g = (const float*)d_in[14]; const float* ln0b = (const float*)d_in[15];
    const float* q1W = (const float*)d_in[16]; const float* q1b = (const float*)d_in[17];
    const float* k1W = (const float*)d_in[18]; const float* k1b = (const float*)d_in[19];
    const float* v1W = (const float*)d_in[20]; const float* v1b = (const float*)d_in[21];
    const float* r1W = (const float*)d_in[22]; const float* r1b = (const float*)d_in[23];
    const float* g1W = (const float*)d_in[24];

    const int N = in_sizes[0] / 256;   // 100000
    const int E = in_sizes[1];         // 1600000
    (void)ws_size; (void)n_in; (void)out_size;

    // ---- workspace layout with reuse: peak ~186 MB ----
    auto rnd = [](size_t b) { return (b + 255) & ~(size_t)255; };
    char* base = (char*)d_ws;
    const size_t S_bf = rnd((size_t)N * 128 * 2);   // 25.6 MB
    const size_t S_f  = rnd((size_t)N * 128 * 4);   // 51.2 MB
    size_t o = 0;
    int* row_off = (int*)(base + o); o += rnd(((size_t)N + 1) * 4);
    int* csr     = (int*)(base + o); o += rnd((size_t)E * 4);
    u16* warena  = (u16*)(base + o); o += rnd((size_t)303104 * 2);
    float* barena = (float*)(base + o); o += rnd((size_t)2112 * 4);
    const size_t R0 = o;                 // 51.2: cnt/cur/bsum -> h -> a0 -> {res1o, a1}
    const size_t R1 = R0 + S_f;          // 76.8: x_bf(slots0-1) -> QKV0(slots0-1) -> h1(slot0)+PASS(slots1-2..)
    const size_t R2 = R1 + 3 * S_bf;     // 51.2: res0o -> PASS tail
    int* cnt  = (int*)(base + R0);
    int* cur  = (int*)(base + R0 + rnd((size_t)N * 4));
    int* bsum = (int*)(base + R0 + 2 * rnd((size_t)N * 4));
    u16*   h     = (u16*)(base + R0);
    float* a0    = (float*)(base + R0);
    float* res1o = (float*)(base + R0);
    float* a1    = (float*)(base + R0 + rnd((size_t)N * 64 * 4));
    u16* x_bf = (u16*)(base + R1);                       // N x 256 bf16, dies after in-GEMM
    unsigned char* QKV0 = (unsigned char*)(base + R1);   // N x 512 B (slots 0-1)
    u16* h1   = (u16*)(base + R1);                       // N x 128 bf16 (slot 0, after QKV0 dead)
    unsigned char* PASS = (unsigned char*)(base + R1 + S_bf);  // N x 1024 B (slots 1-2 + R2)
    float* res0o = (float*)(base + R2);                  // dead after gres0 (before PASS written)

    // weight arena sections
    u16* inWt   = warena;
    u16* qkv0t  = warena + 32768;      // rows 0..383 qkv0, 384..511 r0 (contiguous)
    u16* qkv1t0 = warena + 98304;      // pass0 rows 0..767
    u16* qkv1t1 = warena + 196608;     // pass1 rows 0..767, 768..831 = r1t (contiguous)

    dim3 blk(256);
    int nwb = (N * 64 + 255) / 256;   // one wave per node
    int nb  = (N + 255) / 256;        // 391 (<= 512)
    int mb  = (N + 127) / 128;        // 782
    int xch = (mb + 7) / 8;           // 98 (XCD-swizzled grid chunk count)

    // ---- prep (weights/bias/x convert) ----
    prep_k<<<(303104 + 255) / 256, blk, 0, stream>>>(in_W, q0W, k0W, v0W, r0W,
                                                     q1W, k1W, v1W, r1W, warena);
    bias_k<<<9, blk, 0, stream>>>(q0b, k0b, v0b, r0b, q1b, k1b, v1b, r1b, barena);
    cvt_k<<<(N * 32 + 255) / 256, blk, 0, stream>>>(x, x_bf, N * 32);

    // ---- CSR build ----
    zero2_k<<<nb, blk, 0, stream>>>(cnt, cur, N);
    hist_k<<<(E + 255) / 256, blk, 0, stream>>>(dst, cnt, E);
    blocksum_k<<<nb, blk, 0, stream>>>(cnt, bsum, N);
    scanb_k<<<1, 512, 0, stream>>>(bsum, nb);
    scanc_k<<<nb, blk, 0, stream>>>(cnt, bsum, row_off, N, E);
    scatter_k<<<(E + 255) / 256, blk, 0, stream>>>(src, dst, row_off, cur, csr, E);

    // ---- layer 0 ----
    mgemm7<0, 256><<<8 * 1 * xch, blk, 0, stream>>>(x_bf, inWt, in_b, h, nullptr,
                                                    N, mb, 1, 128);
    mgemm7<1, 128><<<8 * 4 * xch, blk, 0, stream>>>(h, qkv0t, barena, QKV0, res0o,
                                                    N, mb, 4, 512);
    attn0_k<<<nwb, blk, 0, stream>>>(QKV0, row_off, csr, a0, N);
    gres0_k<<<nwb, blk, 0, stream>>>(a0, res0o, g0W, ln0g, ln0b, h1, N);

    // ---- layer 1: pass0 (qkv), attn; pass1 (qkv + r1), attn; gres ----
    mgemm7<2, 128><<<8 * 6 * xch, blk, 0, stream>>>(h1, qkv1t0, barena + 512, PASS,
                                                    nullptr, N, mb, 6, 768);
    attn1f_k<true><<<nwb, blk, 0, stream>>>(PASS, row_off, csr, a1, N);

    mgemm7<3, 128><<<8 * 7 * xch, blk, 0, stream>>>(h1, qkv1t1, barena + 1280, PASS,
                                                    res1o, N, mb, 7, 832);
    attn1f_k<false><<<nwb, blk, 0, stream>>>(PASS, row_off, csr, a1, N);

    gres1_k<<<nwb, blk, 0, stream>>>(a1, res1o, g1W, (float*)d_out, N);
}

// Round 16
// 739.324 us; speedup vs baseline: 1.7976x; 1.0466x over previous
//
#include <hip/hip_runtime.h>

// GraphTransformerModel: 2-layer graph attention network.
// CSR build (rank-scatter) -> collapsed layer-0 GEMM (x @ [inW@{q,k,v,r}0W], K=256)
// -> attn0 (fp8 q/v, 512B rows) -> gres0+LN
// -> 2x {qkv1 4-head GEMM (1024B rows) -> attn1f} -> gres1.
// mgemm7: XCD-swizzled blocks, global_load_lds + XOR swizzle, LDS-staged epilogues.
// fp8 = e4m3 x16 scale. Peak workspace ~187 MB.

typedef unsigned short u16;
typedef __attribute__((ext_vector_type(8))) unsigned short ushort8;
typedef __attribute__((ext_vector_type(8))) short short8v;   // 8 bf16 (4 VGPRs)
typedef __attribute__((ext_vector_type(4))) float f32x4;
typedef __attribute__((ext_vector_type(2))) float f32x2;

__device__ __forceinline__ float bf2f(unsigned short u) {
    return __uint_as_float(((unsigned)u) << 16);
}
__device__ __forceinline__ unsigned short f2bf(float f) {
    unsigned u = __float_as_uint(f);
    unsigned r = 0x7fffu + ((u >> 16) & 1u);   // round-to-nearest-even
    return (unsigned short)((u + r) >> 16);
}
__device__ __forceinline__ unsigned char f2fp8(float f) {   // HW e4m3 encode
    return (unsigned char)__builtin_amdgcn_cvt_pk_fp8_f32(f, 0.f, 0, false);
}

// async global->LDS, 16B per lane; dest is wave-uniform base + lane*16 (HW).
__device__ __forceinline__ void gload16(const void* gp, const void* lp) {
    __builtin_amdgcn_global_load_lds(
        (const __attribute__((address_space(1))) unsigned*)(uintptr_t)gp,
        (__attribute__((address_space(3))) unsigned*)(unsigned)(uintptr_t)lp,
        16, 0, 0);
}

// ---------------- fused weight prep (layer-1 sections) ----------------
// arena (u16): [98304)=qkv1t[2][768][128]  [294912)=r1t[64][128]
// (regions below 98304 are legacy/unused after the layer-0 collapse)
__global__ void prep_k(const float* __restrict__ inW,
                       const float* __restrict__ q0W, const float* __restrict__ k0W,
                       const float* __restrict__ v0W, const float* __restrict__ r0W,
                       const float* __restrict__ q1W, const float* __restrict__ k1W,
                       const float* __restrict__ v1W, const float* __restrict__ r1W,
                       u16* __restrict__ arena) {
    int i = blockIdx.x * 256 + threadIdx.x + 98304;
    if (i >= 303104) return;
    float val;
    if (i < 294912) {                      // qkv1t [2][768][128]: pass p covers cols p*256..+255
        int j = i - 98304;
        int row = j >> 7, kk = j & 127;
        int p = row / 768, rr = row - p * 768;
        int sec = rr >> 8, c = p * 256 + (rr & 255);
        const float* s = (sec == 0) ? q1W : (sec == 1) ? k1W : v1W;
        val = s[kk * 512 + c];
    } else {                               // r1t [64][128]
        int j = i - 294912;
        int n = j >> 7, kk = j & 127;
        val = r1W[kk * 64 + n];
    }
    arena[i] = f2bf(val);
}

// ---------------- collapsed layer-0 weights: cwt[512][256], cwb[512] ----------------
// cwt[n][k] = sum_j inW[k][j] * sW[j][n], sections n: 0-127 q0, 128-255 k0,
// 256-383 v0, 384-511 r0.  cwb[n] = sum_j in_b[j]*sW[j][n] + sb[n].
__global__ void cw_k(const float* __restrict__ inW, const float* __restrict__ in_b,
                     const float* __restrict__ q0W, const float* __restrict__ k0W,
                     const float* __restrict__ v0W, const float* __restrict__ r0W,
                     const float* __restrict__ q0b, const float* __restrict__ k0b,
                     const float* __restrict__ v0b, const float* __restrict__ r0b,
                     u16* __restrict__ cwt, float* __restrict__ cwb) {
    int i = blockIdx.x * 256 + threadIdx.x;
    if (i < 131072) {
        int n = i >> 8, k = i & 255;
        int sec = n >> 7, c = n & 127;
        const float* s = (sec == 0) ? q0W : (sec == 1) ? k0W : (sec == 2) ? v0W : r0W;
        float acc = 0.f;
        for (int j = 0; j < 128; ++j) acc = fmaf(inW[k * 128 + j], s[j * 128 + c], acc);
        cwt[(size_t)n * 256 + k] = f2bf(acc);
    } else if (i < 131584) {
        int n = i - 131072;
        int sec = n >> 7, c = n & 127;
        const float* s = (sec == 0) ? q0W : (sec == 1) ? k0W : (sec == 2) ? v0W : r0W;
        const float* b = (sec == 0) ? q0b : (sec == 1) ? k0b : (sec == 2) ? v0b : r0b;
        float acc = b[c];
        for (int j = 0; j < 128; ++j) acc = fmaf(in_b[j], s[j * 128 + c], acc);
        cwb[n] = acc;
    }
}

// fused layer-1 biases (1536 floats): [0)=qkv1b_p0[768] [768)=qkv1b_p1[768]; +r1b[64]
__global__ void bias_k(const float* __restrict__ q1b, const float* __restrict__ k1b,
                       const float* __restrict__ v1b, const float* __restrict__ r1b,
                       float* __restrict__ out) {
    int i = blockIdx.x * 256 + threadIdx.x;
    if (i >= 1600) return;
    if (i < 1536) {
        int p = i / 768, rr = i - p * 768;
        int sec = rr >> 8, c = p * 256 + (rr & 255);
        out[i] = (sec == 0) ? q1b[c] : (sec == 1) ? k1b[c] : v1b[c];
    } else {
        out[i] = r1b[i - 1536];
    }
}

// ---------------- f32 -> bf16 convert (8 elems/thread) ----------------
__global__ void cvt_k(const float* __restrict__ in, u16* __restrict__ out, int n8) {
    int i = blockIdx.x * 256 + threadIdx.x;
    if (i >= n8) return;
    float4 a = *(const float4*)(in + (size_t)i * 8);
    float4 b = *(const float4*)(in + (size_t)i * 8 + 4);
    ushort8 o = {f2bf(a.x), f2bf(a.y), f2bf(a.z), f2bf(a.w),
                 f2bf(b.x), f2bf(b.y), f2bf(b.z), f2bf(b.w)};
    *(ushort8*)(out + (size_t)i * 8) = o;
}

// ---------------- MFMA GEMM v7: XCD-swizzled, fused multi-section ----------------
// C_cols = A[M,K](bf16) @ Bt[Nvalid,K](bf16)^T + bias.  1D grid = 8*ny*ceil(MB/8);
// block id decodes so all ny column-blocks of one A-tile share id%8 (same XCD).
// 128x128 tiles, BK=64 via global_load_lds, XOR swizzle.
// fp8 sections: LDS byte tile [128][144], 128B-row bursts.
// bf16 sections: LDS tile [128][272B], 256B-row bursts.
// MODE 1: layer0 combo: sec 0,2 fp8; sec 1 bf16 k; sec 3 -> f32 C2 [M,128]
// MODE 2: layer1 pass:  sec 0-1,4-5 fp8; sec 2-3 bf16 k
// MODE 3: layer1 pass+aux: like MODE2; sec 6 -> f32 C2 [M,64]
template <int MODE, int K>
__global__ __launch_bounds__(256) void mgemm7(const u16* __restrict__ A,
                                              const u16* __restrict__ Bt,
                                              const float* __restrict__ bias,
                                              void* __restrict__ C,
                                              float* __restrict__ C2,
                                              int M, int MB, int ny, int Nvalid) {
    __shared__ __align__(16) unsigned char smem[36864];   // As 16K | Bs 16K; epi tile reuse
    u16* As = (u16*)smem;
    u16* Bs = (u16*)(smem + 16384);
    int id = blockIdx.x;
    int xcd = id & 7, rest = id >> 3;
    int y = rest % ny;
    int x = (rest / ny) * 8 + xcd;
    if (x >= MB) return;
    const int bm = x * 128;
    const int bn = y * 128;
    const int t = threadIdx.x, lane = t & 63, wid = t >> 6;
    const int wm = (wid >> 1) * 64, wn = (wid & 1) * 64;
    const int jlog = ((lane & 7) ^ (lane >> 3)) * 8;
    f32x4 acc[4][4] = {};
    for (int k0 = 0; k0 < K; k0 += 64) {
#pragma unroll
        for (int c2 = 0; c2 < 4; ++c2) {
            int seg = c2 * 4 + wid;
            int row = seg * 8 + (lane >> 3);
            int ga = bm + row; if (ga >= M) ga = 0;
            gload16(A + (size_t)ga * K + k0 + jlog, (const char*)As + seg * 1024);
            int gb = bn + row; if (gb >= Nvalid) gb = 0;
            gload16(Bt + (size_t)gb * K + k0 + jlog, (const char*)Bs + seg * 1024);
        }
        __syncthreads();
#pragma unroll
        for (int ks = 0; ks < 2; ++ks) {
            const int jx = ks * 4 + (lane >> 4);
            short8v af[4], bfr[4];
#pragma unroll
            for (int i = 0; i < 4; ++i) {
                int ra = wm + i * 16 + (lane & 15);
                af[i] = *(const short8v*)((const char*)As + ra * 128 + ((jx ^ (ra & 7)) << 4));
                int rb = wn + i * 16 + (lane & 15);
                bfr[i] = *(const short8v*)((const char*)Bs + rb * 128 + ((jx ^ (rb & 7)) << 4));
            }
#pragma unroll
            for (int mi = 0; mi < 4; ++mi)
#pragma unroll
                for (int ni = 0; ni < 4; ++ni)
                    acc[mi][ni] = __builtin_amdgcn_mfma_f32_16x16x32_bf16(
                        af[mi], bfr[ni], acc[mi][ni], 0, 0, 0);
        }
        if (k0 + 64 < K) __syncthreads();
    }
    const int sec = y;
    // fp8 staged sections
    bool fp8lds = false;
    int gsecoff = 0, rowbytes = 0;
    if (MODE == 1) {
        if (sec == 0)      { fp8lds = true; gsecoff = 0;   rowbytes = 512; }
        else if (sec == 2) { fp8lds = true; gsecoff = 384; rowbytes = 512; }
    } else if (MODE >= 2) {
        if (sec < 2)                  { fp8lds = true; gsecoff = sec * 128;             rowbytes = 1024; }
        else if (sec >= 4 && sec < 6) { fp8lds = true; gsecoff = 768 + (sec - 4) * 128; rowbytes = 1024; }
    }
    if (fp8lds) {
        unsigned char* tile = smem;                 // 128 rows x 144B stride
        __syncthreads();
#pragma unroll
        for (int ni = 0; ni < 4; ++ni) {
            int lcol = wn + ni * 16 + (lane & 15);
            float bs = bias[bn + lcol];
#pragma unroll
            for (int mi = 0; mi < 4; ++mi) {
#pragma unroll
                for (int j = 0; j < 4; ++j) {
                    int lrow = wm + mi * 16 + (lane >> 4) * 4 + j;
                    float val = acc[mi][ni][j] + bs;
                    tile[lrow * 144 + ((((lcol >> 4) ^ (lrow & 7)) << 4) | (lcol & 15))] =
                        f2fp8(val * 16.f);
                }
            }
        }
        __syncthreads();
#pragma unroll
        for (int it = 0; it < 4; ++it) {            // 1024 chunks of 16B
            int lin = it * 256 + t;
            int row = lin >> 3, ch = lin & 7;
            int crow = bm + row;
            if (crow < M) {
                const float4 vsrc = *(const float4*)(tile + row * 144 + ((ch ^ (row & 7)) << 4));
                *(float4*)((unsigned char*)C + (size_t)crow * rowbytes + gsecoff + ch * 16) = vsrc;
            }
        }
        return;
    }
    // bf16 staged sections (full 256B rows)
    bool bf16lds = false;
    if (MODE == 1 && sec == 1)             { bf16lds = true; gsecoff = 128; rowbytes = 512; }
    else if (MODE >= 2 && sec >= 2 && sec < 4) {
        bf16lds = true; gsecoff = 256 + (sec - 2) * 256; rowbytes = 1024;
    }
    if (bf16lds) {
        unsigned char* tile = smem;                 // 128 rows x 272B stride
        __syncthreads();
#pragma unroll
        for (int ni = 0; ni < 4; ++ni) {
            int lcol = wn + ni * 16 + (lane & 15);
            float bs = bias[bn + lcol];
            int by = lcol * 2, ch = by >> 4;
#pragma unroll
            for (int mi = 0; mi < 4; ++mi) {
#pragma unroll
                for (int j = 0; j < 4; ++j) {
                    int lrow = wm + mi * 16 + (lane >> 4) * 4 + j;
                    float val = acc[mi][ni][j] + bs;
                    *(u16*)(tile + lrow * 272 + ((ch ^ (lrow & 7)) << 4) + (by & 15)) = f2bf(val);
                }
            }
        }
        __syncthreads();
#pragma unroll
        for (int it = 0; it < 8; ++it) {            // 2048 chunks of 16B
            int lin = it * 256 + t;
            int row = lin >> 4, ch = lin & 15;
            int crow = bm + row;
            if (crow < M) {
                const float4 vsrc = *(const float4*)(tile + row * 272 + ((ch ^ (row & 7)) << 4));
                *(float4*)((unsigned char*)C + (size_t)crow * rowbytes + gsecoff + ch * 16) = vsrc;
            }
        }
        return;
    }
    // direct f32 sections
#pragma unroll
    for (int ni = 0; ni < 4; ++ni) {
        int lcol = wn + ni * 16 + (lane & 15);
        int ccol = bn + lcol;
        if (ccol >= Nvalid) continue;
        float bs = bias[ccol];
#pragma unroll
        for (int mi = 0; mi < 4; ++mi) {
#pragma unroll
            for (int j = 0; j < 4; ++j) {
                int crow = bm + wm + mi * 16 + (lane >> 4) * 4 + j;
                if (crow >= M) continue;
                float val = acc[mi][ni][j] + bs;
                if (MODE == 1) {          // sec == 3: res0o f32 [M,128]
                    C2[(size_t)crow * 128 + lcol] = val;
                } else {                  // MODE 3, sec == 6: res1o f32 [M,64]
                    C2[(size_t)crow * 64 + lcol] = val;
                }
            }
        }
    }
}

// ---------------- CSR build (rank-based, single atomic pass) ----------------
__global__ void zero1_k(int* __restrict__ a, int n) {
    int i = blockIdx.x * 256 + threadIdx.x;
    if (i < n) a[i] = 0;
}

__global__ void hist_k(const int* __restrict__ dst, int* __restrict__ cnt,
                       int* __restrict__ rank, int E) {
    int i = blockIdx.x * 256 + threadIdx.x;
    if (i < E) rank[i] = atomicAdd(&cnt[dst[i]], 1);
}

__global__ void blocksum_k(const int* __restrict__ cnt, int* __restrict__ bsum, int n) {
    __shared__ int sd[256];
    int i = blockIdx.x * 256 + threadIdx.x;
    sd[threadIdx.x] = (i < n) ? cnt[i] : 0;
    __syncthreads();
    for (int off = 128; off > 0; off >>= 1) {
        if (threadIdx.x < off) sd[threadIdx.x] += sd[threadIdx.x + off];
        __syncthreads();
    }
    if (threadIdx.x == 0) bsum[blockIdx.x] = sd[0];
}

__global__ void scanb_k(int* bsum, int nb) {
    __shared__ int tmp[512];
    int t = threadIdx.x;
    tmp[t] = (t < nb) ? bsum[t] : 0;
    __syncthreads();
    for (int off = 1; off < 512; off <<= 1) {
        int v = (t >= off) ? tmp[t - off] : 0;
        __syncthreads();
        tmp[t] += v;
        __syncthreads();
    }
    if (t < nb) bsum[t] = (t ? tmp[t - 1] : 0);
}

__global__ void scanc_k(const int* __restrict__ cnt, const int* __restrict__ bsum,
                        int* __restrict__ row_off, int n, int E) {
    __shared__ int tmp[256];
    int b = blockIdx.x, t = threadIdx.x;
    int i = b * 256 + t;
    int own = (i < n) ? cnt[i] : 0;
    tmp[t] = own;
    __syncthreads();
    for (int off = 1; off < 256; off <<= 1) {
        int v = (t >= off) ? tmp[t - off] : 0;
        __syncthreads();
        tmp[t] += v;
        __syncthreads();
    }
    if (i < n) row_off[i] = bsum[b] + tmp[t] - own;
    if (b == 0 && t == 0) row_off[n] = E;
}

__global__ void scatter_k(const int* __restrict__ src, const int* __restrict__ dst,
                          const int* __restrict__ row_off, const int* __restrict__ rank,
                          int* __restrict__ csr_src, int E) {
    int i = blockIdx.x * 256 + threadIdx.x;
    if (i < E) csr_src[row_off[dst[i]] + rank[i]] = src[i];
}

// ---------------- attention layer 0: 8 heads x d=16, fp8 q/v, 512B rows ----------------
__global__ __launch_bounds__(256) void attn0_k(const unsigned char* __restrict__ qkv,
                                               const int* __restrict__ row_off,
                                               const int* __restrict__ csr,
                                               float* __restrict__ out, int n) {
    int w = (blockIdx.x * 256 + threadIdx.x) >> 6;
    int lane = threadIdx.x & 63;
    if (w >= n) return;
    int beg = row_off[w], end = row_off[w + 1];
    unsigned kv = *(const unsigned*)(qkv + (size_t)w * 512 + 128 + 4 * lane);
    const float KS = 0.25f / 16.f;                        // 1/sqrt(16) / q-scale
    float k0f = bf2f((u16)kv) * KS, k1f = bf2f((u16)(kv >> 16)) * KS;
    float den = 0.f, num0 = 0.f, num1 = 0.f;
    int e = beg;
    for (; e + 4 <= end; e += 4) {
        int s0 = csr[e], s1 = csr[e + 1], s2 = csr[e + 2], s3 = csr[e + 3];
        const unsigned char* r0 = qkv + (size_t)s0 * 512;
        const unsigned char* r1 = qkv + (size_t)s1 * 512;
        const unsigned char* r2 = qkv + (size_t)s2 * 512;
        const unsigned char* r3 = qkv + (size_t)s3 * 512;
        int qa = *(const unsigned short*)(r0 + 2 * lane);
        int qb = *(const unsigned short*)(r1 + 2 * lane);
        int qc = *(const unsigned short*)(r2 + 2 * lane);
        int qd = *(const unsigned short*)(r3 + 2 * lane);
        int va = *(const unsigned short*)(r0 + 384 + 2 * lane);
        int vb = *(const unsigned short*)(r1 + 384 + 2 * lane);
        int vc = *(const unsigned short*)(r2 + 384 + 2 * lane);
        int vd = *(const unsigned short*)(r3 + 384 + 2 * lane);
        f32x2 qaf = __builtin_amdgcn_cvt_pk_f32_fp8(qa, false);
        f32x2 qbf = __builtin_amdgcn_cvt_pk_f32_fp8(qb, false);
        f32x2 qcf = __builtin_amdgcn_cvt_pk_f32_fp8(qc, false);
        f32x2 qdf = __builtin_amdgcn_cvt_pk_f32_fp8(qd, false);
        float pa = qaf.x * k0f + qaf.y * k1f;
        float pb = qbf.x * k0f + qbf.y * k1f;
        float pc = qcf.x * k0f + qcf.y * k1f;
        float pd = qdf.x * k0f + qdf.y * k1f;
#pragma unroll
        for (int off = 1; off < 8; off <<= 1) {
            pa += __shfl_xor(pa, off); pb += __shfl_xor(pb, off);
            pc += __shfl_xor(pc, off); pd += __shfl_xor(pd, off);
        }
        float wa = __expf(pa), wb = __expf(pb);
        float wc = __expf(pc), wd = __expf(pd);
        den += (wa + wb) + (wc + wd);
        f32x2 vaf = __builtin_amdgcn_cvt_pk_f32_fp8(va, false);
        f32x2 vbf = __builtin_amdgcn_cvt_pk_f32_fp8(vb, false);
        f32x2 vcf = __builtin_amdgcn_cvt_pk_f32_fp8(vc, false);
        f32x2 vdf = __builtin_amdgcn_cvt_pk_f32_fp8(vd, false);
        num0 = fmaf(wa, vaf.x, num0); num1 = fmaf(wa, vaf.y, num1);
        num0 = fmaf(wb, vbf.x, num0); num1 = fmaf(wb, vbf.y, num1);
        num0 = fmaf(wc, vcf.x, num0); num1 = fmaf(wc, vcf.y, num1);
        num0 = fmaf(wd, vdf.x, num0); num1 = fmaf(wd, vdf.y, num1);
    }
    for (; e < end; ++e) {
        int s = csr[e];
        const unsigned char* r = qkv + (size_t)s * 512;
        int qv = *(const unsigned short*)(r + 2 * lane);
        f32x2 qf = __builtin_amdgcn_cvt_pk_f32_fp8(qv, false);
        float p = qf.x * k0f + qf.y * k1f;
        p += __shfl_xor(p, 1);
        p += __shfl_xor(p, 2);
        p += __shfl_xor(p, 4);
        float wt = __expf(p);
        den += wt;
        int vv = *(const unsigned short*)(r + 384 + 2 * lane);
        f32x2 vf = __builtin_amdgcn_cvt_pk_f32_fp8(vv, false);
        num0 = fmaf(wt, vf.x, num0); num1 = fmaf(wt, vf.y, num1);
    }
    float inv = (end > beg) ? (1.f / den) * (1.f / 16.f) : 0.f;   // v descale
    *(float2*)(out + ((size_t)w << 7) + 2 * lane) = make_float2(num0 * inv, num1 * inv);
}

// ---------------- attention layer 1 fused (one 4-head pass): d=64, 1024B rows ----------
template <bool FIRST>
__global__ __launch_bounds__(256) void attn1f_k(const unsigned char* __restrict__ qkv,
                                                const int* __restrict__ row_off,
                                                const int* __restrict__ csr,
                                                float* __restrict__ out, int n) {
    int w = (blockIdx.x * 256 + threadIdx.x) >> 6;
    int lane = threadIdx.x & 63;
    if (w >= n) return;
    int beg = row_off[w], end = row_off[w + 1];
    const float KS = 0.125f / 16.f;                       // 1/sqrt(64) / q-scale
    float kr0, kr1, kr2, kr3;
    {
        uint2 kk2 = *(const uint2*)(qkv + (size_t)w * 1024 + 256 + 8 * lane);
        kr0 = bf2f((u16)kk2.x) * KS; kr1 = bf2f((u16)(kk2.x >> 16)) * KS;
        kr2 = bf2f((u16)kk2.y) * KS; kr3 = bf2f((u16)(kk2.y >> 16)) * KS;
    }
    float den = 0.f, num0 = 0.f, num1 = 0.f, num2 = 0.f, num3 = 0.f;
    int e = beg;
    for (; e + 4 <= end; e += 4) {
        int s0 = csr[e], s1 = csr[e + 1], s2 = csr[e + 2], s3 = csr[e + 3];
        const unsigned char* r0 = qkv + (size_t)s0 * 1024;
        const unsigned char* r1 = qkv + (size_t)s1 * 1024;
        const unsigned char* r2 = qkv + (size_t)s2 * 1024;
        const unsigned char* r3 = qkv + (size_t)s3 * 1024;
        unsigned qa = *(const unsigned*)(r0 + 4 * lane);
        unsigned qb = *(const unsigned*)(r1 + 4 * lane);
        unsigned qc = *(const unsigned*)(r2 + 4 * lane);
        unsigned qd = *(const unsigned*)(r3 + 4 * lane);
        unsigned va = *(const unsigned*)(r0 + 768 + 4 * lane);
        unsigned vb = *(const unsigned*)(r1 + 768 + 4 * lane);
        unsigned vc = *(const unsigned*)(r2 + 768 + 4 * lane);
        unsigned vd = *(const unsigned*)(r3 + 768 + 4 * lane);
        f32x2 qa0 = __builtin_amdgcn_cvt_pk_f32_fp8((int)qa, false);
        f32x2 qa1 = __builtin_amdgcn_cvt_pk_f32_fp8((int)qa, true);
        f32x2 qb0 = __builtin_amdgcn_cvt_pk_f32_fp8((int)qb, false);
        f32x2 qb1 = __builtin_amdgcn_cvt_pk_f32_fp8((int)qb, true);
        f32x2 qc0 = __builtin_amdgcn_cvt_pk_f32_fp8((int)qc, false);
        f32x2 qc1 = __builtin_amdgcn_cvt_pk_f32_fp8((int)qc, true);
        f32x2 qd0 = __builtin_amdgcn_cvt_pk_f32_fp8((int)qd, false);
        f32x2 qd1 = __builtin_amdgcn_cvt_pk_f32_fp8((int)qd, true);
        float pa = qa0.x * kr0 + qa0.y * kr1 + qa1.x * kr2 + qa1.y * kr3;
        float pb = qb0.x * kr0 + qb0.y * kr1 + qb1.x * kr2 + qb1.y * kr3;
        float pc = qc0.x * kr0 + qc0.y * kr1 + qc1.x * kr2 + qc1.y * kr3;
        float pd = qd0.x * kr0 + qd0.y * kr1 + qd1.x * kr2 + qd1.y * kr3;
#pragma unroll
        for (int off = 1; off < 16; off <<= 1) {
            pa += __shfl_xor(pa, off); pb += __shfl_xor(pb, off);
            pc += __shfl_xor(pc, off); pd += __shfl_xor(pd, off);
        }
        float wa = __expf(pa), wb = __expf(pb);
        float wc = __expf(pc), wd = __expf(pd);
        den += (wa + wb) + (wc + wd);
        f32x2 va0 = __builtin_amdgcn_cvt_pk_f32_fp8((int)va, false);
        f32x2 va1 = __builtin_amdgcn_cvt_pk_f32_fp8((int)va, true);
        f32x2 vb0 = __builtin_amdgcn_cvt_pk_f32_fp8((int)vb, false);
        f32x2 vb1 = __builtin_amdgcn_cvt_pk_f32_fp8((int)vb, true);
        f32x2 vc0 = __builtin_amdgcn_cvt_pk_f32_fp8((int)vc, false);
        f32x2 vc1 = __builtin_amdgcn_cvt_pk_f32_fp8((int)vc, true);
        f32x2 vd0 = __builtin_amdgcn_cvt_pk_f32_fp8((int)vd, false);
        f32x2 vd1 = __builtin_amdgcn_cvt_pk_f32_fp8((int)vd, true);
        num0 = fmaf(wa, va0.x, num0); num1 = fmaf(wa, va0.y, num1);
        num2 = fmaf(wa, va1.x, num2); num3 = fmaf(wa, va1.y, num3);
        num0 = fmaf(wb, vb0.x, num0); num1 = fmaf(wb, vb0.y, num1);
        num2 = fmaf(wb, vb1.x, num2); num3 = fmaf(wb, vb1.y, num3);
        num0 = fmaf(wc, vc0.x, num0); num1 = fmaf(wc, vc0.y, num1);
        num2 = fmaf(wc, vc1.x, num2); num3 = fmaf(wc, vc1.y, num3);
        num0 = fmaf(wd, vd0.x, num0); num1 = fmaf(wd, vd0.y, num1);
        num2 = fmaf(wd, vd1.x, num2); num3 = fmaf(wd, vd1.y, num3);
    }
    for (; e < end; ++e) {
        int s = csr[e];
        const unsigned char* r = qkv + (size_t)s * 1024;
        unsigned qv = *(const unsigned*)(r + 4 * lane);
        f32x2 q0 = __builtin_amdgcn_cvt_pk_f32_fp8((int)qv, false);
        f32x2 q1 = __builtin_amdgcn_cvt_pk_f32_fp8((int)qv, true);
        float p = q0.x * kr0 + q0.y * kr1 + q1.x * kr2 + q1.y * kr3;
#pragma unroll
        for (int off = 1; off < 16; off <<= 1) p += __shfl_xor(p, off);
        float wt = __expf(p);
        den += wt;
        unsigned vv = *(const unsigned*)(r + 768 + 4 * lane);
        f32x2 v0 = __builtin_amdgcn_cvt_pk_f32_fp8((int)vv, false);
        f32x2 v1 = __builtin_amdgcn_cvt_pk_f32_fp8((int)vv, true);
        num0 = fmaf(wt, v0.x, num0); num1 = fmaf(wt, v0.y, num1);
        num2 = fmaf(wt, v1.x, num2); num3 = fmaf(wt, v1.y, num3);
    }
    float inv = (end > beg) ? 1.f / den : 0.f;
    float o0 = num0 * inv, o1 = num1 * inv, o2 = num2 * inv, o3 = num3 * inv;
    o0 += __shfl_xor(o0, 16); o1 += __shfl_xor(o1, 16);
    o2 += __shfl_xor(o2, 16); o3 += __shfl_xor(o3, 16);
    o0 += __shfl_xor(o0, 32); o1 += __shfl_xor(o1, 32);
    o2 += __shfl_xor(o2, 32); o3 += __shfl_xor(o3, 32);
    if (lane < 16) {
        const float HS = 1.f / 128.f;   // head-mean (1/8) * v descale (1/16)
        float4* op = (float4*)(out + ((size_t)w << 6) + lane * 4);
        if (FIRST) {
            *op = make_float4(o0 * HS, o1 * HS, o2 * HS, o3 * HS);
        } else {
            float4 tv = *op;
            tv.x += o0 * HS; tv.y += o1 * HS; tv.z += o2 * HS; tv.w += o3 * HS;
            *op = tv;
        }
    }
}

// ---------------- gated residual + LN + relu (layer 0), bf16 h1 out ----------------
__global__ __launch_bounds__(256) void gres0_k(const float* __restrict__ x, const float* __restrict__ res,
                                               const float* __restrict__ gw,
                                               const float* __restrict__ lng, const float* __restrict__ lnb,
                                               u16* __restrict__ h1, int n) {
    int w = (blockIdx.x * 256 + threadIdx.x) >> 6;
    int lane = threadIdx.x & 63;
    if (w >= n) return;
    size_t base = (size_t)w * 128;
    float x1 = x[base + lane], x2 = x[base + lane + 64];
    float r1 = res[base + lane], r2 = res[base + lane + 64];
    float ca1 = gw[lane] + gw[256 + lane];
    float ca2 = gw[lane + 64] + gw[256 + lane + 64];
    float cr1 = gw[128 + lane] - gw[256 + lane];
    float cr2 = gw[128 + lane + 64] - gw[256 + lane + 64];
    float dot = x1 * ca1 + x2 * ca2 + r1 * cr1 + r2 * cr2;
#pragma unroll
    for (int off = 1; off < 64; off <<= 1) dot += __shfl_xor(dot, off);
    float g = 1.f / (1.f + __expf(-dot));
    float o1 = x1 * g + r1 * (1.f - g);
    float o2 = x2 * g + r2 * (1.f - g);
    float s = o1 + o2;
#pragma unroll
    for (int off = 1; off < 64; off <<= 1) s += __shfl_xor(s, off);
    float mu = s * (1.f / 128.f);
    float d1 = o1 - mu, d2 = o2 - mu;
    float vs = d1 * d1 + d2 * d2;
#pragma unroll
    for (int off = 1; off < 64; off <<= 1) vs += __shfl_xor(vs, off);
    float rstd = rsqrtf(vs * (1.f / 128.f) + 1e-5f);
    float y1 = d1 * rstd * lng[lane] + lnb[lane];
    float y2 = d2 * rstd * lng[lane + 64] + lnb[lane + 64];
    h1[base + lane] = f2bf(fmaxf(y1, 0.f));
    h1[base + lane + 64] = f2bf(fmaxf(y2, 0.f));
}

// ---------------- gated residual only (layer 1, d=64) ----------------
__global__ __launch_bounds__(256) void gres1_k(const float* __restrict__ x, const float* __restrict__ res,
                                               const float* __restrict__ gw,
                                               float* __restrict__ out, int n) {
    int w = (blockIdx.x * 256 + threadIdx.x) >> 6;
    int lane = threadIdx.x & 63;
    if (w >= n) return;
    size_t base = (size_t)w * 64;
    float xv = x[base + lane];
    float rv = res[base + lane];
    float ca = gw[lane] + gw[128 + lane];
    float cr = gw[64 + lane] - gw[128 + lane];
    float dot = xv * ca + rv * cr;
#pragma unroll
    for (int off = 1; off < 64; off <<= 1) dot += __shfl_xor(dot, off);
    float g = 1.f / (1.f + __expf(-dot));
    out[base + lane] = xv * g + rv * (1.f - g);
}

extern "C" void kernel_launch(void* const* d_in, const int* in_sizes, int n_in,
                              void* d_out, int out_size, void* d_ws, size_t ws_size,
                              hipStream_t stream) {
    const float* x    = (const float*)d_in[0];
    const int*   src  = (const int*)d_in[1];
    const int*   dst  = (const int*)d_in[2];
    const float* in_W = (const float*)d_in[3];
    const float* in_b = (const float*)d_in[4];
    const float* q0W = (const float*)d_in[5];  const float* q0b = (const float*)d_in[6];
    const float* k0W = (const float*)d_in[7];  const float* k0b = (const float*)d_in[8];
    const float* v0W = (const float*)d_in[9];  const float* v0b = (const float*)d_in[10];
    const float* r0W = (const float*)d_in[11]; const float* r0b = (const float*)d_in[12];
    const float* g0W = (const float*)d_in[13];
    const float* ln0g = (const float*)d_in[14]; const float* ln0b = (const float*)d_in[15];
    const float* q1W = (const float*)d_in[16]; const float* q1b = (const float*)d_in[17];
    const float* k1W = (const float*)d_in[18]; const float* k1b = (const float*)d_in[19];
    const float* v1W = (const float*)d_in[20]; const float* v1b = (const float*)d_in[21];
    const float* r1W = (const float*)d_in[22]; const float* r1b = (const float*)d_in[23];
    const float* g1W = (const float*)d_in[24];

    const int N = in_sizes[0] / 256;   // 100000
    const int E = in_sizes[1];         // 1600000
    (void)ws_size; (void)n_in; (void)out_size;

    // ---- workspace layout: headers + 3.5 regions of 51.2 MB, peak ~187 MB ----
    auto rnd = [](size_t b) { return (b + 255) & ~(size_t)255; };
    char* base = (char*)d_ws;
    const size_t S_f = rnd((size_t)N * 128 * 4);    // 51.2 MB region unit
    size_t o = 0;
    int* row_off = (int*)(base + o); o += rnd(((size_t)N + 1) * 4);
    int* csr     = (int*)(base + o); o += rnd((size_t)E * 4);
    u16* warena  = (u16*)(base + o); o += rnd((size_t)(303104 + 131072) * 2);
    float* barena = (float*)(base + o); o += rnd((size_t)(1600 + 512) * 4);
    char* RB = base + o;
    // Region A [0,S): cnt/bsum -> QKV0 -> PASS head
    // Region B [S,2S): res0o -> PASS tail
    // Region C [2S,3S): x_bf -> a0 -> {a1, res1o}
    // Region D [3S,3.5S): rank -> h1
    int* cnt  = (int*)RB;
    int* bsum = (int*)(RB + rnd((size_t)N * 4));
    unsigned char* QKV0 = (unsigned char*)RB;            // N x 512 B
    unsigned char* PASS = (unsigned char*)RB;            // N x 1024 B (A+B)
    float* res0o = (float*)(RB + S_f);
    u16*   x_bf  = (u16*)(RB + 2 * S_f);                 // N x 256 bf16
    float* a0    = (float*)(RB + 2 * S_f);
    float* a1    = (float*)(RB + 2 * S_f);
    float* res1o = (float*)(RB + 2 * S_f + rnd((size_t)N * 64 * 4));
    int*   rank  = (int*)(RB + 3 * S_f);                 // E ints (6.4 MB)
    u16*   h1    = (u16*)(RB + 3 * S_f);                 // N x 128 bf16

    // weight arena sections
    u16* qkv1t0 = warena + 98304;      // pass0 rows 0..767
    u16* qkv1t1 = warena + 196608;     // pass1 rows 0..767, 768..831 = r1t (contiguous)
    u16* cwt    = warena + 303104;     // collapsed layer-0 [512][256]
    float* qkv1b = barena;             // [0..1536) p0|p1, [1536..1600) r1b
    float* cwb   = barena + 1600;      // collapsed layer-0 biases [512]

    dim3 blk(256);
    int nwb = (N * 64 + 255) / 256;   // one wave per node
    int nb  = (N + 255) / 256;        // 391 (<= 512)
    int mb  = (N + 127) / 128;        // 782
    int xch = (mb + 7) / 8;           // 98 (XCD-swizzled grid chunk count)

    // ---- prep (weights/bias/x convert) ----
    prep_k<<<(303104 - 98304 + 255) / 256, blk, 0, stream>>>(in_W, q0W, k0W, v0W, r0W,
                                                             q1W, k1W, v1W, r1W, warena);
    cw_k<<<(131584 + 255) / 256, blk, 0, stream>>>(in_W, in_b, q0W, k0W, v0W, r0W,
                                                   q0b, k0b, v0b, r0b, cwt, cwb);
    bias_k<<<7, blk, 0, stream>>>(q1b, k1b, v1b, r1b, barena);
    cvt_k<<<(N * 32 + 255) / 256, blk, 0, stream>>>(x, x_bf, N * 32);

    // ---- CSR build (rank-based) ----
    zero1_k<<<nb, blk, 0, stream>>>(cnt, N);
    hist_k<<<(E + 255) / 256, blk, 0, stream>>>(dst, cnt, rank, E);
    blocksum_k<<<nb, blk, 0, stream>>>(cnt, bsum, N);
    scanb_k<<<1, 512, 0, stream>>>(bsum, nb);
    scanc_k<<<nb, blk, 0, stream>>>(cnt, bsum, row_off, N, E);
    scatter_k<<<(E + 255) / 256, blk, 0, stream>>>(src, dst, row_off, rank, csr, E);

    // ---- layer 0: one collapsed K=256 GEMM from x_bf ----
    mgemm7<1, 256><<<8 * 4 * xch, blk, 0, stream>>>(x_bf, cwt, cwb, QKV0, res0o,
                                                    N, mb, 4, 512);
    attn0_k<<<nwb, blk, 0, stream>>>(QKV0, row_off, csr, a0, N);
    gres0_k<<<nwb, blk, 0, stream>>>(a0, res0o, g0W, ln0g, ln0b, h1, N);

    // ---- layer 1: pass0 (qkv), attn; pass1 (qkv + r1), attn; gres ----
    mgemm7<2, 128><<<8 * 6 * xch, blk, 0, stream>>>(h1, qkv1t0, qkv1b, PASS,
                                                    nullptr, N, mb, 6, 768);
    attn1f_k<true><<<nwb, blk, 0, stream>>>(PASS, row_off, csr, a1, N);

    mgemm7<3, 128><<<8 * 7 * xch, blk, 0, stream>>>(h1, qkv1t1, qkv1b + 768, PASS,
                                                    res1o, N, mb, 7, 832);
    attn1f_k<false><<<nwb, blk, 0, stream>>>(PASS, row_off, csr, a1, N);

    gres1_k<<<nwb, blk, 0, stream>>>(a1, res1o, g1W, (float*)d_out, N);
}

// Round 17
// 730.744 us; speedup vs baseline: 1.8187x; 1.0117x over previous
//
#include <hip/hip_runtime.h>

// GraphTransformerModel: 2-layer graph attention network.
// CSR build (rank-scatter) -> collapsed layer-0 GEMM (x @ [inW@{q,k,v,r}0W], K=256)
// -> attn0+gres0+LN fused (fp8 q/v, 512B rows) -> qkv1 pass0 GEMM -> attn1f
// -> qkv1 pass1 GEMM -> attn1g (attn + gated-res fused, writes d_out).
// mgemm7: XCD-swizzled blocks, global_load_lds + XOR swizzle, LDS-staged epilogues.
// fp8 = e4m3 x16 scale. Peak workspace ~190 MB.

typedef unsigned short u16;
typedef __attribute__((ext_vector_type(8))) unsigned short ushort8;
typedef __attribute__((ext_vector_type(8))) short short8v;   // 8 bf16 (4 VGPRs)
typedef __attribute__((ext_vector_type(4))) float f32x4;
typedef __attribute__((ext_vector_type(2))) float f32x2;

__device__ __forceinline__ float bf2f(unsigned short u) {
    return __uint_as_float(((unsigned)u) << 16);
}
__device__ __forceinline__ unsigned short f2bf(float f) {
    unsigned u = __float_as_uint(f);
    unsigned r = 0x7fffu + ((u >> 16) & 1u);   // round-to-nearest-even
    return (unsigned short)((u + r) >> 16);
}
__device__ __forceinline__ unsigned char f2fp8(float f) {   // HW e4m3 encode
    return (unsigned char)__builtin_amdgcn_cvt_pk_fp8_f32(f, 0.f, 0, false);
}

// async global->LDS, 16B per lane; dest is wave-uniform base + lane*16 (HW).
__device__ __forceinline__ void gload16(const void* gp, const void* lp) {
    __builtin_amdgcn_global_load_lds(
        (const __attribute__((address_space(1))) unsigned*)(uintptr_t)gp,
        (__attribute__((address_space(3))) unsigned*)(unsigned)(uintptr_t)lp,
        16, 0, 0);
}

// ---------------- fused weight prep (layer-1 sections) ----------------
// arena (u16): [98304)=qkv1t[2][768][128]  [294912)=r1t[64][128]
__global__ void prep_k(const float* __restrict__ q1W, const float* __restrict__ k1W,
                       const float* __restrict__ v1W, const float* __restrict__ r1W,
                       u16* __restrict__ arena) {
    int i = blockIdx.x * 256 + threadIdx.x + 98304;
    if (i >= 303104) return;
    float val;
    if (i < 294912) {                      // qkv1t [2][768][128]: pass p covers cols p*256..+255
        int j = i - 98304;
        int row = j >> 7, kk = j & 127;
        int p = row / 768, rr = row - p * 768;
        int sec = rr >> 8, c = p * 256 + (rr & 255);
        const float* s = (sec == 0) ? q1W : (sec == 1) ? k1W : v1W;
        val = s[kk * 512 + c];
    } else {                               // r1t [64][128]
        int j = i - 294912;
        int n = j >> 7, kk = j & 127;
        val = r1W[kk * 64 + n];
    }
    arena[i] = f2bf(val);
}

// ---------------- collapsed layer-0 weights: cwt[512][256], cwb[512] ----------------
__global__ void cw_k(const float* __restrict__ inW, const float* __restrict__ in_b,
                     const float* __restrict__ q0W, const float* __restrict__ k0W,
                     const float* __restrict__ v0W, const float* __restrict__ r0W,
                     const float* __restrict__ q0b, const float* __restrict__ k0b,
                     const float* __restrict__ v0b, const float* __restrict__ r0b,
                     u16* __restrict__ cwt, float* __restrict__ cwb) {
    int i = blockIdx.x * 256 + threadIdx.x;
    if (i < 131072) {
        int n = i >> 8, k = i & 255;
        int sec = n >> 7, c = n & 127;
        const float* s = (sec == 0) ? q0W : (sec == 1) ? k0W : (sec == 2) ? v0W : r0W;
        float acc = 0.f;
        for (int j = 0; j < 128; ++j) acc = fmaf(inW[k * 128 + j], s[j * 128 + c], acc);
        cwt[(size_t)n * 256 + k] = f2bf(acc);
    } else if (i < 131584) {
        int n = i - 131072;
        int sec = n >> 7, c = n & 127;
        const float* s = (sec == 0) ? q0W : (sec == 1) ? k0W : (sec == 2) ? v0W : r0W;
        const float* b = (sec == 0) ? q0b : (sec == 1) ? k0b : (sec == 2) ? v0b : r0b;
        float acc = b[c];
        for (int j = 0; j < 128; ++j) acc = fmaf(in_b[j], s[j * 128 + c], acc);
        cwb[n] = acc;
    }
}

// fused layer-1 biases (1600 floats): [0)=p0[768] [768)=p1[768] [1536)=r1b[64]
__global__ void bias_k(const float* __restrict__ q1b, const float* __restrict__ k1b,
                       const float* __restrict__ v1b, const float* __restrict__ r1b,
                       float* __restrict__ out) {
    int i = blockIdx.x * 256 + threadIdx.x;
    if (i >= 1600) return;
    if (i < 1536) {
        int p = i / 768, rr = i - p * 768;
        int sec = rr >> 8, c = p * 256 + (rr & 255);
        out[i] = (sec == 0) ? q1b[c] : (sec == 1) ? k1b[c] : v1b[c];
    } else {
        out[i] = r1b[i - 1536];
    }
}

// ---------------- f32 -> bf16 convert (8 elems/thread) ----------------
__global__ void cvt_k(const float* __restrict__ in, u16* __restrict__ out, int n8) {
    int i = blockIdx.x * 256 + threadIdx.x;
    if (i >= n8) return;
    float4 a = *(const float4*)(in + (size_t)i * 8);
    float4 b = *(const float4*)(in + (size_t)i * 8 + 4);
    ushort8 o = {f2bf(a.x), f2bf(a.y), f2bf(a.z), f2bf(a.w),
                 f2bf(b.x), f2bf(b.y), f2bf(b.z), f2bf(b.w)};
    *(ushort8*)(out + (size_t)i * 8) = o;
}

// ---------------- MFMA GEMM v7: XCD-swizzled, fused multi-section ----------------
// MODE 1: layer0 combo: sec 0,2 fp8; sec 1 bf16 k; sec 3 -> f32 C2 [M,128]
// MODE 2: layer1 pass:  sec 0-1,4-5 fp8; sec 2-3 bf16 k
// MODE 3: layer1 pass+aux: like MODE2; sec 6 -> f32 C2 [M,64]
template <int MODE, int K>
__global__ __launch_bounds__(256) void mgemm7(const u16* __restrict__ A,
                                              const u16* __restrict__ Bt,
                                              const float* __restrict__ bias,
                                              void* __restrict__ C,
                                              float* __restrict__ C2,
                                              int M, int MB, int ny, int Nvalid) {
    __shared__ __align__(16) unsigned char smem[36864];   // As 16K | Bs 16K; epi tile reuse
    u16* As = (u16*)smem;
    u16* Bs = (u16*)(smem + 16384);
    int id = blockIdx.x;
    int xcd = id & 7, rest = id >> 3;
    int y = rest % ny;
    int x = (rest / ny) * 8 + xcd;
    if (x >= MB) return;
    const int bm = x * 128;
    const int bn = y * 128;
    const int t = threadIdx.x, lane = t & 63, wid = t >> 6;
    const int wm = (wid >> 1) * 64, wn = (wid & 1) * 64;
    const int jlog = ((lane & 7) ^ (lane >> 3)) * 8;
    f32x4 acc[4][4] = {};
    for (int k0 = 0; k0 < K; k0 += 64) {
#pragma unroll
        for (int c2 = 0; c2 < 4; ++c2) {
            int seg = c2 * 4 + wid;
            int row = seg * 8 + (lane >> 3);
            int ga = bm + row; if (ga >= M) ga = 0;
            gload16(A + (size_t)ga * K + k0 + jlog, (const char*)As + seg * 1024);
            int gb = bn + row; if (gb >= Nvalid) gb = 0;
            gload16(Bt + (size_t)gb * K + k0 + jlog, (const char*)Bs + seg * 1024);
        }
        __syncthreads();
#pragma unroll
        for (int ks = 0; ks < 2; ++ks) {
            const int jx = ks * 4 + (lane >> 4);
            short8v af[4], bfr[4];
#pragma unroll
            for (int i = 0; i < 4; ++i) {
                int ra = wm + i * 16 + (lane & 15);
                af[i] = *(const short8v*)((const char*)As + ra * 128 + ((jx ^ (ra & 7)) << 4));
                int rb = wn + i * 16 + (lane & 15);
                bfr[i] = *(const short8v*)((const char*)Bs + rb * 128 + ((jx ^ (rb & 7)) << 4));
            }
#pragma unroll
            for (int mi = 0; mi < 4; ++mi)
#pragma unroll
                for (int ni = 0; ni < 4; ++ni)
                    acc[mi][ni] = __builtin_amdgcn_mfma_f32_16x16x32_bf16(
                        af[mi], bfr[ni], acc[mi][ni], 0, 0, 0);
        }
        if (k0 + 64 < K) __syncthreads();
    }
    const int sec = y;
    bool fp8lds = false;
    int gsecoff = 0, rowbytes = 0;
    if (MODE == 1) {
        if (sec == 0)      { fp8lds = true; gsecoff = 0;   rowbytes = 512; }
        else if (sec == 2) { fp8lds = true; gsecoff = 384; rowbytes = 512; }
    } else if (MODE >= 2) {
        if (sec < 2)                  { fp8lds = true; gsecoff = sec * 128;             rowbytes = 1024; }
        else if (sec >= 4 && sec < 6) { fp8lds = true; gsecoff = 768 + (sec - 4) * 128; rowbytes = 1024; }
    }
    if (fp8lds) {
        unsigned char* tile = smem;                 // 128 rows x 144B stride
        __syncthreads();
#pragma unroll
        for (int ni = 0; ni < 4; ++ni) {
            int lcol = wn + ni * 16 + (lane & 15);
            float bs = bias[bn + lcol];
#pragma unroll
            for (int mi = 0; mi < 4; ++mi) {
#pragma unroll
                for (int j = 0; j < 4; ++j) {
                    int lrow = wm + mi * 16 + (lane >> 4) * 4 + j;
                    float val = acc[mi][ni][j] + bs;
                    tile[lrow * 144 + ((((lcol >> 4) ^ (lrow & 7)) << 4) | (lcol & 15))] =
                        f2fp8(val * 16.f);
                }
            }
        }
        __syncthreads();
#pragma unroll
        for (int it = 0; it < 4; ++it) {            // 1024 chunks of 16B
            int lin = it * 256 + t;
            int row = lin >> 3, ch = lin & 7;
            int crow = bm + row;
            if (crow < M) {
                const float4 vsrc = *(const float4*)(tile + row * 144 + ((ch ^ (row & 7)) << 4));
                *(float4*)((unsigned char*)C + (size_t)crow * rowbytes + gsecoff + ch * 16) = vsrc;
            }
        }
        return;
    }
    bool bf16lds = false;
    if (MODE == 1 && sec == 1)             { bf16lds = true; gsecoff = 128; rowbytes = 512; }
    else if (MODE >= 2 && sec >= 2 && sec < 4) {
        bf16lds = true; gsecoff = 256 + (sec - 2) * 256; rowbytes = 1024;
    }
    if (bf16lds) {
        unsigned char* tile = smem;                 // 128 rows x 272B stride
        __syncthreads();
#pragma unroll
        for (int ni = 0; ni < 4; ++ni) {
            int lcol = wn + ni * 16 + (lane & 15);
            float bs = bias[bn + lcol];
            int by = lcol * 2, ch = by >> 4;
#pragma unroll
            for (int mi = 0; mi < 4; ++mi) {
#pragma unroll
                for (int j = 0; j < 4; ++j) {
                    int lrow = wm + mi * 16 + (lane >> 4) * 4 + j;
                    float val = acc[mi][ni][j] + bs;
                    *(u16*)(tile + lrow * 272 + ((ch ^ (lrow & 7)) << 4) + (by & 15)) = f2bf(val);
                }
            }
        }
        __syncthreads();
#pragma unroll
        for (int it = 0; it < 8; ++it) {            // 2048 chunks of 16B
            int lin = it * 256 + t;
            int row = lin >> 4, ch = lin & 15;
            int crow = bm + row;
            if (crow < M) {
                const float4 vsrc = *(const float4*)(tile + row * 272 + ((ch ^ (row & 7)) << 4));
                *(float4*)((unsigned char*)C + (size_t)crow * rowbytes + gsecoff + ch * 16) = vsrc;
            }
        }
        return;
    }
#pragma unroll
    for (int ni = 0; ni < 4; ++ni) {
        int lcol = wn + ni * 16 + (lane & 15);
        int ccol = bn + lcol;
        if (ccol >= Nvalid) continue;
        float bs = bias[ccol];
#pragma unroll
        for (int mi = 0; mi < 4; ++mi) {
#pragma unroll
            for (int j = 0; j < 4; ++j) {
                int crow = bm + wm + mi * 16 + (lane >> 4) * 4 + j;
                if (crow >= M) continue;
                float val = acc[mi][ni][j] + bs;
                if (MODE == 1) {
                    C2[(size_t)crow * 128 + lcol] = val;
                } else {
                    C2[(size_t)crow * 64 + lcol] = val;
                }
            }
        }
    }
}

// ---------------- CSR build (rank-based, single atomic pass) ----------------
__global__ void zero1_k(int* __restrict__ a, int n) {
    int i = blockIdx.x * 256 + threadIdx.x;
    if (i < n) a[i] = 0;
}

__global__ void hist_k(const int* __restrict__ dst, int* __restrict__ cnt,
                       int* __restrict__ rank, int E) {
    int i = blockIdx.x * 256 + threadIdx.x;
    if (i < E) rank[i] = atomicAdd(&cnt[dst[i]], 1);
}

__global__ void blocksum_k(const int* __restrict__ cnt, int* __restrict__ bsum, int n) {
    __shared__ int sd[256];
    int i = blockIdx.x * 256 + threadIdx.x;
    sd[threadIdx.x] = (i < n) ? cnt[i] : 0;
    __syncthreads();
    for (int off = 128; off > 0; off >>= 1) {
        if (threadIdx.x < off) sd[threadIdx.x] += sd[threadIdx.x + off];
        __syncthreads();
    }
    if (threadIdx.x == 0) bsum[blockIdx.x] = sd[0];
}

__global__ void scanb_k(int* bsum, int nb) {
    __shared__ int tmp[512];
    int t = threadIdx.x;
    tmp[t] = (t < nb) ? bsum[t] : 0;
    __syncthreads();
    for (int off = 1; off < 512; off <<= 1) {
        int v = (t >= off) ? tmp[t - off] : 0;
        __syncthreads();
        tmp[t] += v;
        __syncthreads();
    }
    if (t < nb) bsum[t] = (t ? tmp[t - 1] : 0);
}

__global__ void scanc_k(const int* __restrict__ cnt, const int* __restrict__ bsum,
                        int* __restrict__ row_off, int n, int E) {
    __shared__ int tmp[256];
    int b = blockIdx.x, t = threadIdx.x;
    int i = b * 256 + t;
    int own = (i < n) ? cnt[i] : 0;
    tmp[t] = own;
    __syncthreads();
    for (int off = 1; off < 256; off <<= 1) {
        int v = (t >= off) ? tmp[t - off] : 0;
        __syncthreads();
        tmp[t] += v;
        __syncthreads();
    }
    if (i < n) row_off[i] = bsum[b] + tmp[t] - own;
    if (b == 0 && t == 0) row_off[n] = E;
}

__global__ void scatter_k(const int* __restrict__ src, const int* __restrict__ dst,
                          const int* __restrict__ row_off, const int* __restrict__ rank,
                          int* __restrict__ csr_src, int E) {
    int i = blockIdx.x * 256 + threadIdx.x;
    if (i < E) csr_src[row_off[dst[i]] + rank[i]] = src[i];
}

// ---------------- attn0 + gres0 + LN fused: 8 heads x d=16, fp8 q/v, 512B rows --------
// lane l: feats 2l,2l+1 (head l>>3). Epilogue does gated residual + LN + relu -> h1.
__global__ __launch_bounds__(256) void attn0_k(const unsigned char* __restrict__ qkv,
                                               const int* __restrict__ row_off,
                                               const int* __restrict__ csr,
                                               const float* __restrict__ res0o,
                                               const float* __restrict__ gw,
                                               const float* __restrict__ lng,
                                               const float* __restrict__ lnb,
                                               u16* __restrict__ h1, int n) {
    int w = (blockIdx.x * 256 + threadIdx.x) >> 6;
    int lane = threadIdx.x & 63;
    if (w >= n) return;
    int beg = row_off[w], end = row_off[w + 1];
    unsigned kv = *(const unsigned*)(qkv + (size_t)w * 512 + 128 + 4 * lane);
    const float KS = (0.25f / 16.f) * 1.44269504f;        // 1/sqrt(16)/qscale * log2e
    float k0f = bf2f((u16)kv) * KS, k1f = bf2f((u16)(kv >> 16)) * KS;
    float den = 0.f, num0 = 0.f, num1 = 0.f;
    int e = beg;
    for (; e + 4 <= end; e += 4) {
        int s0 = csr[e], s1 = csr[e + 1], s2 = csr[e + 2], s3 = csr[e + 3];
        const unsigned char* r0 = qkv + (size_t)s0 * 512;
        const unsigned char* r1 = qkv + (size_t)s1 * 512;
        const unsigned char* r2 = qkv + (size_t)s2 * 512;
        const unsigned char* r3 = qkv + (size_t)s3 * 512;
        int qa = *(const unsigned short*)(r0 + 2 * lane);
        int qb = *(const unsigned short*)(r1 + 2 * lane);
        int qc = *(const unsigned short*)(r2 + 2 * lane);
        int qd = *(const unsigned short*)(r3 + 2 * lane);
        int va = *(const unsigned short*)(r0 + 384 + 2 * lane);
        int vb = *(const unsigned short*)(r1 + 384 + 2 * lane);
        int vc = *(const unsigned short*)(r2 + 384 + 2 * lane);
        int vd = *(const unsigned short*)(r3 + 384 + 2 * lane);
        f32x2 qaf = __builtin_amdgcn_cvt_pk_f32_fp8(qa, false);
        f32x2 qbf = __builtin_amdgcn_cvt_pk_f32_fp8(qb, false);
        f32x2 qcf = __builtin_amdgcn_cvt_pk_f32_fp8(qc, false);
        f32x2 qdf = __builtin_amdgcn_cvt_pk_f32_fp8(qd, false);
        float pa = qaf.x * k0f + qaf.y * k1f;
        float pb = qbf.x * k0f + qbf.y * k1f;
        float pc = qcf.x * k0f + qcf.y * k1f;
        float pd = qdf.x * k0f + qdf.y * k1f;
#pragma unroll
        for (int off = 1; off < 8; off <<= 1) {
            pa += __shfl_xor(pa, off); pb += __shfl_xor(pb, off);
            pc += __shfl_xor(pc, off); pd += __shfl_xor(pd, off);
        }
        float wa = exp2f(pa), wb = exp2f(pb);
        float wc = exp2f(pc), wd = exp2f(pd);
        den += (wa + wb) + (wc + wd);
        f32x2 vaf = __builtin_amdgcn_cvt_pk_f32_fp8(va, false);
        f32x2 vbf = __builtin_amdgcn_cvt_pk_f32_fp8(vb, false);
        f32x2 vcf = __builtin_amdgcn_cvt_pk_f32_fp8(vc, false);
        f32x2 vdf = __builtin_amdgcn_cvt_pk_f32_fp8(vd, false);
        num0 = fmaf(wa, vaf.x, num0); num1 = fmaf(wa, vaf.y, num1);
        num0 = fmaf(wb, vbf.x, num0); num1 = fmaf(wb, vbf.y, num1);
        num0 = fmaf(wc, vcf.x, num0); num1 = fmaf(wc, vcf.y, num1);
        num0 = fmaf(wd, vdf.x, num0); num1 = fmaf(wd, vdf.y, num1);
    }
    for (; e < end; ++e) {
        int s = csr[e];
        const unsigned char* r = qkv + (size_t)s * 512;
        int qv = *(const unsigned short*)(r + 2 * lane);
        f32x2 qf = __builtin_amdgcn_cvt_pk_f32_fp8(qv, false);
        float p = qf.x * k0f + qf.y * k1f;
        p += __shfl_xor(p, 1);
        p += __shfl_xor(p, 2);
        p += __shfl_xor(p, 4);
        float wt = exp2f(p);
        den += wt;
        int vv = *(const unsigned short*)(r + 384 + 2 * lane);
        f32x2 vf = __builtin_amdgcn_cvt_pk_f32_fp8(vv, false);
        num0 = fmaf(wt, vf.x, num0); num1 = fmaf(wt, vf.y, num1);
    }
    float inv = (end > beg) ? (1.f / den) * (1.f / 16.f) : 0.f;   // v descale
    float x1 = num0 * inv, x2 = num1 * inv;
    // ---- fused gated residual + LN + relu (feats 2l, 2l+1) ----
    f32x2 rv  = *(const f32x2*)(res0o + (size_t)w * 128 + 2 * lane);
    f32x2 ga  = *(const f32x2*)(gw + 2 * lane);
    f32x2 gb  = *(const f32x2*)(gw + 128 + 2 * lane);
    f32x2 gc  = *(const f32x2*)(gw + 256 + 2 * lane);
    float ca1 = ga.x + gc.x, ca2 = ga.y + gc.y;
    float cr1 = gb.x - gc.x, cr2 = gb.y - gc.y;
    float dot = x1 * ca1 + x2 * ca2 + rv.x * cr1 + rv.y * cr2;
#pragma unroll
    for (int off = 1; off < 64; off <<= 1) dot += __shfl_xor(dot, off);
    float g = 1.f / (1.f + __expf(-dot));
    float o1 = x1 * g + rv.x * (1.f - g);
    float o2 = x2 * g + rv.y * (1.f - g);
    float s = o1 + o2;
#pragma unroll
    for (int off = 1; off < 64; off <<= 1) s += __shfl_xor(s, off);
    float mu = s * (1.f / 128.f);
    float d1 = o1 - mu, d2 = o2 - mu;
    float vs = d1 * d1 + d2 * d2;
#pragma unroll
    for (int off = 1; off < 64; off <<= 1) vs += __shfl_xor(vs, off);
    float rstd = rsqrtf(vs * (1.f / 128.f) + 1e-5f);
    f32x2 lg = *(const f32x2*)(lng + 2 * lane);
    f32x2 lb = *(const f32x2*)(lnb + 2 * lane);
    float y1 = fmaxf(d1 * rstd * lg.x + lb.x, 0.f);
    float y2 = fmaxf(d2 * rstd * lg.y + lb.y, 0.f);
    unsigned pk = (unsigned)f2bf(y1) | ((unsigned)f2bf(y2) << 16);
    ((unsigned*)h1)[(size_t)w * 64 + lane] = pk;
}

// ---------------- attn1 core (one 4-head pass over 1024B rows) ----------------
// Computes per-lane o0..o3 (valid in lanes 0-15 after head-sum) and den validity.
__device__ __forceinline__ void attn1_core(const unsigned char* __restrict__ qkv,
                                           const int* __restrict__ csr,
                                           int w, int lane, int beg, int end,
                                           float& o0, float& o1, float& o2, float& o3) {
    const float KS = (0.125f / 16.f) * 1.44269504f;       // 1/sqrt(64)/qscale * log2e
    float kr0, kr1, kr2, kr3;
    {
        uint2 kk2 = *(const uint2*)(qkv + (size_t)w * 1024 + 256 + 8 * lane);
        kr0 = bf2f((u16)kk2.x) * KS; kr1 = bf2f((u16)(kk2.x >> 16)) * KS;
        kr2 = bf2f((u16)kk2.y) * KS; kr3 = bf2f((u16)(kk2.y >> 16)) * KS;
    }
    float den = 0.f, num0 = 0.f, num1 = 0.f, num2 = 0.f, num3 = 0.f;
    int e = beg;
    for (; e + 4 <= end; e += 4) {
        int s0 = csr[e], s1 = csr[e + 1], s2 = csr[e + 2], s3 = csr[e + 3];
        const unsigned char* r0 = qkv + (size_t)s0 * 1024;
        const unsigned char* r1 = qkv + (size_t)s1 * 1024;
        const unsigned char* r2 = qkv + (size_t)s2 * 1024;
        const unsigned char* r3 = qkv + (size_t)s3 * 1024;
        unsigned qa = *(const unsigned*)(r0 + 4 * lane);
        unsigned qb = *(const unsigned*)(r1 + 4 * lane);
        unsigned qc = *(const unsigned*)(r2 + 4 * lane);
        unsigned qd = *(const unsigned*)(r3 + 4 * lane);
        unsigned va = *(const unsigned*)(r0 + 768 + 4 * lane);
        unsigned vb = *(const unsigned*)(r1 + 768 + 4 * lane);
        unsigned vc = *(const unsigned*)(r2 + 768 + 4 * lane);
        unsigned vd = *(const unsigned*)(r3 + 768 + 4 * lane);
        f32x2 qa0 = __builtin_amdgcn_cvt_pk_f32_fp8((int)qa, false);
        f32x2 qa1 = __builtin_amdgcn_cvt_pk_f32_fp8((int)qa, true);
        f32x2 qb0 = __builtin_amdgcn_cvt_pk_f32_fp8((int)qb, false);
        f32x2 qb1 = __builtin_amdgcn_cvt_pk_f32_fp8((int)qb, true);
        f32x2 qc0 = __builtin_amdgcn_cvt_pk_f32_fp8((int)qc, false);
        f32x2 qc1 = __builtin_amdgcn_cvt_pk_f32_fp8((int)qc, true);
        f32x2 qd0 = __builtin_amdgcn_cvt_pk_f32_fp8((int)qd, false);
        f32x2 qd1 = __builtin_amdgcn_cvt_pk_f32_fp8((int)qd, true);
        float pa = qa0.x * kr0 + qa0.y * kr1 + qa1.x * kr2 + qa1.y * kr3;
        float pb = qb0.x * kr0 + qb0.y * kr1 + qb1.x * kr2 + qb1.y * kr3;
        float pc = qc0.x * kr0 + qc0.y * kr1 + qc1.x * kr2 + qc1.y * kr3;
        float pd = qd0.x * kr0 + qd0.y * kr1 + qd1.x * kr2 + qd1.y * kr3;
#pragma unroll
        for (int off = 1; off < 16; off <<= 1) {
            pa += __shfl_xor(pa, off); pb += __shfl_xor(pb, off);
            pc += __shfl_xor(pc, off); pd += __shfl_xor(pd, off);
        }
        float wa = exp2f(pa), wb = exp2f(pb);
        float wc = exp2f(pc), wd = exp2f(pd);
        den += (wa + wb) + (wc + wd);
        f32x2 va0 = __builtin_amdgcn_cvt_pk_f32_fp8((int)va, false);
        f32x2 va1 = __builtin_amdgcn_cvt_pk_f32_fp8((int)va, true);
        f32x2 vb0 = __builtin_amdgcn_cvt_pk_f32_fp8((int)vb, false);
        f32x2 vb1 = __builtin_amdgcn_cvt_pk_f32_fp8((int)vb, true);
        f32x2 vc0 = __builtin_amdgcn_cvt_pk_f32_fp8((int)vc, false);
        f32x2 vc1 = __builtin_amdgcn_cvt_pk_f32_fp8((int)vc, true);
        f32x2 vd0 = __builtin_amdgcn_cvt_pk_f32_fp8((int)vd, false);
        f32x2 vd1 = __builtin_amdgcn_cvt_pk_f32_fp8((int)vd, true);
        num0 = fmaf(wa, va0.x, num0); num1 = fmaf(wa, va0.y, num1);
        num2 = fmaf(wa, va1.x, num2); num3 = fmaf(wa, va1.y, num3);
        num0 = fmaf(wb, vb0.x, num0); num1 = fmaf(wb, vb0.y, num1);
        num2 = fmaf(wb, vb1.x, num2); num3 = fmaf(wb, vb1.y, num3);
        num0 = fmaf(wc, vc0.x, num0); num1 = fmaf(wc, vc0.y, num1);
        num2 = fmaf(wc, vc1.x, num2); num3 = fmaf(wc, vc1.y, num3);
        num0 = fmaf(wd, vd0.x, num0); num1 = fmaf(wd, vd0.y, num1);
        num2 = fmaf(wd, vd1.x, num2); num3 = fmaf(wd, vd1.y, num3);
    }
    for (; e < end; ++e) {
        int s = csr[e];
        const unsigned char* r = qkv + (size_t)s * 1024;
        unsigned qv = *(const unsigned*)(r + 4 * lane);
        f32x2 q0 = __builtin_amdgcn_cvt_pk_f32_fp8((int)qv, false);
        f32x2 q1 = __builtin_amdgcn_cvt_pk_f32_fp8((int)qv, true);
        float p = q0.x * kr0 + q0.y * kr1 + q1.x * kr2 + q1.y * kr3;
#pragma unroll
        for (int off = 1; off < 16; off <<= 1) p += __shfl_xor(p, off);
        float wt = exp2f(p);
        den += wt;
        unsigned vv = *(const unsigned*)(r + 768 + 4 * lane);
        f32x2 v0 = __builtin_amdgcn_cvt_pk_f32_fp8((int)vv, false);
        f32x2 v1 = __builtin_amdgcn_cvt_pk_f32_fp8((int)vv, true);
        num0 = fmaf(wt, v0.x, num0); num1 = fmaf(wt, v0.y, num1);
        num2 = fmaf(wt, v1.x, num2); num3 = fmaf(wt, v1.y, num3);
    }
    float inv = (end > beg) ? 1.f / den : 0.f;
    o0 = num0 * inv; o1 = num1 * inv; o2 = num2 * inv; o3 = num3 * inv;
    o0 += __shfl_xor(o0, 16); o1 += __shfl_xor(o1, 16);
    o2 += __shfl_xor(o2, 16); o3 += __shfl_xor(o3, 16);
    o0 += __shfl_xor(o0, 32); o1 += __shfl_xor(o1, 32);
    o2 += __shfl_xor(o2, 32); o3 += __shfl_xor(o3, 32);
}

// pass 0: write partial head-mean to a1
__global__ __launch_bounds__(256) void attn1f_k(const unsigned char* __restrict__ qkv,
                                                const int* __restrict__ row_off,
                                                const int* __restrict__ csr,
                                                float* __restrict__ out, int n) {
    int w = (blockIdx.x * 256 + threadIdx.x) >> 6;
    int lane = threadIdx.x & 63;
    if (w >= n) return;
    int beg = row_off[w], end = row_off[w + 1];
    float o0, o1, o2, o3;
    attn1_core(qkv, csr, w, lane, beg, end, o0, o1, o2, o3);
    if (lane < 16) {
        const float HS = 1.f / 128.f;   // head-mean (1/8) * v descale (1/16)
        *(float4*)(out + ((size_t)w << 6) + lane * 4) =
            make_float4(o0 * HS, o1 * HS, o2 * HS, o3 * HS);
    }
}

// pass 1 + fused gres1: reads a1 partial + res1o, writes final d_out
__global__ __launch_bounds__(256) void attn1g_k(const unsigned char* __restrict__ qkv,
                                                const int* __restrict__ row_off,
                                                const int* __restrict__ csr,
                                                const float* __restrict__ a1,
                                                const float* __restrict__ res1o,
                                                const float* __restrict__ gw,
                                                float* __restrict__ out, int n) {
    int w = (blockIdx.x * 256 + threadIdx.x) >> 6;
    int lane = threadIdx.x & 63;
    if (w >= n) return;
    int beg = row_off[w], end = row_off[w + 1];
    float o0, o1, o2, o3;
    attn1_core(qkv, csr, w, lane, beg, end, o0, o1, o2, o3);
    // ---- fused gated residual over 64 feats (lanes 0-15 hold 4 feats each) ----
    const float HS = 1.f / 128.f;
    int ll = lane & 15;
    size_t base = (size_t)w * 64 + ll * 4;
    float4 ap = *(const float4*)(a1 + base);
    float4 rp = *(const float4*)(res1o + base);
    float4 g0 = *(const float4*)(gw + ll * 4);
    float4 g1 = *(const float4*)(gw + 64 + ll * 4);
    float4 g2 = *(const float4*)(gw + 128 + ll * 4);
    float xv0 = ap.x + o0 * HS, xv1 = ap.y + o1 * HS;
    float xv2 = ap.z + o2 * HS, xv3 = ap.w + o3 * HS;
    float dot = xv0 * (g0.x + g2.x) + xv1 * (g0.y + g2.y)
              + xv2 * (g0.z + g2.z) + xv3 * (g0.w + g2.w)
              + rp.x * (g1.x - g2.x) + rp.y * (g1.y - g2.y)
              + rp.z * (g1.z - g2.z) + rp.w * (g1.w - g2.w);
#pragma unroll
    for (int off = 1; off < 16; off <<= 1) dot += __shfl_xor(dot, off);
    float g = 1.f / (1.f + __expf(-dot));
    if (lane < 16) {
        float4 ov;
        ov.x = xv0 * g + rp.x * (1.f - g);
        ov.y = xv1 * g + rp.y * (1.f - g);
        ov.z = xv2 * g + rp.z * (1.f - g);
        ov.w = xv3 * g + rp.w * (1.f - g);
        *(float4*)(out + base) = ov;
    }
}

extern "C" void kernel_launch(void* const* d_in, const int* in_sizes, int n_in,
                              void* d_out, int out_size, void* d_ws, size_t ws_size,
                              hipStream_t stream) {
    const float* x    = (const float*)d_in[0];
    const int*   src  = (const int*)d_in[1];
    const int*   dst  = (const int*)d_in[2];
    const float* in_W = (const float*)d_in[3];
    const float* in_b = (const float*)d_in[4];
    const float* q0W = (const float*)d_in[5];  const float* q0b = (const float*)d_in[6];
    const float* k0W = (const float*)d_in[7];  const float* k0b = (const float*)d_in[8];
    const float* v0W = (const float*)d_in[9];  const float* v0b = (const float*)d_in[10];
    const float* r0W = (const float*)d_in[11]; const float* r0b = (const float*)d_in[12];
    const float* g0W = (const float*)d_in[13];
    const float* ln0g = (const float*)d_in[14]; const float* ln0b = (const float*)d_in[15];
    const float* q1W = (const float*)d_in[16]; const float* q1b = (const float*)d_in[17];
    const float* k1W = (const float*)d_in[18]; const float* k1b = (const float*)d_in[19];
    const float* v1W = (const float*)d_in[20]; const float* v1b = (const float*)d_in[21];
    const float* r1W = (const float*)d_in[22]; const float* r1b = (const float*)d_in[23];
    const float* g1W = (const float*)d_in[24];

    const int N = in_sizes[0] / 256;   // 100000
    const int E = in_sizes[1];         // 1600000
    (void)ws_size; (void)n_in; (void)out_size;

    // ---- workspace layout: headers + 3.5 regions of 51.2 MB, peak ~190 MB ----
    auto rnd = [](size_t b) { return (b + 255) & ~(size_t)255; };
    char* base = (char*)d_ws;
    const size_t S_f = rnd((size_t)N * 128 * 4);    // 51.2 MB region unit
    size_t o = 0;
    int* row_off = (int*)(base + o); o += rnd(((size_t)N + 1) * 4);
    int* csr     = (int*)(base + o); o += rnd((size_t)E * 4);
    u16* warena  = (u16*)(base + o); o += rnd((size_t)(303104 + 131072) * 2);
    float* barena = (float*)(base + o); o += rnd((size_t)(1600 + 512) * 4);
    char* RB = base + o;
    // Region A [0,S): cnt/bsum -> QKV0 -> PASS head
    // Region B [S,2S): res0o -> PASS tail
    // Region C [2S,3S): x_bf -> {a1, res1o}
    // Region D [3S,3.5S): rank -> h1
    int* cnt  = (int*)RB;
    int* bsum = (int*)(RB + rnd((size_t)N * 4));
    unsigned char* QKV0 = (unsigned char*)RB;            // N x 512 B
    unsigned char* PASS = (unsigned char*)RB;            // N x 1024 B (A+B)
    float* res0o = (float*)(RB + S_f);
    u16*   x_bf  = (u16*)(RB + 2 * S_f);                 // N x 256 bf16
    float* a1    = (float*)(RB + 2 * S_f);
    float* res1o = (float*)(RB + 2 * S_f + rnd((size_t)N * 64 * 4));
    int*   rank  = (int*)(RB + 3 * S_f);                 // E ints (6.4 MB)
    u16*   h1    = (u16*)(RB + 3 * S_f);                 // N x 128 bf16

    // weight arena sections
    u16* qkv1t0 = warena + 98304;      // pass0 rows 0..767
    u16* qkv1t1 = warena + 196608;     // pass1 rows 0..767, 768..831 = r1t (contiguous)
    u16* cwt    = warena + 303104;     // collapsed layer-0 [512][256]
    float* qkv1b = barena;             // [0..1536) p0|p1, [1536..1600) r1b
    float* cwb   = barena + 1600;      // collapsed layer-0 biases [512]

    dim3 blk(256);
    int nwb = (N * 64 + 255) / 256;   // one wave per node
    int nb  = (N + 255) / 256;        // 391 (<= 512)
    int mb  = (N + 127) / 128;        // 782
    int xch = (mb + 7) / 8;           // 98 (XCD-swizzled grid chunk count)

    // ---- prep (weights/bias/x convert) ----
    prep_k<<<(303104 - 98304 + 255) / 256, blk, 0, stream>>>(q1W, k1W, v1W, r1W, warena);
    cw_k<<<(131584 + 255) / 256, blk, 0, stream>>>(in_W, in_b, q0W, k0W, v0W, r0W,
                                                   q0b, k0b, v0b, r0b, cwt, cwb);
    bias_k<<<7, blk, 0, stream>>>(q1b, k1b, v1b, r1b, barena);
    cvt_k<<<(N * 32 + 255) / 256, blk, 0, stream>>>(x, x_bf, N * 32);

    // ---- CSR build (rank-based) ----
    zero1_k<<<nb, blk, 0, stream>>>(cnt, N);
    hist_k<<<(E + 255) / 256, blk, 0, stream>>>(dst, cnt, rank, E);
    blocksum_k<<<nb, blk, 0, stream>>>(cnt, bsum, N);
    scanb_k<<<1, 512, 0, stream>>>(bsum, nb);
    scanc_k<<<nb, blk, 0, stream>>>(cnt, bsum, row_off, N, E);
    scatter_k<<<(E + 255) / 256, blk, 0, stream>>>(src, dst, row_off, rank, csr, E);

    // ---- layer 0: collapsed K=256 GEMM, then fused attn0+gres0 ----
    mgemm7<1, 256><<<8 * 4 * xch, blk, 0, stream>>>(x_bf, cwt, cwb, QKV0, res0o,
                                                    N, mb, 4, 512);
    attn0_k<<<nwb, blk, 0, stream>>>(QKV0, row_off, csr, res0o, g0W, ln0g, ln0b, h1, N);

    // ---- layer 1: pass0 (qkv) -> attn1f; pass1 (qkv + r1) -> attn1g (fused gres1) ----
    mgemm7<2, 128><<<8 * 6 * xch, blk, 0, stream>>>(h1, qkv1t0, qkv1b, PASS,
                                                    nullptr, N, mb, 6, 768);
    attn1f_k<<<nwb, blk, 0, stream>>>(PASS, row_off, csr, a1, N);

    mgemm7<3, 128><<<8 * 7 * xch, blk, 0, stream>>>(h1, qkv1t1, qkv1b + 768, PASS,
                                                    res1o, N, mb, 7, 832);
    attn1g_k<<<nwb, blk, 0, stream>>>(PASS, row_off, csr, a1, res1o, g1W,
                                      (float*)d_out, N);
}

// Round 18
// 678.152 us; speedup vs baseline: 1.9597x; 1.0776x over previous
//
#include <hip/hip_runtime.h>

// GraphTransformerModel: 2-layer graph attention network.
// CSR build (rank-scatter) -> collapsed layer-0 GEMM (x @ [inW@{q,k,v,r}0W], K=256)
// -> attn0+gres0+LN fused (fp8 q/v, 512B rows) -> ONE qkv1 GEMM (all-fp8 1536B rows,
// res1 -> d_out) -> attn1s single 8-head pass + fused gres1 (writes d_out).
// mgemm7: XCD-swizzled blocks, global_load_lds + XOR swizzle, LDS-staged epilogues.
// fp8 = e4m3 x16 scale. Peak workspace ~187 MB.

typedef unsigned short u16;
typedef __attribute__((ext_vector_type(8))) unsigned short ushort8;
typedef __attribute__((ext_vector_type(8))) short short8v;   // 8 bf16 (4 VGPRs)
typedef __attribute__((ext_vector_type(4))) float f32x4;
typedef __attribute__((ext_vector_type(2))) float f32x2;

__device__ __forceinline__ float bf2f(unsigned short u) {
    return __uint_as_float(((unsigned)u) << 16);
}
__device__ __forceinline__ unsigned short f2bf(float f) {
    unsigned u = __float_as_uint(f);
    unsigned r = 0x7fffu + ((u >> 16) & 1u);   // round-to-nearest-even
    return (unsigned short)((u + r) >> 16);
}
__device__ __forceinline__ unsigned char f2fp8(float f) {   // HW e4m3 encode
    return (unsigned char)__builtin_amdgcn_cvt_pk_fp8_f32(f, 0.f, 0, false);
}

// async global->LDS, 16B per lane; dest is wave-uniform base + lane*16 (HW).
__device__ __forceinline__ void gload16(const void* gp, const void* lp) {
    __builtin_amdgcn_global_load_lds(
        (const __attribute__((address_space(1))) unsigned*)(uintptr_t)gp,
        (__attribute__((address_space(3))) unsigned*)(unsigned)(uintptr_t)lp,
        16, 0, 0);
}

// ---------------- layer-1 weight prep: qkv1t[1600][128] ----------------
// row n: n<512 q1W col n; <1024 k1W col n-512; <1536 v1W col n-1024; else r1W col n-1536.
__global__ void prep_k(const float* __restrict__ q1W, const float* __restrict__ k1W,
                       const float* __restrict__ v1W, const float* __restrict__ r1W,
                       u16* __restrict__ arena) {
    int i = blockIdx.x * 256 + threadIdx.x;
    if (i >= 204800) return;
    int row = i >> 7, kk = i & 127;
    float val;
    if (row < 512)       val = q1W[kk * 512 + row];
    else if (row < 1024) val = k1W[kk * 512 + row - 512];
    else if (row < 1536) val = v1W[kk * 512 + row - 1024];
    else                 val = r1W[kk * 64 + (row - 1536)];
    arena[i] = f2bf(val);
}

// ---------------- collapsed layer-0 weights: cwt[512][256], cwb[512] ----------------
__global__ void cw_k(const float* __restrict__ inW, const float* __restrict__ in_b,
                     const float* __restrict__ q0W, const float* __restrict__ k0W,
                     const float* __restrict__ v0W, const float* __restrict__ r0W,
                     const float* __restrict__ q0b, const float* __restrict__ k0b,
                     const float* __restrict__ v0b, const float* __restrict__ r0b,
                     u16* __restrict__ cwt, float* __restrict__ cwb) {
    int i = blockIdx.x * 256 + threadIdx.x;
    if (i < 131072) {
        int n = i >> 8, k = i & 255;
        int sec = n >> 7, c = n & 127;
        const float* s = (sec == 0) ? q0W : (sec == 1) ? k0W : (sec == 2) ? v0W : r0W;
        float acc = 0.f;
        for (int j = 0; j < 128; ++j) acc = fmaf(inW[k * 128 + j], s[j * 128 + c], acc);
        cwt[(size_t)n * 256 + k] = f2bf(acc);
    } else if (i < 131584) {
        int n = i - 131072;
        int sec = n >> 7, c = n & 127;
        const float* s = (sec == 0) ? q0W : (sec == 1) ? k0W : (sec == 2) ? v0W : r0W;
        const float* b = (sec == 0) ? q0b : (sec == 1) ? k0b : (sec == 2) ? v0b : r0b;
        float acc = b[c];
        for (int j = 0; j < 128; ++j) acc = fmaf(in_b[j], s[j * 128 + c], acc);
        cwb[n] = acc;
    }
}

// layer-1 biases (1600 floats): [0)=q1b[512] [512)=k1b[512] [1024)=v1b[512] [1536)=r1b[64]
__global__ void bias_k(const float* __restrict__ q1b, const float* __restrict__ k1b,
                       const float* __restrict__ v1b, const float* __restrict__ r1b,
                       float* __restrict__ out) {
    int i = blockIdx.x * 256 + threadIdx.x;
    if (i >= 1600) return;
    if (i < 512)       out[i] = q1b[i];
    else if (i < 1024) out[i] = k1b[i - 512];
    else if (i < 1536) out[i] = v1b[i - 1024];
    else               out[i] = r1b[i - 1536];
}

// ---------------- f32 -> bf16 convert (8 elems/thread) ----------------
__global__ void cvt_k(const float* __restrict__ in, u16* __restrict__ out, int n8) {
    int i = blockIdx.x * 256 + threadIdx.x;
    if (i >= n8) return;
    float4 a = *(const float4*)(in + (size_t)i * 8);
    float4 b = *(const float4*)(in + (size_t)i * 8 + 4);
    ushort8 o = {f2bf(a.x), f2bf(a.y), f2bf(a.z), f2bf(a.w),
                 f2bf(b.x), f2bf(b.y), f2bf(b.z), f2bf(b.w)};
    *(ushort8*)(out + (size_t)i * 8) = o;
}

// ---------------- MFMA GEMM v7: XCD-swizzled, fused multi-section ----------------
// MODE 1: layer0 combo (512B rows): sec 0,2 fp8; sec 1 bf16 k; sec 3 -> f32 C2 [M,128]
// MODE 4: layer1 single (1536B rows): sec 0-11 fp8; sec 12 -> f32 C2 [M,64]
template <int MODE, int K>
__global__ __launch_bounds__(256) void mgemm7(const u16* __restrict__ A,
                                              const u16* __restrict__ Bt,
                                              const float* __restrict__ bias,
                                              void* __restrict__ C,
                                              float* __restrict__ C2,
                                              int M, int MB, int ny, int Nvalid) {
    __shared__ __align__(16) unsigned char smem[36864];   // As 16K | Bs 16K; epi tile reuse
    u16* As = (u16*)smem;
    u16* Bs = (u16*)(smem + 16384);
    int id = blockIdx.x;
    int xcd = id & 7, rest = id >> 3;
    int y = rest % ny;
    int x = (rest / ny) * 8 + xcd;
    if (x >= MB) return;
    const int bm = x * 128;
    const int bn = y * 128;
    const int t = threadIdx.x, lane = t & 63, wid = t >> 6;
    const int wm = (wid >> 1) * 64, wn = (wid & 1) * 64;
    const int jlog = ((lane & 7) ^ (lane >> 3)) * 8;
    f32x4 acc[4][4] = {};
    for (int k0 = 0; k0 < K; k0 += 64) {
#pragma unroll
        for (int c2 = 0; c2 < 4; ++c2) {
            int seg = c2 * 4 + wid;
            int row = seg * 8 + (lane >> 3);
            int ga = bm + row; if (ga >= M) ga = 0;
            gload16(A + (size_t)ga * K + k0 + jlog, (const char*)As + seg * 1024);
            int gb = bn + row; if (gb >= Nvalid) gb = 0;
            gload16(Bt + (size_t)gb * K + k0 + jlog, (const char*)Bs + seg * 1024);
        }
        __syncthreads();
#pragma unroll
        for (int ks = 0; ks < 2; ++ks) {
            const int jx = ks * 4 + (lane >> 4);
            short8v af[4], bfr[4];
#pragma unroll
            for (int i = 0; i < 4; ++i) {
                int ra = wm + i * 16 + (lane & 15);
                af[i] = *(const short8v*)((const char*)As + ra * 128 + ((jx ^ (ra & 7)) << 4));
                int rb = wn + i * 16 + (lane & 15);
                bfr[i] = *(const short8v*)((const char*)Bs + rb * 128 + ((jx ^ (rb & 7)) << 4));
            }
#pragma unroll
            for (int mi = 0; mi < 4; ++mi)
#pragma unroll
                for (int ni = 0; ni < 4; ++ni)
                    acc[mi][ni] = __builtin_amdgcn_mfma_f32_16x16x32_bf16(
                        af[mi], bfr[ni], acc[mi][ni], 0, 0, 0);
        }
        if (k0 + 64 < K) __syncthreads();
    }
    const int sec = y;
    bool fp8lds = false;
    int gsecoff = 0, rowbytes = 0;
    if (MODE == 1) {
        if (sec == 0)      { fp8lds = true; gsecoff = 0;   rowbytes = 512; }
        else if (sec == 2) { fp8lds = true; gsecoff = 384; rowbytes = 512; }
    } else {   // MODE 4
        if (sec < 12)      { fp8lds = true; gsecoff = sec * 128; rowbytes = 1536; }
    }
    if (fp8lds) {
        unsigned char* tile = smem;                 // 128 rows x 144B stride
        __syncthreads();
#pragma unroll
        for (int ni = 0; ni < 4; ++ni) {
            int lcol = wn + ni * 16 + (lane & 15);
            float bs = bias[bn + lcol];
#pragma unroll
            for (int mi = 0; mi < 4; ++mi) {
#pragma unroll
                for (int j = 0; j < 4; ++j) {
                    int lrow = wm + mi * 16 + (lane >> 4) * 4 + j;
                    float val = acc[mi][ni][j] + bs;
                    tile[lrow * 144 + ((((lcol >> 4) ^ (lrow & 7)) << 4) | (lcol & 15))] =
                        f2fp8(val * 16.f);
                }
            }
        }
        __syncthreads();
#pragma unroll
        for (int it = 0; it < 4; ++it) {            // 1024 chunks of 16B
            int lin = it * 256 + t;
            int row = lin >> 3, ch = lin & 7;
            int crow = bm + row;
            if (crow < M) {
                const float4 vsrc = *(const float4*)(tile + row * 144 + ((ch ^ (row & 7)) << 4));
                *(float4*)((unsigned char*)C + (size_t)crow * rowbytes + gsecoff + ch * 16) = vsrc;
            }
        }
        return;
    }
    if (MODE == 1 && sec == 1) {   // bf16 k section, 512B rows at +128
        unsigned char* tile = smem;                 // 128 rows x 272B stride
        __syncthreads();
#pragma unroll
        for (int ni = 0; ni < 4; ++ni) {
            int lcol = wn + ni * 16 + (lane & 15);
            float bs = bias[bn + lcol];
            int by = lcol * 2, ch = by >> 4;
#pragma unroll
            for (int mi = 0; mi < 4; ++mi) {
#pragma unroll
                for (int j = 0; j < 4; ++j) {
                    int lrow = wm + mi * 16 + (lane >> 4) * 4 + j;
                    float val = acc[mi][ni][j] + bs;
                    *(u16*)(tile + lrow * 272 + ((ch ^ (lrow & 7)) << 4) + (by & 15)) = f2bf(val);
                }
            }
        }
        __syncthreads();
#pragma unroll
        for (int it = 0; it < 8; ++it) {            // 2048 chunks of 16B
            int lin = it * 256 + t;
            int row = lin >> 4, ch = lin & 15;
            int crow = bm + row;
            if (crow < M) {
                const float4 vsrc = *(const float4*)(tile + row * 272 + ((ch ^ (row & 7)) << 4));
                *(float4*)((unsigned char*)C + (size_t)crow * 512 + 128 + ch * 16) = vsrc;
            }
        }
        return;
    }
    // direct f32 sections (MODE1 sec3: res0o [M,128]; MODE4 sec12: res1 [M,64])
#pragma unroll
    for (int ni = 0; ni < 4; ++ni) {
        int lcol = wn + ni * 16 + (lane & 15);
        int ccol = bn + lcol;
        if (ccol >= Nvalid) continue;
        float bs = bias[ccol];
#pragma unroll
        for (int mi = 0; mi < 4; ++mi) {
#pragma unroll
            for (int j = 0; j < 4; ++j) {
                int crow = bm + wm + mi * 16 + (lane >> 4) * 4 + j;
                if (crow >= M) continue;
                float val = acc[mi][ni][j] + bs;
                if (MODE == 1) C2[(size_t)crow * 128 + lcol] = val;
                else           C2[(size_t)crow * 64 + lcol] = val;
            }
        }
    }
}

// ---------------- CSR build (rank-based, single atomic pass) ----------------
__global__ void zero1_k(int* __restrict__ a, int n) {
    int i = blockIdx.x * 256 + threadIdx.x;
    if (i < n) a[i] = 0;
}

__global__ void hist_k(const int* __restrict__ dst, int* __restrict__ cnt,
                       int* __restrict__ rank, int E) {
    int i = blockIdx.x * 256 + threadIdx.x;
    if (i < E) rank[i] = atomicAdd(&cnt[dst[i]], 1);
}

__global__ void blocksum_k(const int* __restrict__ cnt, int* __restrict__ bsum, int n) {
    __shared__ int sd[256];
    int i = blockIdx.x * 256 + threadIdx.x;
    sd[threadIdx.x] = (i < n) ? cnt[i] : 0;
    __syncthreads();
    for (int off = 128; off > 0; off >>= 1) {
        if (threadIdx.x < off) sd[threadIdx.x] += sd[threadIdx.x + off];
        __syncthreads();
    }
    if (threadIdx.x == 0) bsum[blockIdx.x] = sd[0];
}

__global__ void scanb_k(int* bsum, int nb) {
    __shared__ int tmp[512];
    int t = threadIdx.x;
    tmp[t] = (t < nb) ? bsum[t] : 0;
    __syncthreads();
    for (int off = 1; off < 512; off <<= 1) {
        int v = (t >= off) ? tmp[t - off] : 0;
        __syncthreads();
        tmp[t] += v;
        __syncthreads();
    }
    if (t < nb) bsum[t] = (t ? tmp[t - 1] : 0);
}

__global__ void scanc_k(const int* __restrict__ cnt, const int* __restrict__ bsum,
                        int* __restrict__ row_off, int n, int E) {
    __shared__ int tmp[256];
    int b = blockIdx.x, t = threadIdx.x;
    int i = b * 256 + t;
    int own = (i < n) ? cnt[i] : 0;
    tmp[t] = own;
    __syncthreads();
    for (int off = 1; off < 256; off <<= 1) {
        int v = (t >= off) ? tmp[t - off] : 0;
        __syncthreads();
        tmp[t] += v;
        __syncthreads();
    }
    if (i < n) row_off[i] = bsum[b] + tmp[t] - own;
    if (b == 0 && t == 0) row_off[n] = E;
}

__global__ void scatter_k(const int* __restrict__ src, const int* __restrict__ dst,
                          const int* __restrict__ row_off, const int* __restrict__ rank,
                          int* __restrict__ csr_src, int E) {
    int i = blockIdx.x * 256 + threadIdx.x;
    if (i < E) csr_src[row_off[dst[i]] + rank[i]] = src[i];
}

// ---------------- attn0 + gres0 + LN fused: 8 heads x d=16, fp8 q/v, 512B rows --------
__global__ __launch_bounds__(256) void attn0_k(const unsigned char* __restrict__ qkv,
                                               const int* __restrict__ row_off,
                                               const int* __restrict__ csr,
                                               const float* __restrict__ res0o,
                                               const float* __restrict__ gw,
                                               const float* __restrict__ lng,
                                               const float* __restrict__ lnb,
                                               u16* __restrict__ h1, int n) {
    int w = (blockIdx.x * 256 + threadIdx.x) >> 6;
    int lane = threadIdx.x & 63;
    if (w >= n) return;
    int beg = row_off[w], end = row_off[w + 1];
    unsigned kv = *(const unsigned*)(qkv + (size_t)w * 512 + 128 + 4 * lane);
    const float KS = (0.25f / 16.f) * 1.44269504f;        // 1/sqrt(16)/qscale * log2e
    float k0f = bf2f((u16)kv) * KS, k1f = bf2f((u16)(kv >> 16)) * KS;
    float den = 0.f, num0 = 0.f, num1 = 0.f;
    int e = beg;
    for (; e + 4 <= end; e += 4) {
        int s0 = csr[e], s1 = csr[e + 1], s2 = csr[e + 2], s3 = csr[e + 3];
        const unsigned char* r0 = qkv + (size_t)s0 * 512;
        const unsigned char* r1 = qkv + (size_t)s1 * 512;
        const unsigned char* r2 = qkv + (size_t)s2 * 512;
        const unsigned char* r3 = qkv + (size_t)s3 * 512;
        int qa = *(const unsigned short*)(r0 + 2 * lane);
        int qb = *(const unsigned short*)(r1 + 2 * lane);
        int qc = *(const unsigned short*)(r2 + 2 * lane);
        int qd = *(const unsigned short*)(r3 + 2 * lane);
        int va = *(const unsigned short*)(r0 + 384 + 2 * lane);
        int vb = *(const unsigned short*)(r1 + 384 + 2 * lane);
        int vc = *(const unsigned short*)(r2 + 384 + 2 * lane);
        int vd = *(const unsigned short*)(r3 + 384 + 2 * lane);
        f32x2 qaf = __builtin_amdgcn_cvt_pk_f32_fp8(qa, false);
        f32x2 qbf = __builtin_amdgcn_cvt_pk_f32_fp8(qb, false);
        f32x2 qcf = __builtin_amdgcn_cvt_pk_f32_fp8(qc, false);
        f32x2 qdf = __builtin_amdgcn_cvt_pk_f32_fp8(qd, false);
        float pa = qaf.x * k0f + qaf.y * k1f;
        float pb = qbf.x * k0f + qbf.y * k1f;
        float pc = qcf.x * k0f + qcf.y * k1f;
        float pd = qdf.x * k0f + qdf.y * k1f;
#pragma unroll
        for (int off = 1; off < 8; off <<= 1) {
            pa += __shfl_xor(pa, off); pb += __shfl_xor(pb, off);
            pc += __shfl_xor(pc, off); pd += __shfl_xor(pd, off);
        }
        float wa = exp2f(pa), wb = exp2f(pb);
        float wc = exp2f(pc), wd = exp2f(pd);
        den += (wa + wb) + (wc + wd);
        f32x2 vaf = __builtin_amdgcn_cvt_pk_f32_fp8(va, false);
        f32x2 vbf = __builtin_amdgcn_cvt_pk_f32_fp8(vb, false);
        f32x2 vcf = __builtin_amdgcn_cvt_pk_f32_fp8(vc, false);
        f32x2 vdf = __builtin_amdgcn_cvt_pk_f32_fp8(vd, false);
        num0 = fmaf(wa, vaf.x, num0); num1 = fmaf(wa, vaf.y, num1);
        num0 = fmaf(wb, vbf.x, num0); num1 = fmaf(wb, vbf.y, num1);
        num0 = fmaf(wc, vcf.x, num0); num1 = fmaf(wc, vcf.y, num1);
        num0 = fmaf(wd, vdf.x, num0); num1 = fmaf(wd, vdf.y, num1);
    }
    for (; e < end; ++e) {
        int s = csr[e];
        const unsigned char* r = qkv + (size_t)s * 512;
        int qv = *(const unsigned short*)(r + 2 * lane);
        f32x2 qf = __builtin_amdgcn_cvt_pk_f32_fp8(qv, false);
        float p = qf.x * k0f + qf.y * k1f;
        p += __shfl_xor(p, 1);
        p += __shfl_xor(p, 2);
        p += __shfl_xor(p, 4);
        float wt = exp2f(p);
        den += wt;
        int vv = *(const unsigned short*)(r + 384 + 2 * lane);
        f32x2 vf = __builtin_amdgcn_cvt_pk_f32_fp8(vv, false);
        num0 = fmaf(wt, vf.x, num0); num1 = fmaf(wt, vf.y, num1);
    }
    float inv = (end > beg) ? (1.f / den) * (1.f / 16.f) : 0.f;   // v descale
    float x1 = num0 * inv, x2 = num1 * inv;
    // ---- fused gated residual + LN + relu (feats 2l, 2l+1) ----
    f32x2 rv  = *(const f32x2*)(res0o + (size_t)w * 128 + 2 * lane);
    f32x2 ga  = *(const f32x2*)(gw + 2 * lane);
    f32x2 gb  = *(const f32x2*)(gw + 128 + 2 * lane);
    f32x2 gc  = *(const f32x2*)(gw + 256 + 2 * lane);
    float ca1 = ga.x + gc.x, ca2 = ga.y + gc.y;
    float cr1 = gb.x - gc.x, cr2 = gb.y - gc.y;
    float dot = x1 * ca1 + x2 * ca2 + rv.x * cr1 + rv.y * cr2;
#pragma unroll
    for (int off = 1; off < 64; off <<= 1) dot += __shfl_xor(dot, off);
    float g = 1.f / (1.f + __expf(-dot));
    float o1 = x1 * g + rv.x * (1.f - g);
    float o2 = x2 * g + rv.y * (1.f - g);
    float s = o1 + o2;
#pragma unroll
    for (int off = 1; off < 64; off <<= 1) s += __shfl_xor(s, off);
    float mu = s * (1.f / 128.f);
    float d1 = o1 - mu, d2 = o2 - mu;
    float vs = d1 * d1 + d2 * d2;
#pragma unroll
    for (int off = 1; off < 64; off <<= 1) vs += __shfl_xor(vs, off);
    float rstd = rsqrtf(vs * (1.f / 128.f) + 1e-5f);
    f32x2 lg = *(const f32x2*)(lng + 2 * lane);
    f32x2 lb = *(const f32x2*)(lnb + 2 * lane);
    float y1 = fmaxf(d1 * rstd * lg.x + lb.x, 0.f);
    float y2 = fmaxf(d2 * rstd * lg.y + lb.y, 0.f);
    unsigned pk = (unsigned)f2bf(y1) | ((unsigned)f2bf(y2) << 16);
    ((unsigned*)h1)[(size_t)w * 64 + lane] = pk;
}

// ---------------- attn1 single pass (8 heads x d=64) + fused gres1 ----------------
// 1536B rows: [q fp8 512B | k fp8 512B | v fp8 512B]. lane l: feats 8l..8l+7
// (head l>>3, 8 lanes/head). res1 lives in `out` (d_out); read then overwrite.
__global__ __launch_bounds__(256) void attn1s_k(const unsigned char* __restrict__ qkv,
                                                const int* __restrict__ row_off,
                                                const int* __restrict__ csr,
                                                const float* __restrict__ gw,
                                                float* __restrict__ out, int n) {
    int w = (blockIdx.x * 256 + threadIdx.x) >> 6;
    int lane = threadIdx.x & 63;
    if (w >= n) return;
    int beg = row_off[w], end = row_off[w + 1];
    const float KS = 1.44269504f / 2048.f;   // log2e / (16*16*sqrt(64))
    float kr[8];
    {
        uint2 kk = *(const uint2*)(qkv + (size_t)w * 1536 + 512 + 8 * lane);
        f32x2 k0 = __builtin_amdgcn_cvt_pk_f32_fp8((int)kk.x, false);
        f32x2 k1 = __builtin_amdgcn_cvt_pk_f32_fp8((int)kk.x, true);
        f32x2 k2 = __builtin_amdgcn_cvt_pk_f32_fp8((int)kk.y, false);
        f32x2 k3 = __builtin_amdgcn_cvt_pk_f32_fp8((int)kk.y, true);
        kr[0] = k0.x * KS; kr[1] = k0.y * KS; kr[2] = k1.x * KS; kr[3] = k1.y * KS;
        kr[4] = k2.x * KS; kr[5] = k2.y * KS; kr[6] = k3.x * KS; kr[7] = k3.y * KS;
    }
    float den = 0.f;
    float num[8] = {};
    int e = beg;
    for (; e + 2 <= end; e += 2) {
        int s0 = csr[e], s1 = csr[e + 1];
        const unsigned char* r0 = qkv + (size_t)s0 * 1536;
        const unsigned char* r1 = qkv + (size_t)s1 * 1536;
        uint2 qa = *(const uint2*)(r0 + 8 * lane);
        uint2 qb = *(const uint2*)(r1 + 8 * lane);
        uint2 va = *(const uint2*)(r0 + 1024 + 8 * lane);
        uint2 vb = *(const uint2*)(r1 + 1024 + 8 * lane);
        f32x2 a0 = __builtin_amdgcn_cvt_pk_f32_fp8((int)qa.x, false);
        f32x2 a1 = __builtin_amdgcn_cvt_pk_f32_fp8((int)qa.x, true);
        f32x2 a2 = __builtin_amdgcn_cvt_pk_f32_fp8((int)qa.y, false);
        f32x2 a3 = __builtin_amdgcn_cvt_pk_f32_fp8((int)qa.y, true);
        f32x2 b0 = __builtin_amdgcn_cvt_pk_f32_fp8((int)qb.x, false);
        f32x2 b1 = __builtin_amdgcn_cvt_pk_f32_fp8((int)qb.x, true);
        f32x2 b2 = __builtin_amdgcn_cvt_pk_f32_fp8((int)qb.y, false);
        f32x2 b3 = __builtin_amdgcn_cvt_pk_f32_fp8((int)qb.y, true);
        float pa = a0.x * kr[0] + a0.y * kr[1] + a1.x * kr[2] + a1.y * kr[3]
                 + a2.x * kr[4] + a2.y * kr[5] + a3.x * kr[6] + a3.y * kr[7];
        float pb = b0.x * kr[0] + b0.y * kr[1] + b1.x * kr[2] + b1.y * kr[3]
                 + b2.x * kr[4] + b2.y * kr[5] + b3.x * kr[6] + b3.y * kr[7];
        pa += __shfl_xor(pa, 1); pb += __shfl_xor(pb, 1);
        pa += __shfl_xor(pa, 2); pb += __shfl_xor(pb, 2);
        pa += __shfl_xor(pa, 4); pb += __shfl_xor(pb, 4);
        float wa = exp2f(pa), wb = exp2f(pb);
        den += wa + wb;
        f32x2 c0 = __builtin_amdgcn_cvt_pk_f32_fp8((int)va.x, false);
        f32x2 c1 = __builtin_amdgcn_cvt_pk_f32_fp8((int)va.x, true);
        f32x2 c2 = __builtin_amdgcn_cvt_pk_f32_fp8((int)va.y, false);
        f32x2 c3 = __builtin_amdgcn_cvt_pk_f32_fp8((int)va.y, true);
        f32x2 d0 = __builtin_amdgcn_cvt_pk_f32_fp8((int)vb.x, false);
        f32x2 d1 = __builtin_amdgcn_cvt_pk_f32_fp8((int)vb.x, true);
        f32x2 d2 = __builtin_amdgcn_cvt_pk_f32_fp8((int)vb.y, false);
        f32x2 d3 = __builtin_amdgcn_cvt_pk_f32_fp8((int)vb.y, true);
        num[0] = fmaf(wa, c0.x, num[0]); num[1] = fmaf(wa, c0.y, num[1]);
        num[2] = fmaf(wa, c1.x, num[2]); num[3] = fmaf(wa, c1.y, num[3]);
        num[4] = fmaf(wa, c2.x, num[4]); num[5] = fmaf(wa, c2.y, num[5]);
        num[6] = fmaf(wa, c3.x, num[6]); num[7] = fmaf(wa, c3.y, num[7]);
        num[0] = fmaf(wb, d0.x, num[0]); num[1] = fmaf(wb, d0.y, num[1]);
        num[2] = fmaf(wb, d1.x, num[2]); num[3] = fmaf(wb, d1.y, num[3]);
        num[4] = fmaf(wb, d2.x, num[4]); num[5] = fmaf(wb, d2.y, num[5]);
        num[6] = fmaf(wb, d3.x, num[6]); num[7] = fmaf(wb, d3.y, num[7]);
    }
    for (; e < end; ++e) {
        int s = csr[e];
        const unsigned char* r = qkv + (size_t)s * 1536;
        uint2 qv = *(const uint2*)(r + 8 * lane);
        f32x2 a0 = __builtin_amdgcn_cvt_pk_f32_fp8((int)qv.x, false);
        f32x2 a1 = __builtin_amdgcn_cvt_pk_f32_fp8((int)qv.x, true);
        f32x2 a2 = __builtin_amdgcn_cvt_pk_f32_fp8((int)qv.y, false);
        f32x2 a3 = __builtin_amdgcn_cvt_pk_f32_fp8((int)qv.y, true);
        float p = a0.x * kr[0] + a0.y * kr[1] + a1.x * kr[2] + a1.y * kr[3]
                + a2.x * kr[4] + a2.y * kr[5] + a3.x * kr[6] + a3.y * kr[7];
        p += __shfl_xor(p, 1);
        p += __shfl_xor(p, 2);
        p += __shfl_xor(p, 4);
        float wt = exp2f(p);
        den += wt;
        uint2 vv = *(const uint2*)(r + 1024 + 8 * lane);
        f32x2 c0 = __builtin_amdgcn_cvt_pk_f32_fp8((int)vv.x, false);
        f32x2 c1 = __builtin_amdgcn_cvt_pk_f32_fp8((int)vv.x, true);
        f32x2 c2 = __builtin_amdgcn_cvt_pk_f32_fp8((int)vv.y, false);
        f32x2 c3 = __builtin_amdgcn_cvt_pk_f32_fp8((int)vv.y, true);
        num[0] = fmaf(wt, c0.x, num[0]); num[1] = fmaf(wt, c0.y, num[1]);
        num[2] = fmaf(wt, c1.x, num[2]); num[3] = fmaf(wt, c1.y, num[3]);
        num[4] = fmaf(wt, c2.x, num[4]); num[5] = fmaf(wt, c2.y, num[5]);
        num[6] = fmaf(wt, c3.x, num[6]); num[7] = fmaf(wt, c3.y, num[7]);
    }
    const float HS = 1.f / 128.f;        // head-mean (1/8) * v descale (1/16)
    float inv = (end > beg) ? (1.f / den) * HS : 0.f;
    float o[8];
#pragma unroll
    for (int j = 0; j < 8; ++j) o[j] = num[j] * inv;
    // head-sum across the 8 head groups (same dim slot l&7)
#pragma unroll
    for (int off = 8; off < 64; off <<= 1)
#pragma unroll
        for (int j = 0; j < 8; ++j) o[j] += __shfl_xor(o[j], off);
    // ---- fused gated residual over 64 feats (all lanes replicated; l&7 = slot) ----
    int ll = lane & 7;
    size_t base = (size_t)w * 64 + ll * 8;
    float4 rp0 = *(const float4*)(out + base);
    float4 rp1 = *(const float4*)(out + base + 4);
    float4 ga0 = *(const float4*)(gw + ll * 8);
    float4 ga1 = *(const float4*)(gw + ll * 8 + 4);
    float4 gb0 = *(const float4*)(gw + 64 + ll * 8);
    float4 gb1 = *(const float4*)(gw + 64 + ll * 8 + 4);
    float4 gc0 = *(const float4*)(gw + 128 + ll * 8);
    float4 gc1 = *(const float4*)(gw + 128 + ll * 8 + 4);
    float dot = o[0] * (ga0.x + gc0.x) + o[1] * (ga0.y + gc0.y)
              + o[2] * (ga0.z + gc0.z) + o[3] * (ga0.w + gc0.w)
              + o[4] * (ga1.x + gc1.x) + o[5] * (ga1.y + gc1.y)
              + o[6] * (ga1.z + gc1.z) + o[7] * (ga1.w + gc1.w)
              + rp0.x * (gb0.x - gc0.x) + rp0.y * (gb0.y - gc0.y)
              + rp0.z * (gb0.z - gc0.z) + rp0.w * (gb0.w - gc0.w)
              + rp1.x * (gb1.x - gc1.x) + rp1.y * (gb1.y - gc1.y)
              + rp1.z * (gb1.z - gc1.z) + rp1.w * (gb1.w - gc1.w);
    dot += __shfl_xor(dot, 1);
    dot += __shfl_xor(dot, 2);
    dot += __shfl_xor(dot, 4);
    float g = 1.f / (1.f + __expf(-dot));
    if (lane < 8) {
        float4 ov0, ov1;
        ov0.x = o[0] * g + rp0.x * (1.f - g);
        ov0.y = o[1] * g + rp0.y * (1.f - g);
        ov0.z = o[2] * g + rp0.z * (1.f - g);
        ov0.w = o[3] * g + rp0.w * (1.f - g);
        ov1.x = o[4] * g + rp1.x * (1.f - g);
        ov1.y = o[5] * g + rp1.y * (1.f - g);
        ov1.z = o[6] * g + rp1.z * (1.f - g);
        ov1.w = o[7] * g + rp1.w * (1.f - g);
        *(float4*)(out + base) = ov0;
        *(float4*)(out + base + 4) = ov1;
    }
}

extern "C" void kernel_launch(void* const* d_in, const int* in_sizes, int n_in,
                              void* d_out, int out_size, void* d_ws, size_t ws_size,
                              hipStream_t stream) {
    const float* x    = (const float*)d_in[0];
    const int*   src  = (const int*)d_in[1];
    const int*   dst  = (const int*)d_in[2];
    const float* in_W = (const float*)d_in[3];
    const float* in_b = (const float*)d_in[4];
    const float* q0W = (const float*)d_in[5];  const float* q0b = (const float*)d_in[6];
    const float* k0W = (const float*)d_in[7];  const float* k0b = (const float*)d_in[8];
    const float* v0W = (const float*)d_in[9];  const float* v0b = (const float*)d_in[10];
    const float* r0W = (const float*)d_in[11]; const float* r0b = (const float*)d_in[12];
    const float* g0W = (const float*)d_in[13];
    const float* ln0g = (const float*)d_in[14]; const float* ln0b = (const float*)d_in[15];
    const float* q1W = (const float*)d_in[16]; const float* q1b = (const float*)d_in[17];
    const float* k1W = (const float*)d_in[18]; const float* k1b = (const float*)d_in[19];
    const float* v1W = (const float*)d_in[20]; const float* v1b = (const float*)d_in[21];
    const float* r1W = (const float*)d_in[22]; const float* r1b = (const float*)d_in[23];
    const float* g1W = (const float*)d_in[24];

    const int N = in_sizes[0] / 256;   // 100000
    const int E = in_sizes[1];         // 1600000
    (void)ws_size; (void)n_in; (void)out_size;

    // ---- workspace layout: headers + 3 regions (PASS) + 0.5 region, ~187 MB ----
    auto rnd = [](size_t b) { return (b + 255) & ~(size_t)255; };
    char* base = (char*)d_ws;
    const size_t S_f = rnd((size_t)N * 128 * 4);    // 51.2 MB region unit
    size_t o = 0;
    int* row_off = (int*)(base + o); o += rnd(((size_t)N + 1) * 4);
    int* csr     = (int*)(base + o); o += rnd((size_t)E * 4);
    u16* warena  = (u16*)(base + o); o += rnd((size_t)(204800 + 131072) * 2);
    float* barena = (float*)(base + o); o += rnd((size_t)(1600 + 512) * 4);
    char* RB = base + o;
    // Regions A,B,C [0,3S): cnt/bsum -> QKV0(A) + res0o(B) + x_bf(C) -> PASS (A+B+C)
    // Region D [3S,3.5S): rank -> h1
    int* cnt  = (int*)RB;
    int* bsum = (int*)(RB + rnd((size_t)N * 4));
    unsigned char* QKV0 = (unsigned char*)RB;            // N x 512 B (A)
    unsigned char* PASS = (unsigned char*)RB;            // N x 1536 B (A+B+C)
    float* res0o = (float*)(RB + S_f);                   // (B)
    u16*   x_bf  = (u16*)(RB + 2 * S_f);                 // N x 256 bf16 (C)
    int*   rank  = (int*)(RB + 3 * S_f);                 // E ints (D)
    u16*   h1    = (u16*)(RB + 3 * S_f);                 // N x 128 bf16 (D, rank dead)

    // weight arena sections
    u16* qkv1t = warena;               // [1600][128] (q|k|v|r1)
    u16* cwt   = warena + 204800;      // collapsed layer-0 [512][256]
    float* qkv1b = barena;             // [1600]
    float* cwb   = barena + 1600;      // collapsed layer-0 biases [512]

    dim3 blk(256);
    int nwb = (N * 64 + 255) / 256;   // one wave per node
    int nb  = (N + 255) / 256;        // 391 (<= 512)
    int mb  = (N + 127) / 128;        // 782
    int xch = (mb + 7) / 8;           // 98 (XCD-swizzled grid chunk count)

    // ---- prep (weights/bias/x convert) ----
    prep_k<<<(204800 + 255) / 256, blk, 0, stream>>>(q1W, k1W, v1W, r1W, qkv1t);
    cw_k<<<(131584 + 255) / 256, blk, 0, stream>>>(in_W, in_b, q0W, k0W, v0W, r0W,
                                                   q0b, k0b, v0b, r0b, cwt, cwb);
    bias_k<<<7, blk, 0, stream>>>(q1b, k1b, v1b, r1b, barena);
    cvt_k<<<(N * 32 + 255) / 256, blk, 0, stream>>>(x, x_bf, N * 32);

    // ---- CSR build (rank-based) ----
    zero1_k<<<nb, blk, 0, stream>>>(cnt, N);
    hist_k<<<(E + 255) / 256, blk, 0, stream>>>(dst, cnt, rank, E);
    blocksum_k<<<nb, blk, 0, stream>>>(cnt, bsum, N);
    scanb_k<<<1, 512, 0, stream>>>(bsum, nb);
    scanc_k<<<nb, blk, 0, stream>>>(cnt, bsum, row_off, N, E);
    scatter_k<<<(E + 255) / 256, blk, 0, stream>>>(src, dst, row_off, rank, csr, E);

    // ---- layer 0: collapsed K=256 GEMM, then fused attn0+gres0 ----
    mgemm7<1, 256><<<8 * 4 * xch, blk, 0, stream>>>(x_bf, cwt, cwb, QKV0, res0o,
                                                    N, mb, 4, 512);
    attn0_k<<<nwb, blk, 0, stream>>>(QKV0, row_off, csr, res0o, g0W, ln0g, ln0b, h1, N);

    // ---- layer 1: ONE GEMM (qkv fp8 + res1 -> d_out), then single-pass attn+gres ----
    mgemm7<4, 128><<<8 * 13 * xch, blk, 0, stream>>>(h1, qkv1t, qkv1b, PASS,
                                                     (float*)d_out, N, mb, 13, 1600);
    attn1s_k<<<nwb, blk, 0, stream>>>(PASS, row_off, csr, g1W, (float*)d_out, N);
}